// Round 1
// baseline (283.048 us; speedup 1.0000x reference)
//
#include <hip/hip_runtime.h>

#define B_   2
#define C_   1024
#define L_   2048
#define H_   16
#define HD_  64
#define BH_  (B_*H_)
#define N_   (B_*L_)
#define SCALE_ (1.0f/(1024.0f*2048.0f))

typedef __attribute__((ext_vector_type(8))) short short8;
typedef __attribute__((ext_vector_type(4))) short bs4;
typedef __attribute__((ext_vector_type(4))) float f32x4;

#define MFMA(a,b,c) __builtin_amdgcn_mfma_f32_16x16x32_bf16((a),(b),(c),0,0,0)

#define GLOAD16(gp, lp) \
  __builtin_amdgcn_global_load_lds( \
      (const __attribute__((address_space(1))) void*)(gp), \
      (__attribute__((address_space(3))) void*)(lp), 16, 0, 0)

__device__ __forceinline__ unsigned short f2b(float f) {
    union { float f; unsigned u; } v; v.f = f;
    unsigned r = (v.u + 0x7fffu + ((v.u >> 16) & 1u)) >> 16;
    return (unsigned short)r;
}
__device__ __forceinline__ bs4 pack4(f32x4 e) {
    union { f32x4 v; unsigned u[4]; } a; a.v = e;
    union { bs4 s; unsigned u[2]; } r;
    r.u[0] = __builtin_amdgcn_perm(a.u[1] + 0x8000u, a.u[0] + 0x8000u, 0x07060302u);
    r.u[1] = __builtin_amdgcn_perm(a.u[3] + 0x8000u, a.u[2] + 0x8000u, 0x07060302u);
    return r.s;
}
__device__ __forceinline__ float b2f(unsigned short s) {
    union { unsigned u; float f; } v; v.u = ((unsigned)s) << 16; return v.f;
}

// ---------------------------------------------------------------------------
// wprep: blocks 0..4095 convert kw/pw/c1w/c2w fp32->bf16;
//        blocks 4096..4351 transpose qw -> qwT bf16 (block 4096 also zeros X1)
// ---------------------------------------------------------------------------
struct Ptr4 { const float* p[4]; };
__global__ __launch_bounds__(256) void wprep(
    Ptr4 src, unsigned short* __restrict__ dst,
    const float* __restrict__ qw, unsigned short* __restrict__ qwT,
    float* __restrict__ X1)
{
    const int bx = blockIdx.x, t = threadIdx.x;
    if (bx < 4096) {
        const float* s = src.p[bx >> 10];
        unsigned short* d = dst + (size_t)(bx >> 10) * ((size_t)C_ * C_);
        int i = (((bx & 1023) * 256) + t) * 4;
        float4 v = *(const float4*)(s + i);
        ushort4 o;
        o.x = f2b(v.x); o.y = f2b(v.y); o.z = f2b(v.z); o.w = f2b(v.w);
        *(ushort4*)(d + i) = o;
        return;
    }
    const int tb = bx - 4096;
    if (tb == 0) {
        ((float4*)X1)[t] = float4{0.f, 0.f, 0.f, 0.f};
        ((float4*)X1)[256 + t] = float4{0.f, 0.f, 0.f, 0.f};
    }
    const int d0 = (tb >> 4) * 64, c0 = (tb & 15) * 64;
    __shared__ float T[64][65];
    const int tr = t >> 6, tc = t & 63;
#pragma unroll
    for (int r = 0; r < 16; ++r)
        T[r * 4 + tr][tc] = qw[(size_t)(d0 + r * 4 + tr) * C_ + c0 + tc];
    __syncthreads();
#pragma unroll
    for (int r = 0; r < 16; ++r) {
        int cc = r * 4 + tr;
        qwT[(size_t)(c0 + cc) * C_ + d0 + tc] = f2b(T[tc][cc]);
    }
}

// x f32 [b][c][l] -> xN bf16 [b][c][l], xT bf16 [b*2048+l][c], X1[b][c]=sum_l x
__global__ __launch_bounds__(256) void prep_x(
    const float* __restrict__ x, unsigned short* __restrict__ xN,
    unsigned short* __restrict__ xT, float* __restrict__ X1)
{
    int b = blockIdx.z, c0 = blockIdx.y * 64, l0 = blockIdx.x * 64;
    __shared__ float T[64][65];
    const float* xb = x + (size_t)b * C_ * L_;
    int tc = threadIdx.x >> 6;
    int tl = threadIdx.x & 63;
#pragma unroll
    for (int r = 0; r < 16; ++r) {
        int c = c0 + r * 4 + tc;
        float v = xb[(size_t)c * L_ + l0 + tl];
        T[r * 4 + tc][tl] = v;
        xN[((size_t)b * C_ + c) * L_ + l0 + tl] = f2b(v);
        float s = v;
#pragma unroll
        for (int d = 1; d < 64; d <<= 1) s += __shfl_xor(s, d);
        if (tl == 0) atomicAdd(&X1[b * C_ + c], s);
    }
    __syncthreads();
#pragma unroll
    for (int r = 0; r < 16; ++r) {
        int lr = r * 4 + tc;
        xT[((size_t)b * L_ + l0 + lr) * C_ + c0 + tl] = f2b(T[tl][lr]);
    }
}

// ---------------------------------------------------------------------------
// gram64: G[b][c1][c2] = sum_l xN[b,c1,l]*xN[b,c2,l]. 64x64, BK=64, dbuf.
// grid (16,16,B) = 512 blocks.
// ---------------------------------------------------------------------------
__global__ __launch_bounds__(256) void gram64(
    const unsigned short* __restrict__ xN, unsigned short* __restrict__ G)
{
    const int t = threadIdx.x, w = t >> 6, lane = t & 63;
    const int b = blockIdx.z;
    const int c10 = blockIdx.y * 64, c20 = blockIdx.x * 64;
    const int l15 = lane & 15, q8 = (lane >> 4) * 8, q4 = (lane >> 4) * 4;
    const int wm = (w >> 1) * 32, wn = (w & 1) * 32;
    const unsigned short* xb = xN + (size_t)b * C_ * L_;

    __shared__ union {
        __align__(16) unsigned short st[2][2][2][64 * 32]; // [buf][A/B][ks]
        __align__(16) unsigned short Cs[64 * 72];
    } u;

    auto stage = [&](int buf, int k0) {
        int row = t >> 2, off = (t & 3) * 8;
        GLOAD16(&xb[(size_t)(c10 + row) * L_ + k0 + off],      &u.st[buf][0][0][(w * 64) * 8]);
        GLOAD16(&xb[(size_t)(c10 + row) * L_ + k0 + 32 + off], &u.st[buf][0][1][(w * 64) * 8]);
        GLOAD16(&xb[(size_t)(c20 + row) * L_ + k0 + off],      &u.st[buf][1][0][(w * 64) * 8]);
        GLOAD16(&xb[(size_t)(c20 + row) * L_ + k0 + 32 + off], &u.st[buf][1][1][(w * 64) * 8]);
    };

    f32x4 acc[2][2] = {};
    stage(0, 0);
    for (int kt = 0; kt < 32; ++kt) {
        const int cur = kt & 1;
        __syncthreads();
        if (kt < 31) stage(cur ^ 1, (kt + 1) * 64);
#pragma unroll
        for (int ks = 0; ks < 2; ++ks) {
            short8 a[2], bf[2];
#pragma unroll
            for (int mi = 0; mi < 2; ++mi)
                a[mi] = *(const short8*)&u.st[cur][0][ks][(wm + mi * 16 + l15) * 32 + q8];
#pragma unroll
            for (int ni = 0; ni < 2; ++ni)
                bf[ni] = *(const short8*)&u.st[cur][1][ks][(wn + ni * 16 + l15) * 32 + q8];
#pragma unroll
            for (int mi = 0; mi < 2; ++mi)
#pragma unroll
                for (int ni = 0; ni < 2; ++ni)
                    acc[mi][ni] = MFMA(a[mi], bf[ni], acc[mi][ni]);
        }
    }

    __syncthreads();
#pragma unroll
    for (int mi = 0; mi < 2; ++mi)
#pragma unroll
        for (int r = 0; r < 4; ++r)
#pragma unroll
            for (int ni = 0; ni < 2; ++ni)
                u.Cs[(wm + mi * 16 + q4 + r) * 72 + wn + ni * 16 + l15] =
                    f2b(acc[mi][ni][r]);
    __syncthreads();
#pragma unroll
    for (int p = 0; p < 2; ++p) {
        int E = p * 256 + t;
        int row = E >> 3, seg = E & 7;
        short8 val = *(const short8*)&u.Cs[row * 72 + seg * 8];
        *(short8*)&G[((size_t)b * C_ + c10 + row) * C_ + c20 + seg * 8] = val;
    }
}

// ---------------------------------------------------------------------------
// mid_ab (grid 32 = bh):
//  ph1: A_h[c,d] = sum_cc G[b][h*64+c][cc]*kw[h*64+d][cc] + X1[c]*kb[d] -> LDS
//       cvec[b][h*64+c] = X1[c]/2048 + (A_h·qb)[c]*SCALE_
//  ph2: BallT[b][cc][h*64+c] = sum_d A_h[c,d]*qwT[cc][h*64+d]
// ---------------------------------------------------------------------------
__global__ __launch_bounds__(256) void mid_ab(
    const unsigned short* __restrict__ G, const unsigned short* __restrict__ kwb,
    const unsigned short* __restrict__ qwT,
    const float* __restrict__ X1, const float* __restrict__ kb,
    const float* __restrict__ qb,
    unsigned short* __restrict__ BallT, float* __restrict__ cvec)
{
    const int t = threadIdx.x, w = t >> 6, lane = t & 63;
    const int bh = blockIdx.x, b = bh >> 4, h = bh & 15;
    const int l15 = lane & 15, q8 = (lane >> 4) * 8, q4 = (lane >> 4) * 4;

    __shared__ union {
        struct { __align__(16) unsigned short Gs[2][64 * 32];
                 __align__(16) unsigned short Ks[2][64 * 32]; } st;
        __align__(16) unsigned short As[64 * 72];
    } u;

    const unsigned short* gb  = G   + ((size_t)b * C_ + h * 64) * C_;
    const unsigned short* kwh = kwb + (size_t)h * 64 * C_;

    auto stage = [&](int buf, int k0) {
        int row = t >> 2, off = (t & 3) * 8;
        GLOAD16(&gb[(size_t)row * C_ + k0 + off], &u.st.Gs[buf][(w * 64) * 8]);
        GLOAD16(&kwh[(size_t)row * C_ + k0 + off], &u.st.Ks[buf][(w * 64) * 8]);
    };

    f32x4 acc[4] = {};
    stage(0, 0);
    for (int kt = 0; kt < 32; ++kt) {
        const int cur = kt & 1;
        __syncthreads();
        if (kt < 31) stage(cur ^ 1, (kt + 1) * 32);
        short8 a = *(const short8*)&u.st.Gs[cur][(w * 16 + l15) * 32 + q8];
#pragma unroll
        for (int ni = 0; ni < 4; ++ni) {
            short8 bf = *(const short8*)&u.st.Ks[cur][(ni * 16 + l15) * 32 + q8];
            acc[ni] = MFMA(a, bf, acc[ni]);
        }
    }
    __syncthreads();

    float x1r[4];
#pragma unroll
    for (int r = 0; r < 4; ++r)
        x1r[r] = X1[b * C_ + h * 64 + w * 16 + q4 + r];
    float ch[4] = {0.f, 0.f, 0.f, 0.f};
#pragma unroll
    for (int ni = 0; ni < 4; ++ni) {
        const int d = ni * 16 + l15;
        const float kbd = kb[h * 64 + d], qbd = qb[h * 64 + d];
#pragma unroll
        for (int r = 0; r < 4; ++r) {
            const int c = w * 16 + q4 + r;
            float a = acc[ni][r] + x1r[r] * kbd;
            u.As[c * 72 + d] = f2b(a);
            ch[r] += a * qbd;
        }
    }
#pragma unroll
    for (int r = 0; r < 4; ++r) {
#pragma unroll
        for (int dd = 1; dd < 16; dd <<= 1) ch[r] += __shfl_xor(ch[r], dd);
        if (l15 == 0)
            cvec[b * C_ + h * 64 + w * 16 + q4 + r] =
                x1r[r] * (1.0f / L_) + ch[r] * SCALE_;
    }
    __syncthreads();

#pragma unroll
    for (int i = 0; i < 4; ++i) {
        const int cc0 = (i * 4 + w) * 64;
        f32x4 ac[4][4] = {};
#pragma unroll
        for (int ks = 0; ks < 2; ++ks) {
            short8 af[4], bf[4];
#pragma unroll
            for (int mi = 0; mi < 4; ++mi)
                af[mi] = *(const short8*)&u.As[(mi * 16 + l15) * 72 + ks * 32 + q8];
#pragma unroll
            for (int ni = 0; ni < 4; ++ni)
                bf[ni] = *(const short8*)&qwT[(size_t)(cc0 + ni * 16 + l15) * C_
                                              + h * 64 + ks * 32 + q8];
#pragma unroll
            for (int mi = 0; mi < 4; ++mi)
#pragma unroll
                for (int ni = 0; ni < 4; ++ni)
                    ac[mi][ni] = MFMA(af[mi], bf[ni], ac[mi][ni]);
        }
#pragma unroll
        for (int ni = 0; ni < 4; ++ni)
#pragma unroll
            for (int mi = 0; mi < 4; ++mi) {
                bs4 o = pack4(ac[mi][ni]);
                *(bs4*)&BallT[((size_t)b * C_ + cc0 + ni * 16 + l15) * C_
                              + h * 64 + mi * 16 + q4] = o;
            }
    }
}

// ---------------------------------------------------------------------------
// wy64: Wy[b][o][cc] = SCALE_ * sum_c pw[o,c]*BallT[b][cc][c]. 64x64 BK=64 dbuf.
// ---------------------------------------------------------------------------
__global__ __launch_bounds__(256) void wy64(
    const unsigned short* __restrict__ pwb, const unsigned short* __restrict__ BallT,
    unsigned short* __restrict__ Wy)
{
    const int t = threadIdx.x, w = t >> 6, lane = t & 63;
    const int b = blockIdx.z;
    const int o0 = blockIdx.y * 64, cc0 = blockIdx.x * 64;
    const int l15 = lane & 15, q8 = (lane >> 4) * 8, q4 = (lane >> 4) * 4;
    const int wm = (w >> 1) * 32, wn = (w & 1) * 32;
    const unsigned short* Bb = BallT + (size_t)b * C_ * C_;

    __shared__ union {
        __align__(16) unsigned short st[2][2][2][64 * 32];
        __align__(16) unsigned short Cs[64 * 72];
    } u;

    auto stage = [&](int buf, int k0) {
        int row = t >> 2, off = (t & 3) * 8;
        GLOAD16(&pwb[(size_t)(o0 + row) * C_ + k0 + off],      &u.st[buf][0][0][(w * 64) * 8]);
        GLOAD16(&pwb[(size_t)(o0 + row) * C_ + k0 + 32 + off], &u.st[buf][0][1][(w * 64) * 8]);
        GLOAD16(&Bb[(size_t)(cc0 + row) * C_ + k0 + off],      &u.st[buf][1][0][(w * 64) * 8]);
        GLOAD16(&Bb[(size_t)(cc0 + row) * C_ + k0 + 32 + off], &u.st[buf][1][1][(w * 64) * 8]);
    };

    f32x4 acc[2][2] = {};
    stage(0, 0);
    for (int kt = 0; kt < 16; ++kt) {
        const int cur = kt & 1;
        __syncthreads();
        if (kt < 15) stage(cur ^ 1, (kt + 1) * 64);
#pragma unroll
        for (int ks = 0; ks < 2; ++ks) {
            short8 a[2], bf[2];
#pragma unroll
            for (int mi = 0; mi < 2; ++mi)
                a[mi] = *(const short8*)&u.st[cur][0][ks][(wm + mi * 16 + l15) * 32 + q8];
#pragma unroll
            for (int ni = 0; ni < 2; ++ni)
                bf[ni] = *(const short8*)&u.st[cur][1][ks][(wn + ni * 16 + l15) * 32 + q8];
#pragma unroll
            for (int mi = 0; mi < 2; ++mi)
#pragma unroll
                for (int ni = 0; ni < 2; ++ni)
                    acc[mi][ni] = MFMA(a[mi], bf[ni], acc[mi][ni]);
        }
    }

    __syncthreads();
#pragma unroll
    for (int mi = 0; mi < 2; ++mi)
#pragma unroll
        for (int r = 0; r < 4; ++r)
#pragma unroll
            for (int ni = 0; ni < 2; ++ni)
                u.Cs[(wm + mi * 16 + q4 + r) * 72 + wn + ni * 16 + l15] =
                    f2b(acc[mi][ni][r] * SCALE_);
    __syncthreads();
#pragma unroll
    for (int p = 0; p < 2; ++p) {
        int E = p * 256 + t;
        int row = E >> 3, seg = E & 7;
        short8 val = *(const short8*)&u.Cs[row * 72 + seg * 8];
        *(short8*)&Wy[((size_t)b * C_ + o0 + row) * C_ + cc0 + seg * 8] = val;
    }
}

// dvec[b][o] = sum_c pwb[o,c]*cvec[b,c] + pb[o]
__global__ __launch_bounds__(256) void gemv_dvec(
    const unsigned short* __restrict__ pwb, const float* __restrict__ cvec,
    const float* __restrict__ pb, float* __restrict__ dvec)
{
    const int t = threadIdx.x, b = blockIdx.y;
    const int o = blockIdx.x * 128 + (t >> 1), part = t & 1;
    __shared__ float cv[1024];
#pragma unroll
    for (int i = 0; i < 4; ++i) cv[t + i * 256] = cvec[b * C_ + t + i * 256];
    __syncthreads();
    const int base = part * 512;
    float acc = 0.f;
#pragma unroll 8
    for (int j = 0; j < 64; ++j) {
        short8 w8 = *(const short8*)&pwb[(size_t)o * C_ + base + j * 8];
#pragma unroll
        for (int e = 0; e < 8; ++e)
            acc = fmaf(b2f((unsigned short)w8[e]), cv[base + j * 8 + e], acc);
    }
    acc += __shfl_xor(acc, 1);
    if (part == 0) dvec[b * C_ + o] = acc + pb[o];
}

// ---------------------------------------------------------------------------
// gemm128: out[o][n] = sum_k A[o][k]*Bt[n][k] (+bias/relu/residuals)
// 128x128 tile, 4 waves (2x2, each 64x64, acc[4][4]), BK=64, dbuf, GLOAD16.
// Grid (N/128, C/128) = 32x8 = 256 blocks.
// Epilogue order: v=acc+bias; relu; v+=add0; outT=f2b(v); v+=add1; outf=v.
// (add1==add0 reuses the loaded value: saves a 16MB f32 read in call 1.)
// ---------------------------------------------------------------------------
__global__ __launch_bounds__(256) void gemm128(
    const unsigned short* __restrict__ A0, size_t abstride,
    const float* __restrict__ bias, int bstride,
    const unsigned short* __restrict__ Bt,
    const float* __restrict__ add0, const float* __restrict__ add1,
    float* __restrict__ outf, unsigned short* __restrict__ outT, int relu)
{
    const int t = threadIdx.x, w = t >> 6, lane = t & 63;
    const int o0 = blockIdx.y * 128, n0 = blockIdx.x * 128;
    const int b_ = n0 >> 11;
    const int l15 = lane & 15, q8 = (lane >> 4) * 8, q4 = (lane >> 4) * 4;
    const int wm = (w >> 1) * 64, wn = (w & 1) * 64;
    const unsigned short* A = A0 + (size_t)b_ * abstride;

    __shared__ union {
        __align__(16) unsigned short st[2][2][2][128 * 32]; // [buf][A/B][ks][row*32+k]
        __align__(16) unsigned short Cs[128 * 136];
    } u;
    __shared__ float biass[128];
    if (t < 128) biass[t] = bias[b_ * bstride + o0 + t];

    auto stage = [&](int buf, int k0) {
        int row = t >> 2, off = (t & 3) * 8;
        // each wave writes a contiguous 16-row slab (wave-uniform LDS base)
        GLOAD16(&A[(size_t)(o0 + row) * C_ + k0 + off],            &u.st[buf][0][0][(w * 16) * 32]);
        GLOAD16(&A[(size_t)(o0 + 64 + row) * C_ + k0 + off],       &u.st[buf][0][0][(64 + w * 16) * 32]);
        GLOAD16(&A[(size_t)(o0 + row) * C_ + k0 + 32 + off],       &u.st[buf][0][1][(w * 16) * 32]);
        GLOAD16(&A[(size_t)(o0 + 64 + row) * C_ + k0 + 32 + off],  &u.st[buf][0][1][(64 + w * 16) * 32]);
        GLOAD16(&Bt[(size_t)(n0 + row) * C_ + k0 + off],           &u.st[buf][1][0][(w * 16) * 32]);
        GLOAD16(&Bt[(size_t)(n0 + 64 + row) * C_ + k0 + off],      &u.st[buf][1][0][(64 + w * 16) * 32]);
        GLOAD16(&Bt[(size_t)(n0 + row) * C_ + k0 + 32 + off],      &u.st[buf][1][1][(w * 16) * 32]);
        GLOAD16(&Bt[(size_t)(n0 + 64 + row) * C_ + k0 + 32 + off], &u.st[buf][1][1][(64 + w * 16) * 32]);
    };

    f32x4 acc[4][4] = {};
    stage(0, 0);
    for (int kt = 0; kt < 16; ++kt) {
        const int cur = kt & 1;
        __syncthreads();
        if (kt < 15) stage(cur ^ 1, (kt + 1) * 64);
#pragma unroll
        for (int ks = 0; ks < 2; ++ks) {
            short8 a[4], b[4];
#pragma unroll
            for (int mi = 0; mi < 4; ++mi)
                a[mi] = *(const short8*)&u.st[cur][0][ks][(wm + mi * 16 + l15) * 32 + q8];
#pragma unroll
            for (int ni = 0; ni < 4; ++ni)
                b[ni] = *(const short8*)&u.st[cur][1][ks][(wn + ni * 16 + l15) * 32 + q8];
#pragma unroll
            for (int mi = 0; mi < 4; ++mi)
#pragma unroll
                for (int ni = 0; ni < 4; ++ni)
                    acc[mi][ni] = MFMA(a[mi], b[ni], acc[mi][ni]);
        }
    }

    __syncthreads();
    const int lbase = n0 & (L_ - 1);
#pragma unroll
    for (int mi = 0; mi < 4; ++mi)
#pragma unroll
        for (int r = 0; r < 4; ++r) {
            const int row = wm + mi * 16 + q4 + r;
            const float bv = biass[row];
#pragma unroll
            for (int ni = 0; ni < 4; ++ni) {
                const int col = wn + ni * 16 + l15;
                float v = acc[mi][ni][r] + bv;
                if (relu) v = fmaxf(v, 0.f);
                const size_t gidx = ((size_t)b_ * C_ + o0 + row) * L_ + lbase + col;
                float a0v = 0.f;
                if (add0) { a0v = add0[gidx]; v += a0v; }
                if (outT) u.Cs[col * 136 + row] = f2b(v);
                if (add1) v += (add1 == add0) ? a0v : add1[gidx];
                if (outf) outf[gidx] = v;
            }
        }

    if (outT) {
        __syncthreads();
#pragma unroll
        for (int p = 0; p < 8; ++p) {
            int E = p * 256 + t;
            int lr = E >> 4, g = E & 15;
            short8 val = *(const short8*)&u.Cs[lr * 136 + g * 8];
            *(short8*)(outT + (size_t)(n0 + lr) * C_ + o0 + g * 8) = val;
        }
    }
}

// ---------------------------------------------------------------------------
extern "C" void kernel_launch(void* const* d_in, const int* in_sizes, int n_in,
                              void* d_out, int out_size, void* d_ws, size_t ws_size,
                              hipStream_t stream) {
    const float* x   = (const float*)d_in[0];
    const float* kw  = (const float*)d_in[1];
    const float* kb  = (const float*)d_in[2];
    const float* qw  = (const float*)d_in[3];
    const float* qb  = (const float*)d_in[4];
    const float* pw  = (const float*)d_in[5];
    const float* pb  = (const float*)d_in[6];
    const float* c1w = (const float*)d_in[7];
    const float* c1b = (const float*)d_in[8];
    const float* c2w = (const float*)d_in[9];
    const float* c2b = (const float*)d_in[10];
    float* out = (float*)d_out;

    char* p = (char*)d_ws;
    auto carve = [&](size_t bytes) { char* r = p; p += (bytes + 255) & ~(size_t)255; return r; };
    const size_t WN = (size_t)C_ * C_;
    const size_t S  = (size_t)B_ * C_ * L_;
    unsigned short* wb    = (unsigned short*)carve(4 * WN * 2);  // kw,pw,c1w,c2w
    unsigned short* kwb   = wb;
    unsigned short* pwb   = wb + WN;
    unsigned short* c1wb  = wb + 2 * WN;
    unsigned short* c2wb  = wb + 3 * WN;
    unsigned short* qwT   = (unsigned short*)carve(WN * 2);
    unsigned short* xN    = (unsigned short*)carve(S * 2);
    unsigned short* xT    = (unsigned short*)carve(S * 2);
    float*          X1    = (float*)carve((size_t)B_ * C_ * 4);
    unsigned short* G     = (unsigned short*)carve((size_t)B_ * WN * 2);
    unsigned short* BallT = (unsigned short*)carve((size_t)B_ * WN * 2);
    float*          cvec  = (float*)carve((size_t)B_ * C_ * 4);
    unsigned short* Wy    = (unsigned short*)carve((size_t)B_ * WN * 2);
    float*          dvec  = (float*)carve((size_t)B_ * C_ * 4);
    unsigned short* yT    = (unsigned short*)carve(S * 2);
    unsigned short* rT    = (unsigned short*)carve(S * 2);
    float*          ybuf2 = (float*)carve(S * 4);   // holds y + x

    Ptr4 wsrc; wsrc.p[0] = kw; wsrc.p[1] = pw; wsrc.p[2] = c1w; wsrc.p[3] = c2w;
    wprep<<<4096 + 256, 256, 0, stream>>>(wsrc, wb, qw, qwT, X1);
    prep_x<<<dim3(L_ / 64, C_ / 64, B_), 256, 0, stream>>>(x, xN, xT, X1);

    gram64<<<dim3(C_ / 64, C_ / 64, B_), 256, 0, stream>>>(xN, G);
    mid_ab<<<BH_, 256, 0, stream>>>(G, kwb, qwT, X1, kb, qb, BallT, cvec);
    wy64<<<dim3(C_ / 64, C_ / 64, B_), 256, 0, stream>>>(pwb, BallT, Wy);
    gemv_dvec<<<dim3(8, B_), 256, 0, stream>>>(pwb, cvec, pb, dvec);

    dim3 gG(N_ / 128, C_ / 128);     // 32 x 8 = 256 blocks = 1/CU
    // y = Wy·x + dvec + x ; yT = bf16(y) ; ybuf2 = y + x (x loaded once)
    gemm128<<<gG, 256, 0, stream>>>(Wy, WN, dvec, C_, xT, x, x, ybuf2, yT, 0);
    // r = relu(c1·y + c1b)
    gemm128<<<gG, 256, 0, stream>>>(c1wb, 0, c1b, 0, yT, nullptr, nullptr, nullptr, rT, 1);
    // out = c2·r + c2b + (y + x)
    gemm128<<<gG, 256, 0, stream>>>(c2wb, 0, c2b, 0, rT, ybuf2, nullptr, out, nullptr, 0);
}

// Round 2
// 255.234 us; speedup vs baseline: 1.1090x; 1.1090x over previous
//
#include <hip/hip_runtime.h>

#define B_   2
#define C_   1024
#define L_   2048
#define H_   16
#define HD_  64
#define BH_  (B_*H_)
#define N_   (B_*L_)
#define SCALE_ (1.0f/(1024.0f*2048.0f))

typedef __attribute__((ext_vector_type(8))) short short8;
typedef __attribute__((ext_vector_type(4))) short bs4;
typedef __attribute__((ext_vector_type(4))) float f32x4;

#define MFMA(a,b,c) __builtin_amdgcn_mfma_f32_16x16x32_bf16((a),(b),(c),0,0,0)

#define GLOAD16(gp, lp) \
  __builtin_amdgcn_global_load_lds( \
      (const __attribute__((address_space(1))) void*)(gp), \
      (__attribute__((address_space(3))) void*)(lp), 16, 0, 0)

__device__ __forceinline__ unsigned short f2b(float f) {
    union { float f; unsigned u; } v; v.f = f;
    unsigned r = (v.u + 0x7fffu + ((v.u >> 16) & 1u)) >> 16;
    return (unsigned short)r;
}
__device__ __forceinline__ bs4 pack4(f32x4 e) {
    union { f32x4 v; unsigned u[4]; } a; a.v = e;
    union { bs4 s; unsigned u[2]; } r;
    r.u[0] = __builtin_amdgcn_perm(a.u[1] + 0x8000u, a.u[0] + 0x8000u, 0x07060302u);
    r.u[1] = __builtin_amdgcn_perm(a.u[3] + 0x8000u, a.u[2] + 0x8000u, 0x07060302u);
    return r.s;
}
__device__ __forceinline__ float b2f(unsigned short s) {
    union { unsigned u; float f; } v; v.u = ((unsigned)s) << 16; return v.f;
}

// ---------------------------------------------------------------------------
// wprep: blocks 0..4095 convert kw/pw/c1w/c2w fp32->bf16;
//        blocks 4096..4351 transpose qw -> qwT bf16 (block 4096 also zeros X1)
// ---------------------------------------------------------------------------
struct Ptr4 { const float* p[4]; };
__global__ __launch_bounds__(256) void wprep(
    Ptr4 src, unsigned short* __restrict__ dst,
    const float* __restrict__ qw, unsigned short* __restrict__ qwT,
    float* __restrict__ X1)
{
    const int bx = blockIdx.x, t = threadIdx.x;
    if (bx < 4096) {
        const float* s = src.p[bx >> 10];
        unsigned short* d = dst + (size_t)(bx >> 10) * ((size_t)C_ * C_);
        int i = (((bx & 1023) * 256) + t) * 4;
        float4 v = *(const float4*)(s + i);
        ushort4 o;
        o.x = f2b(v.x); o.y = f2b(v.y); o.z = f2b(v.z); o.w = f2b(v.w);
        *(ushort4*)(d + i) = o;
        return;
    }
    const int tb = bx - 4096;
    if (tb == 0) {
        ((float4*)X1)[t] = float4{0.f, 0.f, 0.f, 0.f};
        ((float4*)X1)[256 + t] = float4{0.f, 0.f, 0.f, 0.f};
    }
    const int d0 = (tb >> 4) * 64, c0 = (tb & 15) * 64;
    __shared__ float T[64][65];
    const int tr = t >> 6, tc = t & 63;
#pragma unroll
    for (int r = 0; r < 16; ++r)
        T[r * 4 + tr][tc] = qw[(size_t)(d0 + r * 4 + tr) * C_ + c0 + tc];
    __syncthreads();
#pragma unroll
    for (int r = 0; r < 16; ++r) {
        int cc = r * 4 + tr;
        qwT[(size_t)(c0 + cc) * C_ + d0 + tc] = f2b(T[tc][cc]);
    }
}

// x f32 [b][c][l] -> xN bf16 [b][c][l], xT bf16 [b*2048+l][c], X1[b][c]=sum_l x
__global__ __launch_bounds__(256) void prep_x(
    const float* __restrict__ x, unsigned short* __restrict__ xN,
    unsigned short* __restrict__ xT, float* __restrict__ X1)
{
    int b = blockIdx.z, c0 = blockIdx.y * 64, l0 = blockIdx.x * 64;
    __shared__ float T[64][65];
    const float* xb = x + (size_t)b * C_ * L_;
    int tc = threadIdx.x >> 6;
    int tl = threadIdx.x & 63;
#pragma unroll
    for (int r = 0; r < 16; ++r) {
        int c = c0 + r * 4 + tc;
        float v = xb[(size_t)c * L_ + l0 + tl];
        T[r * 4 + tc][tl] = v;
        xN[((size_t)b * C_ + c) * L_ + l0 + tl] = f2b(v);
        float s = v;
#pragma unroll
        for (int d = 1; d < 64; d <<= 1) s += __shfl_xor(s, d);
        if (tl == 0) atomicAdd(&X1[b * C_ + c], s);
    }
    __syncthreads();
#pragma unroll
    for (int r = 0; r < 16; ++r) {
        int lr = r * 4 + tc;
        xT[((size_t)b * L_ + l0 + lr) * C_ + c0 + tl] = f2b(T[tl][lr]);
    }
}

// ---------------------------------------------------------------------------
// gram64: G[b][c1][c2] = sum_l xN[b,c1,l]*xN[b,c2,l]. 64x64, BK=64, dbuf.
// grid (16,16,B) = 512 blocks.
// ---------------------------------------------------------------------------
__global__ __launch_bounds__(256) void gram64(
    const unsigned short* __restrict__ xN, unsigned short* __restrict__ G)
{
    const int t = threadIdx.x, w = t >> 6, lane = t & 63;
    const int b = blockIdx.z;
    const int c10 = blockIdx.y * 64, c20 = blockIdx.x * 64;
    const int l15 = lane & 15, q8 = (lane >> 4) * 8, q4 = (lane >> 4) * 4;
    const int wm = (w >> 1) * 32, wn = (w & 1) * 32;
    const unsigned short* xb = xN + (size_t)b * C_ * L_;

    __shared__ union {
        __align__(16) unsigned short st[2][2][2][64 * 32]; // [buf][A/B][ks]
        __align__(16) unsigned short Cs[64 * 72];
    } u;

    auto stage = [&](int buf, int k0) {
        int row = t >> 2, off = (t & 3) * 8;
        GLOAD16(&xb[(size_t)(c10 + row) * L_ + k0 + off],      &u.st[buf][0][0][(w * 64) * 8]);
        GLOAD16(&xb[(size_t)(c10 + row) * L_ + k0 + 32 + off], &u.st[buf][0][1][(w * 64) * 8]);
        GLOAD16(&xb[(size_t)(c20 + row) * L_ + k0 + off],      &u.st[buf][1][0][(w * 64) * 8]);
        GLOAD16(&xb[(size_t)(c20 + row) * L_ + k0 + 32 + off], &u.st[buf][1][1][(w * 64) * 8]);
    };

    f32x4 acc[2][2] = {};
    stage(0, 0);
    for (int kt = 0; kt < 32; ++kt) {
        const int cur = kt & 1;
        __syncthreads();
        if (kt < 31) stage(cur ^ 1, (kt + 1) * 64);
#pragma unroll
        for (int ks = 0; ks < 2; ++ks) {
            short8 a[2], bf[2];
#pragma unroll
            for (int mi = 0; mi < 2; ++mi)
                a[mi] = *(const short8*)&u.st[cur][0][ks][(wm + mi * 16 + l15) * 32 + q8];
#pragma unroll
            for (int ni = 0; ni < 2; ++ni)
                bf[ni] = *(const short8*)&u.st[cur][1][ks][(wn + ni * 16 + l15) * 32 + q8];
#pragma unroll
            for (int mi = 0; mi < 2; ++mi)
#pragma unroll
                for (int ni = 0; ni < 2; ++ni)
                    acc[mi][ni] = MFMA(a[mi], bf[ni], acc[mi][ni]);
        }
    }

    __syncthreads();
#pragma unroll
    for (int mi = 0; mi < 2; ++mi)
#pragma unroll
        for (int r = 0; r < 4; ++r)
#pragma unroll
            for (int ni = 0; ni < 2; ++ni)
                u.Cs[(wm + mi * 16 + q4 + r) * 72 + wn + ni * 16 + l15] =
                    f2b(acc[mi][ni][r]);
    __syncthreads();
#pragma unroll
    for (int p = 0; p < 2; ++p) {
        int E = p * 256 + t;
        int row = E >> 3, seg = E & 7;
        short8 val = *(const short8*)&u.Cs[row * 72 + seg * 8];
        *(short8*)&G[((size_t)b * C_ + c10 + row) * C_ + c20 + seg * 8] = val;
    }
}

// ---------------------------------------------------------------------------
// mid_ab (grid 32 = bh):
//  ph1: A_h[c,d] = sum_cc G[b][h*64+c][cc]*kw[h*64+d][cc] + X1[c]*kb[d] -> LDS
//       cvec[b][h*64+c] = X1[c]/2048 + (A_h·qb)[c]*SCALE_
//  ph2: BallT[b][cc][h*64+c] = sum_d A_h[c,d]*qwT[cc][h*64+d]
// ---------------------------------------------------------------------------
__global__ __launch_bounds__(256) void mid_ab(
    const unsigned short* __restrict__ G, const unsigned short* __restrict__ kwb,
    const unsigned short* __restrict__ qwT,
    const float* __restrict__ X1, const float* __restrict__ kb,
    const float* __restrict__ qb,
    unsigned short* __restrict__ BallT, float* __restrict__ cvec)
{
    const int t = threadIdx.x, w = t >> 6, lane = t & 63;
    const int bh = blockIdx.x, b = bh >> 4, h = bh & 15;
    const int l15 = lane & 15, q8 = (lane >> 4) * 8, q4 = (lane >> 4) * 4;

    __shared__ union {
        struct { __align__(16) unsigned short Gs[2][64 * 32];
                 __align__(16) unsigned short Ks[2][64 * 32]; } st;
        __align__(16) unsigned short As[64 * 72];
    } u;

    const unsigned short* gb  = G   + ((size_t)b * C_ + h * 64) * C_;
    const unsigned short* kwh = kwb + (size_t)h * 64 * C_;

    auto stage = [&](int buf, int k0) {
        int row = t >> 2, off = (t & 3) * 8;
        GLOAD16(&gb[(size_t)row * C_ + k0 + off], &u.st.Gs[buf][(w * 64) * 8]);
        GLOAD16(&kwh[(size_t)row * C_ + k0 + off], &u.st.Ks[buf][(w * 64) * 8]);
    };

    f32x4 acc[4] = {};
    stage(0, 0);
    for (int kt = 0; kt < 32; ++kt) {
        const int cur = kt & 1;
        __syncthreads();
        if (kt < 31) stage(cur ^ 1, (kt + 1) * 32);
        short8 a = *(const short8*)&u.st.Gs[cur][(w * 16 + l15) * 32 + q8];
#pragma unroll
        for (int ni = 0; ni < 4; ++ni) {
            short8 bf = *(const short8*)&u.st.Ks[cur][(ni * 16 + l15) * 32 + q8];
            acc[ni] = MFMA(a, bf, acc[ni]);
        }
    }
    __syncthreads();

    float x1r[4];
#pragma unroll
    for (int r = 0; r < 4; ++r)
        x1r[r] = X1[b * C_ + h * 64 + w * 16 + q4 + r];
    float ch[4] = {0.f, 0.f, 0.f, 0.f};
#pragma unroll
    for (int ni = 0; ni < 4; ++ni) {
        const int d = ni * 16 + l15;
        const float kbd = kb[h * 64 + d], qbd = qb[h * 64 + d];
#pragma unroll
        for (int r = 0; r < 4; ++r) {
            const int c = w * 16 + q4 + r;
            float a = acc[ni][r] + x1r[r] * kbd;
            u.As[c * 72 + d] = f2b(a);
            ch[r] += a * qbd;
        }
    }
#pragma unroll
    for (int r = 0; r < 4; ++r) {
#pragma unroll
        for (int dd = 1; dd < 16; dd <<= 1) ch[r] += __shfl_xor(ch[r], dd);
        if (l15 == 0)
            cvec[b * C_ + h * 64 + w * 16 + q4 + r] =
                x1r[r] * (1.0f / L_) + ch[r] * SCALE_;
    }
    __syncthreads();

#pragma unroll
    for (int i = 0; i < 4; ++i) {
        const int cc0 = (i * 4 + w) * 64;
        f32x4 ac[4][4] = {};
#pragma unroll
        for (int ks = 0; ks < 2; ++ks) {
            short8 af[4], bf[4];
#pragma unroll
            for (int mi = 0; mi < 4; ++mi)
                af[mi] = *(const short8*)&u.As[(mi * 16 + l15) * 72 + ks * 32 + q8];
#pragma unroll
            for (int ni = 0; ni < 4; ++ni)
                bf[ni] = *(const short8*)&qwT[(size_t)(cc0 + ni * 16 + l15) * C_
                                              + h * 64 + ks * 32 + q8];
#pragma unroll
            for (int mi = 0; mi < 4; ++mi)
#pragma unroll
                for (int ni = 0; ni < 4; ++ni)
                    ac[mi][ni] = MFMA(af[mi], bf[ni], ac[mi][ni]);
        }
#pragma unroll
        for (int ni = 0; ni < 4; ++ni)
#pragma unroll
            for (int mi = 0; mi < 4; ++mi) {
                bs4 o = pack4(ac[mi][ni]);
                *(bs4*)&BallT[((size_t)b * C_ + cc0 + ni * 16 + l15) * C_
                              + h * 64 + mi * 16 + q4] = o;
            }
    }
}

// ---------------------------------------------------------------------------
// wy64: Wy[b][o][cc] = SCALE_ * sum_c pw[o,c]*BallT[b][cc][c]. 64x64 BK=64 dbuf.
// ---------------------------------------------------------------------------
__global__ __launch_bounds__(256) void wy64(
    const unsigned short* __restrict__ pwb, const unsigned short* __restrict__ BallT,
    unsigned short* __restrict__ Wy)
{
    const int t = threadIdx.x, w = t >> 6, lane = t & 63;
    const int b = blockIdx.z;
    const int o0 = blockIdx.y * 64, cc0 = blockIdx.x * 64;
    const int l15 = lane & 15, q8 = (lane >> 4) * 8, q4 = (lane >> 4) * 4;
    const int wm = (w >> 1) * 32, wn = (w & 1) * 32;
    const unsigned short* Bb = BallT + (size_t)b * C_ * C_;

    __shared__ union {
        __align__(16) unsigned short st[2][2][2][64 * 32];
        __align__(16) unsigned short Cs[64 * 72];
    } u;

    auto stage = [&](int buf, int k0) {
        int row = t >> 2, off = (t & 3) * 8;
        GLOAD16(&pwb[(size_t)(o0 + row) * C_ + k0 + off],      &u.st[buf][0][0][(w * 64) * 8]);
        GLOAD16(&pwb[(size_t)(o0 + row) * C_ + k0 + 32 + off], &u.st[buf][0][1][(w * 64) * 8]);
        GLOAD16(&Bb[(size_t)(cc0 + row) * C_ + k0 + off],      &u.st[buf][1][0][(w * 64) * 8]);
        GLOAD16(&Bb[(size_t)(cc0 + row) * C_ + k0 + 32 + off], &u.st[buf][1][1][(w * 64) * 8]);
    };

    f32x4 acc[2][2] = {};
    stage(0, 0);
    for (int kt = 0; kt < 16; ++kt) {
        const int cur = kt & 1;
        __syncthreads();
        if (kt < 15) stage(cur ^ 1, (kt + 1) * 64);
#pragma unroll
        for (int ks = 0; ks < 2; ++ks) {
            short8 a[2], bf[2];
#pragma unroll
            for (int mi = 0; mi < 2; ++mi)
                a[mi] = *(const short8*)&u.st[cur][0][ks][(wm + mi * 16 + l15) * 32 + q8];
#pragma unroll
            for (int ni = 0; ni < 2; ++ni)
                bf[ni] = *(const short8*)&u.st[cur][1][ks][(wn + ni * 16 + l15) * 32 + q8];
#pragma unroll
            for (int mi = 0; mi < 2; ++mi)
#pragma unroll
                for (int ni = 0; ni < 2; ++ni)
                    acc[mi][ni] = MFMA(a[mi], bf[ni], acc[mi][ni]);
        }
    }

    __syncthreads();
#pragma unroll
    for (int mi = 0; mi < 2; ++mi)
#pragma unroll
        for (int r = 0; r < 4; ++r)
#pragma unroll
            for (int ni = 0; ni < 2; ++ni)
                u.Cs[(wm + mi * 16 + q4 + r) * 72 + wn + ni * 16 + l15] =
                    f2b(acc[mi][ni][r] * SCALE_);
    __syncthreads();
#pragma unroll
    for (int p = 0; p < 2; ++p) {
        int E = p * 256 + t;
        int row = E >> 3, seg = E & 7;
        short8 val = *(const short8*)&u.Cs[row * 72 + seg * 8];
        *(short8*)&Wy[((size_t)b * C_ + o0 + row) * C_ + cc0 + seg * 8] = val;
    }
}

// dvec[b][o] = sum_c pwb[o,c]*cvec[b,c] + pb[o]
__global__ __launch_bounds__(256) void gemv_dvec(
    const unsigned short* __restrict__ pwb, const float* __restrict__ cvec,
    const float* __restrict__ pb, float* __restrict__ dvec)
{
    const int t = threadIdx.x, b = blockIdx.y;
    const int o = blockIdx.x * 128 + (t >> 1), part = t & 1;
    __shared__ float cv[1024];
#pragma unroll
    for (int i = 0; i < 4; ++i) cv[t + i * 256] = cvec[b * C_ + t + i * 256];
    __syncthreads();
    const int base = part * 512;
    float acc = 0.f;
#pragma unroll 8
    for (int j = 0; j < 64; ++j) {
        short8 w8 = *(const short8*)&pwb[(size_t)o * C_ + base + j * 8];
#pragma unroll
        for (int e = 0; e < 8; ++e)
            acc = fmaf(b2f((unsigned short)w8[e]), cv[base + j * 8 + e], acc);
    }
    acc += __shfl_xor(acc, 1);
    if (part == 0) dvec[b * C_ + o] = acc + pb[o];
}

// ---------------------------------------------------------------------------
// gemm64x128: out[o][n] = sum_k A[o][k]*Bt[n][k] (+bias/relu/residuals)
// Tile 64(M=o) x 128(N=n), BK=64, dbuf, GLOAD16.
// 4 waves in 2x2: each wave owns 32x64 (acc[2][4]); 16 MFMA / 12 ds_read per
// K-step per wave. Grid (N/128, C/64) = 32x16 = 512 blocks = 2 blocks/CU
// (inter-block overlap hides the vmcnt(0)+barrier drain; 128^2 tile at
// 1 block/CU measured 6.8% MfmaUtil — grid-starved).
// Epilogue order: v=acc+bias; relu; v+=add0; outT=f2b(v); v+=add1; outf=v.
// ---------------------------------------------------------------------------
__global__ __launch_bounds__(256) void gemm64x128(
    const unsigned short* __restrict__ A0, size_t abstride,
    const float* __restrict__ bias, int bstride,
    const unsigned short* __restrict__ Bt,
    const float* __restrict__ add0, const float* __restrict__ add1,
    float* __restrict__ outf, unsigned short* __restrict__ outT, int relu)
{
    const int t = threadIdx.x, w = t >> 6, lane = t & 63;
    const int o0 = blockIdx.y * 64, n0 = blockIdx.x * 128;
    const int b_ = n0 >> 11;
    const int l15 = lane & 15, q8 = (lane >> 4) * 8, q4 = (lane >> 4) * 4;
    const int wm = (w >> 1) * 32, wn = (w & 1) * 64;
    const unsigned short* A = A0 + (size_t)b_ * abstride;

    __shared__ union {
        struct {
            __align__(16) unsigned short sA[2][2][64 * 32];   // [buf][ks][row*32+k]
            __align__(16) unsigned short sB[2][2][128 * 32];
        } st;
        __align__(16) unsigned short Cs[128 * 72];            // [n][o] transpose buf
    } u;
    __shared__ float biass[64];
    if (t < 64) biass[t] = bias[b_ * bstride + o0 + t];

    auto stage = [&](int buf, int k0) {
        int row = t >> 2, off = (t & 3) * 8;
        // wave w writes rows w*16..w*16+15 (1 KB contiguous, wave-uniform base)
        GLOAD16(&A[(size_t)(o0 + row) * C_ + k0 + off],            &u.st.sA[buf][0][(w * 16) * 32]);
        GLOAD16(&A[(size_t)(o0 + row) * C_ + k0 + 32 + off],       &u.st.sA[buf][1][(w * 16) * 32]);
        GLOAD16(&Bt[(size_t)(n0 + row) * C_ + k0 + off],           &u.st.sB[buf][0][(w * 16) * 32]);
        GLOAD16(&Bt[(size_t)(n0 + row) * C_ + k0 + 32 + off],      &u.st.sB[buf][1][(w * 16) * 32]);
        GLOAD16(&Bt[(size_t)(n0 + 64 + row) * C_ + k0 + off],      &u.st.sB[buf][0][(64 + w * 16) * 32]);
        GLOAD16(&Bt[(size_t)(n0 + 64 + row) * C_ + k0 + 32 + off], &u.st.sB[buf][1][(64 + w * 16) * 32]);
    };

    f32x4 acc[2][4] = {};
    stage(0, 0);
    for (int kt = 0; kt < 16; ++kt) {
        const int cur = kt & 1;
        __syncthreads();
        if (kt < 15) stage(cur ^ 1, (kt + 1) * 64);
#pragma unroll
        for (int ks = 0; ks < 2; ++ks) {
            short8 a[2], b[4];
#pragma unroll
            for (int mi = 0; mi < 2; ++mi)
                a[mi] = *(const short8*)&u.st.sA[cur][ks][(wm + mi * 16 + l15) * 32 + q8];
#pragma unroll
            for (int ni = 0; ni < 4; ++ni)
                b[ni] = *(const short8*)&u.st.sB[cur][ks][(wn + ni * 16 + l15) * 32 + q8];
#pragma unroll
            for (int mi = 0; mi < 2; ++mi)
#pragma unroll
                for (int ni = 0; ni < 4; ++ni)
                    acc[mi][ni] = MFMA(a[mi], b[ni], acc[mi][ni]);
        }
    }

    __syncthreads();
    const int lbase = n0 & (L_ - 1);
#pragma unroll
    for (int mi = 0; mi < 2; ++mi)
#pragma unroll
        for (int r = 0; r < 4; ++r) {
            const int row = wm + mi * 16 + q4 + r;
            const float bv = biass[row];
#pragma unroll
            for (int ni = 0; ni < 4; ++ni) {
                const int col = wn + ni * 16 + l15;
                float v = acc[mi][ni][r] + bv;
                if (relu) v = fmaxf(v, 0.f);
                const size_t gidx = ((size_t)b_ * C_ + o0 + row) * L_ + lbase + col;
                float a0v = 0.f;
                if (add0) { a0v = add0[gidx]; v += a0v; }
                if (outT) u.Cs[col * 72 + row] = f2b(v);
                if (add1) v += (add1 == add0) ? a0v : add1[gidx];
                if (outf) outf[gidx] = v;
            }
        }

    if (outT) {
        __syncthreads();
#pragma unroll
        for (int p = 0; p < 4; ++p) {
            int E = p * 256 + t;           // 1024 short8 = 128 rows x 8 segs
            int lr = E >> 3, g = E & 7;
            short8 val = *(const short8*)&u.Cs[lr * 72 + g * 8];
            *(short8*)(outT + (size_t)(n0 + lr) * C_ + o0 + g * 8) = val;
        }
    }
}

// ---------------------------------------------------------------------------
extern "C" void kernel_launch(void* const* d_in, const int* in_sizes, int n_in,
                              void* d_out, int out_size, void* d_ws, size_t ws_size,
                              hipStream_t stream) {
    const float* x   = (const float*)d_in[0];
    const float* kw  = (const float*)d_in[1];
    const float* kb  = (const float*)d_in[2];
    const float* qw  = (const float*)d_in[3];
    const float* qb  = (const float*)d_in[4];
    const float* pw  = (const float*)d_in[5];
    const float* pb  = (const float*)d_in[6];
    const float* c1w = (const float*)d_in[7];
    const float* c1b = (const float*)d_in[8];
    const float* c2w = (const float*)d_in[9];
    const float* c2b = (const float*)d_in[10];
    float* out = (float*)d_out;

    char* p = (char*)d_ws;
    auto carve = [&](size_t bytes) { char* r = p; p += (bytes + 255) & ~(size_t)255; return r; };
    const size_t WN = (size_t)C_ * C_;
    const size_t S  = (size_t)B_ * C_ * L_;
    unsigned short* wb    = (unsigned short*)carve(4 * WN * 2);  // kw,pw,c1w,c2w
    unsigned short* kwb   = wb;
    unsigned short* pwb   = wb + WN;
    unsigned short* c1wb  = wb + 2 * WN;
    unsigned short* c2wb  = wb + 3 * WN;
    unsigned short* qwT   = (unsigned short*)carve(WN * 2);
    unsigned short* xN    = (unsigned short*)carve(S * 2);
    unsigned short* xT    = (unsigned short*)carve(S * 2);
    float*          X1    = (float*)carve((size_t)B_ * C_ * 4);
    unsigned short* G     = (unsigned short*)carve((size_t)B_ * WN * 2);
    unsigned short* BallT = (unsigned short*)carve((size_t)B_ * WN * 2);
    float*          cvec  = (float*)carve((size_t)B_ * C_ * 4);
    unsigned short* Wy    = (unsigned short*)carve((size_t)B_ * WN * 2);
    float*          dvec  = (float*)carve((size_t)B_ * C_ * 4);
    unsigned short* yT    = (unsigned short*)carve(S * 2);
    unsigned short* rT    = (unsigned short*)carve(S * 2);
    float*          ybuf2 = (float*)carve(S * 4);   // holds y + x

    Ptr4 wsrc; wsrc.p[0] = kw; wsrc.p[1] = pw; wsrc.p[2] = c1w; wsrc.p[3] = c2w;
    wprep<<<4096 + 256, 256, 0, stream>>>(wsrc, wb, qw, qwT, X1);
    prep_x<<<dim3(L_ / 64, C_ / 64, B_), 256, 0, stream>>>(x, xN, xT, X1);

    gram64<<<dim3(C_ / 64, C_ / 64, B_), 256, 0, stream>>>(xN, G);
    mid_ab<<<BH_, 256, 0, stream>>>(G, kwb, qwT, X1, kb, qb, BallT, cvec);
    wy64<<<dim3(C_ / 64, C_ / 64, B_), 256, 0, stream>>>(pwb, BallT, Wy);
    gemv_dvec<<<dim3(8, B_), 256, 0, stream>>>(pwb, cvec, pb, dvec);

    dim3 gG(N_ / 128, C_ / 64);      // 32 x 16 = 512 blocks = 2/CU
    // y = Wy·x + dvec + x ; yT = bf16(y) ; ybuf2 = y + x (x loaded once)
    gemm64x128<<<gG, 256, 0, stream>>>(Wy, WN, dvec, C_, xT, x, x, ybuf2, yT, 0);
    // r = relu(c1·y + c1b)
    gemm64x128<<<gG, 256, 0, stream>>>(c1wb, 0, c1b, 0, yT, nullptr, nullptr, nullptr, rT, 1);
    // out = c2·r + c2b + (y + x)
    gemm64x128<<<gG, 256, 0, stream>>>(c2wb, 0, c2b, 0, rT, ybuf2, nullptr, out, nullptr, 0);
}

// Round 5
// 241.079 us; speedup vs baseline: 1.1741x; 1.0587x over previous
//
#include <hip/hip_runtime.h>

#define B_   2
#define C_   1024
#define L_   2048
#define H_   16
#define HD_  64
#define BH_  (B_*H_)
#define N_   (B_*L_)
#define SCALE_ (1.0f/(1024.0f*2048.0f))

typedef __attribute__((ext_vector_type(8))) short short8;
typedef __attribute__((ext_vector_type(4))) short bs4;
typedef __attribute__((ext_vector_type(4))) float f32x4;

#define MFMA(a,b,c) __builtin_amdgcn_mfma_f32_16x16x32_bf16((a),(b),(c),0,0,0)

#define GLOAD16(gp, lp) \
  __builtin_amdgcn_global_load_lds( \
      (const __attribute__((address_space(1))) void*)(gp), \
      (__attribute__((address_space(3))) void*)(lp), 16, 0, 0)

__device__ __forceinline__ unsigned short f2b(float f) {
    union { float f; unsigned u; } v; v.f = f;
    unsigned r = (v.u + 0x7fffu + ((v.u >> 16) & 1u)) >> 16;
    return (unsigned short)r;
}
__device__ __forceinline__ bs4 pack4(f32x4 e) {
    union { f32x4 v; unsigned u[4]; } a; a.v = e;
    union { bs4 s; unsigned u[2]; } r;
    r.u[0] = __builtin_amdgcn_perm(a.u[1] + 0x8000u, a.u[0] + 0x8000u, 0x07060302u);
    r.u[1] = __builtin_amdgcn_perm(a.u[3] + 0x8000u, a.u[2] + 0x8000u, 0x07060302u);
    return r.s;
}
__device__ __forceinline__ float b2f(unsigned short s) {
    union { unsigned u; float f; } v; v.u = ((unsigned)s) << 16; return v.f;
}

// ---------------------------------------------------------------------------
// wprep: blocks 0..4095 convert kw/pw/c1w/c2w fp32->bf16;
//        blocks 4096..4351 transpose qw -> qwT bf16 (block 4096 also zeros X1)
// ---------------------------------------------------------------------------
struct Ptr4 { const float* p[4]; };
__global__ __launch_bounds__(256) void wprep(
    Ptr4 src, unsigned short* __restrict__ dst,
    const float* __restrict__ qw, unsigned short* __restrict__ qwT,
    float* __restrict__ X1)
{
    const int bx = blockIdx.x, t = threadIdx.x;
    if (bx < 4096) {
        const float* s = src.p[bx >> 10];
        unsigned short* d = dst + (size_t)(bx >> 10) * ((size_t)C_ * C_);
        int i = (((bx & 1023) * 256) + t) * 4;
        float4 v = *(const float4*)(s + i);
        ushort4 o;
        o.x = f2b(v.x); o.y = f2b(v.y); o.z = f2b(v.z); o.w = f2b(v.w);
        *(ushort4*)(d + i) = o;
        return;
    }
    const int tb = bx - 4096;
    if (tb == 0) {
        ((float4*)X1)[t] = float4{0.f, 0.f, 0.f, 0.f};
        ((float4*)X1)[256 + t] = float4{0.f, 0.f, 0.f, 0.f};
    }
    const int d0 = (tb >> 4) * 64, c0 = (tb & 15) * 64;
    __shared__ float T[64][65];
    const int tr = t >> 6, tc = t & 63;
#pragma unroll
    for (int r = 0; r < 16; ++r)
        T[r * 4 + tr][tc] = qw[(size_t)(d0 + r * 4 + tr) * C_ + c0 + tc];
    __syncthreads();
#pragma unroll
    for (int r = 0; r < 16; ++r) {
        int cc = r * 4 + tr;
        qwT[(size_t)(c0 + cc) * C_ + d0 + tc] = f2b(T[tc][cc]);
    }
}

// x f32 [b][c][l] -> xN bf16 [b][c][l], xT bf16 [b*2048+l][c], X1[b][c]=sum_l x
__global__ __launch_bounds__(256) void prep_x(
    const float* __restrict__ x, unsigned short* __restrict__ xN,
    unsigned short* __restrict__ xT, float* __restrict__ X1)
{
    int b = blockIdx.z, c0 = blockIdx.y * 64, l0 = blockIdx.x * 64;
    __shared__ float T[64][65];
    const float* xb = x + (size_t)b * C_ * L_;
    int tc = threadIdx.x >> 6;
    int tl = threadIdx.x & 63;
#pragma unroll
    for (int r = 0; r < 16; ++r) {
        int c = c0 + r * 4 + tc;
        float v = xb[(size_t)c * L_ + l0 + tl];
        T[r * 4 + tc][tl] = v;
        xN[((size_t)b * C_ + c) * L_ + l0 + tl] = f2b(v);
        float s = v;
#pragma unroll
        for (int d = 1; d < 64; d <<= 1) s += __shfl_xor(s, d);
        if (tl == 0) atomicAdd(&X1[b * C_ + c], s);
    }
    __syncthreads();
#pragma unroll
    for (int r = 0; r < 16; ++r) {
        int lr = r * 4 + tc;
        xT[((size_t)b * L_ + l0 + lr) * C_ + c0 + tl] = f2b(T[tl][lr]);
    }
}

// ---------------------------------------------------------------------------
// gram64sym: G[b][c1][c2] = sum_l xN[b,c1,l]*xN[b,c2,l].  G is SYMMETRIC:
// only the 136 lower-triangle 64x64 tile-pairs (i>=j) are computed
// (grid (136,B) = 272 blocks vs 512); off-diagonal blocks are emitted twice
// (direct + transposed restage through LDS). 64x64 tile, BK=64, dbuf.
// ---------------------------------------------------------------------------
__global__ __launch_bounds__(256) void gram64sym(
    const unsigned short* __restrict__ xN, unsigned short* __restrict__ G)
{
    const int t = threadIdx.x, w = t >> 6, lane = t & 63;
    const int b = blockIdx.y;
    // decode pair index -> (i,j), i>=j
    int p = blockIdx.x, i = 0;
    while (p > i) { p -= i + 1; ++i; }
    const int c10 = i * 64, c20 = p * 64;
    const int l15 = lane & 15, q8 = (lane >> 4) * 8, q4 = (lane >> 4) * 4;
    const int wm = (w >> 1) * 32, wn = (w & 1) * 32;
    const unsigned short* xb = xN + (size_t)b * C_ * L_;

    __shared__ union {
        __align__(16) unsigned short st[2][2][2][64 * 32]; // [buf][A/B][ks]
        __align__(16) unsigned short Cs[64 * 72];
    } u;

    auto stage = [&](int buf, int k0) {
        int row = t >> 2, off = (t & 3) * 8;
        GLOAD16(&xb[(size_t)(c10 + row) * L_ + k0 + off],      &u.st[buf][0][0][(w * 64) * 8]);
        GLOAD16(&xb[(size_t)(c10 + row) * L_ + k0 + 32 + off], &u.st[buf][0][1][(w * 64) * 8]);
        GLOAD16(&xb[(size_t)(c20 + row) * L_ + k0 + off],      &u.st[buf][1][0][(w * 64) * 8]);
        GLOAD16(&xb[(size_t)(c20 + row) * L_ + k0 + 32 + off], &u.st[buf][1][1][(w * 64) * 8]);
    };

    f32x4 acc[2][2] = {};
    stage(0, 0);
    for (int kt = 0; kt < 32; ++kt) {
        const int cur = kt & 1;
        __syncthreads();
        if (kt < 31) stage(cur ^ 1, (kt + 1) * 64);
#pragma unroll
        for (int ks = 0; ks < 2; ++ks) {
            short8 a[2], bf[2];
#pragma unroll
            for (int mi = 0; mi < 2; ++mi)
                a[mi] = *(const short8*)&u.st[cur][0][ks][(wm + mi * 16 + l15) * 32 + q8];
#pragma unroll
            for (int ni = 0; ni < 2; ++ni)
                bf[ni] = *(const short8*)&u.st[cur][1][ks][(wn + ni * 16 + l15) * 32 + q8];
#pragma unroll
            for (int mi = 0; mi < 2; ++mi)
#pragma unroll
                for (int ni = 0; ni < 2; ++ni)
                    acc[mi][ni] = MFMA(a[mi], bf[ni], acc[mi][ni]);
        }
    }

    // ---- direct block: Cs[row(c1)][col(c2)] -> G[c10+row][c20+col] ----
    __syncthreads();
#pragma unroll
    for (int mi = 0; mi < 2; ++mi)
#pragma unroll
        for (int r = 0; r < 4; ++r)
#pragma unroll
            for (int ni = 0; ni < 2; ++ni)
                u.Cs[(wm + mi * 16 + q4 + r) * 72 + wn + ni * 16 + l15] =
                    f2b(acc[mi][ni][r]);
    __syncthreads();
#pragma unroll
    for (int pp = 0; pp < 2; ++pp) {
        int E = pp * 256 + t;
        int row = E >> 3, seg = E & 7;
        short8 val = *(const short8*)&u.Cs[row * 72 + seg * 8];
        *(short8*)&G[((size_t)b * C_ + c10 + row) * C_ + c20 + seg * 8] = val;
    }

    if (c10 != c20) {
        // ---- transposed block: CsT[col(c2)][row(c1)] -> G[c20+col][c10+row]
        __syncthreads();
#pragma unroll
        for (int mi = 0; mi < 2; ++mi)
#pragma unroll
            for (int r = 0; r < 4; ++r)
#pragma unroll
                for (int ni = 0; ni < 2; ++ni)
                    u.Cs[(wn + ni * 16 + l15) * 72 + wm + mi * 16 + q4 + r] =
                        f2b(acc[mi][ni][r]);
        __syncthreads();
#pragma unroll
        for (int pp = 0; pp < 2; ++pp) {
            int E = pp * 256 + t;
            int row = E >> 3, seg = E & 7;
            short8 val = *(const short8*)&u.Cs[row * 72 + seg * 8];
            *(short8*)&G[((size_t)b * C_ + c20 + row) * C_ + c10 + seg * 8] = val;
        }
    }
}

// ---------------------------------------------------------------------------
// mid_ab (grid 32 = bh):
//  ph1: A_h[c,d] = sum_cc G[b][h*64+c][cc]*kw[h*64+d][cc] + X1[c]*kb[d] -> LDS
//       cvec[b][h*64+c] = X1[c]/2048 + (A_h·qb)[c]*SCALE_
//  ph2: BallT[b][cc][h*64+c] = sum_d A_h[c,d]*qwT[cc][h*64+d]
// ---------------------------------------------------------------------------
__global__ __launch_bounds__(256) void mid_ab(
    const unsigned short* __restrict__ G, const unsigned short* __restrict__ kwb,
    const unsigned short* __restrict__ qwT,
    const float* __restrict__ X1, const float* __restrict__ kb,
    const float* __restrict__ qb,
    unsigned short* __restrict__ BallT, float* __restrict__ cvec)
{
    const int t = threadIdx.x, w = t >> 6, lane = t & 63;
    const int bh = blockIdx.x, b = bh >> 4, h = bh & 15;
    const int l15 = lane & 15, q8 = (lane >> 4) * 8, q4 = (lane >> 4) * 4;

    __shared__ union {
        struct { __align__(16) unsigned short Gs[2][64 * 32];
                 __align__(16) unsigned short Ks[2][64 * 32]; } st;
        __align__(16) unsigned short As[64 * 72];
    } u;

    const unsigned short* gb  = G   + ((size_t)b * C_ + h * 64) * C_;
    const unsigned short* kwh = kwb + (size_t)h * 64 * C_;

    auto stage = [&](int buf, int k0) {
        int row = t >> 2, off = (t & 3) * 8;
        GLOAD16(&gb[(size_t)row * C_ + k0 + off], &u.st.Gs[buf][(w * 64) * 8]);
        GLOAD16(&kwh[(size_t)row * C_ + k0 + off], &u.st.Ks[buf][(w * 64) * 8]);
    };

    f32x4 acc[4] = {};
    stage(0, 0);
    for (int kt = 0; kt < 32; ++kt) {
        const int cur = kt & 1;
        __syncthreads();
        if (kt < 31) stage(cur ^ 1, (kt + 1) * 32);
        short8 a = *(const short8*)&u.st.Gs[cur][(w * 16 + l15) * 32 + q8];
#pragma unroll
        for (int ni = 0; ni < 4; ++ni) {
            short8 bf = *(const short8*)&u.st.Ks[cur][(ni * 16 + l15) * 32 + q8];
            acc[ni] = MFMA(a, bf, acc[ni]);
        }
    }
    __syncthreads();

    float x1r[4];
#pragma unroll
    for (int r = 0; r < 4; ++r)
        x1r[r] = X1[b * C_ + h * 64 + w * 16 + q4 + r];
    float ch[4] = {0.f, 0.f, 0.f, 0.f};
#pragma unroll
    for (int ni = 0; ni < 4; ++ni) {
        const int d = ni * 16 + l15;
        const float kbd = kb[h * 64 + d], qbd = qb[h * 64 + d];
#pragma unroll
        for (int r = 0; r < 4; ++r) {
            const int c = w * 16 + q4 + r;
            float a = acc[ni][r] + x1r[r] * kbd;
            u.As[c * 72 + d] = f2b(a);
            ch[r] += a * qbd;
        }
    }
#pragma unroll
    for (int r = 0; r < 4; ++r) {
#pragma unroll
        for (int dd = 1; dd < 16; dd <<= 1) ch[r] += __shfl_xor(ch[r], dd);
        if (l15 == 0)
            cvec[b * C_ + h * 64 + w * 16 + q4 + r] =
                x1r[r] * (1.0f / L_) + ch[r] * SCALE_;
    }
    __syncthreads();

#pragma unroll
    for (int i = 0; i < 4; ++i) {
        const int cc0 = (i * 4 + w) * 64;
        f32x4 ac[4][4] = {};
#pragma unroll
        for (int ks = 0; ks < 2; ++ks) {
            short8 af[4], bf[4];
#pragma unroll
            for (int mi = 0; mi < 4; ++mi)
                af[mi] = *(const short8*)&u.As[(mi * 16 + l15) * 72 + ks * 32 + q8];
#pragma unroll
            for (int ni = 0; ni < 4; ++ni)
                bf[ni] = *(const short8*)&qwT[(size_t)(cc0 + ni * 16 + l15) * C_
                                              + h * 64 + ks * 32 + q8];
#pragma unroll
            for (int mi = 0; mi < 4; ++mi)
#pragma unroll
                for (int ni = 0; ni < 4; ++ni)
                    ac[mi][ni] = MFMA(af[mi], bf[ni], ac[mi][ni]);
        }
#pragma unroll
        for (int ni = 0; ni < 4; ++ni)
#pragma unroll
            for (int mi = 0; mi < 4; ++mi) {
                bs4 o = pack4(ac[mi][ni]);
                *(bs4*)&BallT[((size_t)b * C_ + cc0 + ni * 16 + l15) * C_
                              + h * 64 + mi * 16 + q4] = o;
            }
    }
}

// ---------------------------------------------------------------------------
// wy64: Wy[b][o][cc] = SCALE_ * sum_c pw[o,c]*BallT[b][cc][c]. 64x64 BK=64 dbuf.
// ---------------------------------------------------------------------------
__global__ __launch_bounds__(256) void wy64(
    const unsigned short* __restrict__ pwb, const unsigned short* __restrict__ BallT,
    unsigned short* __restrict__ Wy)
{
    const int t = threadIdx.x, w = t >> 6, lane = t & 63;
    const int b = blockIdx.z;
    const int o0 = blockIdx.y * 64, cc0 = blockIdx.x * 64;
    const int l15 = lane & 15, q8 = (lane >> 4) * 8, q4 = (lane >> 4) * 4;
    const int wm = (w >> 1) * 32, wn = (w & 1) * 32;
    const unsigned short* Bb = BallT + (size_t)b * C_ * C_;

    __shared__ union {
        __align__(16) unsigned short st[2][2][2][64 * 32];
        __align__(16) unsigned short Cs[64 * 72];
    } u;

    auto stage = [&](int buf, int k0) {
        int row = t >> 2, off = (t & 3) * 8;
        GLOAD16(&pwb[(size_t)(o0 + row) * C_ + k0 + off],      &u.st[buf][0][0][(w * 64) * 8]);
        GLOAD16(&pwb[(size_t)(o0 + row) * C_ + k0 + 32 + off], &u.st[buf][0][1][(w * 64) * 8]);
        GLOAD16(&Bb[(size_t)(cc0 + row) * C_ + k0 + off],      &u.st[buf][1][0][(w * 64) * 8]);
        GLOAD16(&Bb[(size_t)(cc0 + row) * C_ + k0 + 32 + off], &u.st[buf][1][1][(w * 64) * 8]);
    };

    f32x4 acc[2][2] = {};
    stage(0, 0);
    for (int kt = 0; kt < 16; ++kt) {
        const int cur = kt & 1;
        __syncthreads();
        if (kt < 15) stage(cur ^ 1, (kt + 1) * 64);
#pragma unroll
        for (int ks = 0; ks < 2; ++ks) {
            short8 a[2], bf[2];
#pragma unroll
            for (int mi = 0; mi < 2; ++mi)
                a[mi] = *(const short8*)&u.st[cur][0][ks][(wm + mi * 16 + l15) * 32 + q8];
#pragma unroll
            for (int ni = 0; ni < 2; ++ni)
                bf[ni] = *(const short8*)&u.st[cur][1][ks][(wn + ni * 16 + l15) * 32 + q8];
#pragma unroll
            for (int mi = 0; mi < 2; ++mi)
#pragma unroll
                for (int ni = 0; ni < 2; ++ni)
                    acc[mi][ni] = MFMA(a[mi], bf[ni], acc[mi][ni]);
        }
    }

    __syncthreads();
#pragma unroll
    for (int mi = 0; mi < 2; ++mi)
#pragma unroll
        for (int r = 0; r < 4; ++r)
#pragma unroll
            for (int ni = 0; ni < 2; ++ni)
                u.Cs[(wm + mi * 16 + q4 + r) * 72 + wn + ni * 16 + l15] =
                    f2b(acc[mi][ni][r] * SCALE_);
    __syncthreads();
#pragma unroll
    for (int p = 0; p < 2; ++p) {
        int E = p * 256 + t;
        int row = E >> 3, seg = E & 7;
        short8 val = *(const short8*)&u.Cs[row * 72 + seg * 8];
        *(short8*)&Wy[((size_t)b * C_ + o0 + row) * C_ + cc0 + seg * 8] = val;
    }
}

// dvec[b][o] = sum_c pwb[o,c]*cvec[b,c] + pb[o]
__global__ __launch_bounds__(256) void gemv_dvec(
    const unsigned short* __restrict__ pwb, const float* __restrict__ cvec,
    const float* __restrict__ pb, float* __restrict__ dvec)
{
    const int t = threadIdx.x, b = blockIdx.y;
    const int o = blockIdx.x * 128 + (t >> 1), part = t & 1;
    __shared__ float cv[1024];
#pragma unroll
    for (int i = 0; i < 4; ++i) cv[t + i * 256] = cvec[b * C_ + t + i * 256];
    __syncthreads();
    const int base = part * 512;
    float acc = 0.f;
#pragma unroll 8
    for (int j = 0; j < 64; ++j) {
        short8 w8 = *(const short8*)&pwb[(size_t)o * C_ + base + j * 8];
#pragma unroll
        for (int e = 0; e < 8; ++e)
            acc = fmaf(b2f((unsigned short)w8[e]), cv[base + j * 8 + e], acc);
    }
    acc += __shfl_xor(acc, 1);
    if (part == 0) dvec[b * C_ + o] = acc + pb[o];
}

// ---------------------------------------------------------------------------
// gemm64: out[o][n] = sum_k A[o][k]*Bt[n][k] (+bias/relu/residuals)
// 64x64 tile, BK=64, dbuf. Grid (N/64, 16) = 1024 blocks = 4/CU.
// Epilogue order: v=acc+bias; relu; v+=add0; outT=f2b(v); v+=add1; outf=v.
// (add1==add0 reuses the loaded value: saves a 16MB f32 read in call 1.)
// ---------------------------------------------------------------------------
__global__ __launch_bounds__(256) void gemm64(
    const unsigned short* __restrict__ A0, size_t abstride,
    const float* __restrict__ bias, int bstride,
    const unsigned short* __restrict__ Bt,
    const float* __restrict__ add0, const float* __restrict__ add1,
    float* __restrict__ outf, unsigned short* __restrict__ outT, int relu)
{
    const int t = threadIdx.x, w = t >> 6, lane = t & 63;
    const int o0 = blockIdx.y * 64, n0 = blockIdx.x * 64;
    const int b_ = n0 >> 11;
    const int l15 = lane & 15, q8 = (lane >> 4) * 8, q4 = (lane >> 4) * 4;
    const int wm = (w >> 1) * 32, wn = (w & 1) * 32;
    const unsigned short* A = A0 + (size_t)b_ * abstride;

    __shared__ union {
        __align__(16) unsigned short st[2][2][2][64 * 32];
        __align__(16) unsigned short Cs[64 * 72];
    } u;
    __shared__ float biass[64];
    if (t < 64) biass[t] = bias[b_ * bstride + o0 + t];

    auto stage = [&](int buf, int k0) {
        int row = t >> 2, off = (t & 3) * 8;
        GLOAD16(&A[(size_t)(o0 + row) * C_ + k0 + off],       &u.st[buf][0][0][(w * 64) * 8]);
        GLOAD16(&A[(size_t)(o0 + row) * C_ + k0 + 32 + off],  &u.st[buf][0][1][(w * 64) * 8]);
        GLOAD16(&Bt[(size_t)(n0 + row) * C_ + k0 + off],      &u.st[buf][1][0][(w * 64) * 8]);
        GLOAD16(&Bt[(size_t)(n0 + row) * C_ + k0 + 32 + off], &u.st[buf][1][1][(w * 64) * 8]);
    };

    f32x4 acc[2][2] = {};
    stage(0, 0);
    for (int kt = 0; kt < 16; ++kt) {
        const int cur = kt & 1;
        __syncthreads();
        if (kt < 15) stage(cur ^ 1, (kt + 1) * 64);
#pragma unroll
        for (int ks = 0; ks < 2; ++ks) {
            short8 a[2], b[2];
#pragma unroll
            for (int mi = 0; mi < 2; ++mi)
                a[mi] = *(const short8*)&u.st[cur][0][ks][(wm + mi * 16 + l15) * 32 + q8];
#pragma unroll
            for (int ni = 0; ni < 2; ++ni)
                b[ni] = *(const short8*)&u.st[cur][1][ks][(wn + ni * 16 + l15) * 32 + q8];
#pragma unroll
            for (int mi = 0; mi < 2; ++mi)
#pragma unroll
                for (int ni = 0; ni < 2; ++ni)
                    acc[mi][ni] = MFMA(a[mi], b[ni], acc[mi][ni]);
        }
    }

    __syncthreads();
    const int lbase = n0 & (L_ - 1);
#pragma unroll
    for (int mi = 0; mi < 2; ++mi)
#pragma unroll
        for (int r = 0; r < 4; ++r) {
            const int row = wm + mi * 16 + q4 + r;
            const float bv = biass[row];
#pragma unroll
            for (int ni = 0; ni < 2; ++ni) {
                const int col = wn + ni * 16 + l15;
                float v = acc[mi][ni][r] + bv;
                if (relu) v = fmaxf(v, 0.f);
                const size_t gidx = ((size_t)b_ * C_ + o0 + row) * L_ + lbase + col;
                float a0v = 0.f;
                if (add0) { a0v = add0[gidx]; v += a0v; }
                if (outT) u.Cs[col * 72 + row] = f2b(v);
                if (add1) v += (add1 == add0) ? a0v : add1[gidx];
                if (outf) outf[gidx] = v;
            }
        }

    if (outT) {
        __syncthreads();
#pragma unroll
        for (int p = 0; p < 2; ++p) {
            int E = p * 256 + t;
            int lr = E >> 3, g = E & 7;
            short8 val = *(const short8*)&u.Cs[lr * 72 + g * 8];
            *(short8*)(outT + (size_t)(n0 + lr) * C_ + o0 + g * 8) = val;
        }
    }
}

// ---------------------------------------------------------------------------
extern "C" void kernel_launch(void* const* d_in, const int* in_sizes, int n_in,
                              void* d_out, int out_size, void* d_ws, size_t ws_size,
                              hipStream_t stream) {
    const float* x   = (const float*)d_in[0];
    const float* kw  = (const float*)d_in[1];
    const float* kb  = (const float*)d_in[2];
    const float* qw  = (const float*)d_in[3];
    const float* qb  = (const float*)d_in[4];
    const float* pw  = (const float*)d_in[5];
    const float* pb  = (const float*)d_in[6];
    const float* c1w = (const float*)d_in[7];
    const float* c1b = (const float*)d_in[8];
    const float* c2w = (const float*)d_in[9];
    const float* c2b = (const float*)d_in[10];
    float* out = (float*)d_out;

    char* p = (char*)d_ws;
    auto carve = [&](size_t bytes) { char* r = p; p += (bytes + 255) & ~(size_t)255; return r; };
    const size_t WN = (size_t)C_ * C_;
    const size_t S  = (size_t)B_ * C_ * L_;
    unsigned short* wb    = (unsigned short*)carve(4 * WN * 2);  // kw,pw,c1w,c2w
    unsigned short* kwb   = wb;
    unsigned short* pwb   = wb + WN;
    unsigned short* c1wb  = wb + 2 * WN;
    unsigned short* c2wb  = wb + 3 * WN;
    unsigned short* qwT   = (unsigned short*)carve(WN * 2);
    unsigned short* xN    = (unsigned short*)carve(S * 2);
    unsigned short* xT    = (unsigned short*)carve(S * 2);
    float*          X1    = (float*)carve((size_t)B_ * C_ * 4);
    unsigned short* G     = (unsigned short*)carve((size_t)B_ * WN * 2);
    unsigned short* BallT = (unsigned short*)carve((size_t)B_ * WN * 2);
    float*          cvec  = (float*)carve((size_t)B_ * C_ * 4);
    unsigned short* Wy    = (unsigned short*)carve((size_t)B_ * WN * 2);
    float*          dvec  = (float*)carve((size_t)B_ * C_ * 4);
    unsigned short* yT    = (unsigned short*)carve(S * 2);
    unsigned short* rT    = (unsigned short*)carve(S * 2);
    float*          ybuf2 = (float*)carve(S * 4);   // holds y + x

    Ptr4 wsrc; wsrc.p[0] = kw; wsrc.p[1] = pw; wsrc.p[2] = c1w; wsrc.p[3] = c2w;
    wprep<<<4096 + 256, 256, 0, stream>>>(wsrc, wb, qw, qwT, X1);
    prep_x<<<dim3(L_ / 64, C_ / 64, B_), 256, 0, stream>>>(x, xN, xT, X1);

    gram64sym<<<dim3(136, B_), 256, 0, stream>>>(xN, G);
    mid_ab<<<BH_, 256, 0, stream>>>(G, kwb, qwT, X1, kb, qb, BallT, cvec);
    wy64<<<dim3(C_ / 64, C_ / 64, B_), 256, 0, stream>>>(pwb, BallT, Wy);
    gemv_dvec<<<dim3(8, B_), 256, 0, stream>>>(pwb, cvec, pb, dvec);

    dim3 gG(N_ / 64, C_ / 64);       // 64 x 16 = 1024 blocks = 4/CU
    // y = Wy·x + dvec + x ; yT = bf16(y) ; ybuf2 = y + x (x loaded once)
    gemm64<<<gG, 256, 0, stream>>>(Wy, WN, dvec, C_, xT, x, x, ybuf2, yT, 0);
    // r = relu(c1·y + c1b)
    gemm64<<<gG, 256, 0, stream>>>(c1wb, 0, c1b, 0, yT, nullptr, nullptr, nullptr, rT, 1);
    // out = c2·r + c2b + (y + x)
    gemm64<<<gG, 256, 0, stream>>>(c2wb, 0, c2b, 0, rT, ybuf2, nullptr, out, nullptr, 0);
}

// Round 6
// 235.903 us; speedup vs baseline: 1.1998x; 1.0219x over previous
//
#include <hip/hip_runtime.h>

#define B_   2
#define C_   1024
#define L_   2048
#define H_   16
#define HD_  64
#define BH_  (B_*H_)
#define N_   (B_*L_)
#define SCALE_ (1.0f/(1024.0f*2048.0f))

typedef __attribute__((ext_vector_type(8))) short short8;
typedef __attribute__((ext_vector_type(4))) short bs4;
typedef __attribute__((ext_vector_type(4))) float f32x4;

#define MFMA(a,b,c) __builtin_amdgcn_mfma_f32_16x16x32_bf16((a),(b),(c),0,0,0)

#define GLOAD16(gp, lp) \
  __builtin_amdgcn_global_load_lds( \
      (const __attribute__((address_space(1))) void*)(gp), \
      (__attribute__((address_space(3))) void*)(lp), 16, 0, 0)

__device__ __forceinline__ unsigned short f2b(float f) {
    union { float f; unsigned u; } v; v.f = f;
    unsigned r = (v.u + 0x7fffu + ((v.u >> 16) & 1u)) >> 16;
    return (unsigned short)r;
}
__device__ __forceinline__ bs4 pack4(f32x4 e) {
    union { f32x4 v; unsigned u[4]; } a; a.v = e;
    union { bs4 s; unsigned u[2]; } r;
    r.u[0] = __builtin_amdgcn_perm(a.u[1] + 0x8000u, a.u[0] + 0x8000u, 0x07060302u);
    r.u[1] = __builtin_amdgcn_perm(a.u[3] + 0x8000u, a.u[2] + 0x8000u, 0x07060302u);
    return r.s;
}
__device__ __forceinline__ float b2f(unsigned short s) {
    union { unsigned u; float f; } v; v.u = ((unsigned)s) << 16; return v.f;
}

// ---------------------------------------------------------------------------
// prep_all: one launch unioning the two independent prep kernels.
//  blocks [0,4096)     : kw/pw/c1w/c2w fp32->bf16 convert
//  blocks [4096,4352)  : transpose qw -> qwT bf16
//  blocks [4352,5376)  : prep_x (x -> xN bf16, xT bf16, X1 row-sums)
// X1 is zeroed by hipMemsetAsync before this launch (block-order-safe).
// ---------------------------------------------------------------------------
struct Ptr4 { const float* p[4]; };
__global__ __launch_bounds__(256) void prep_all(
    Ptr4 src, unsigned short* __restrict__ dst,
    const float* __restrict__ qw, unsigned short* __restrict__ qwT,
    const float* __restrict__ x, unsigned short* __restrict__ xN,
    unsigned short* __restrict__ xT, float* __restrict__ X1)
{
    const int bx = blockIdx.x, t = threadIdx.x;
    __shared__ float T[64][65];

    if (bx < 4096) {
        const float* s = src.p[bx >> 10];
        unsigned short* d = dst + (size_t)(bx >> 10) * ((size_t)C_ * C_);
        int i = (((bx & 1023) * 256) + t) * 4;
        float4 v = *(const float4*)(s + i);
        ushort4 o;
        o.x = f2b(v.x); o.y = f2b(v.y); o.z = f2b(v.z); o.w = f2b(v.w);
        *(ushort4*)(d + i) = o;
        return;
    }
    if (bx < 4352) {
        const int tb = bx - 4096;
        const int d0 = (tb >> 4) * 64, c0 = (tb & 15) * 64;
        const int tr = t >> 6, tc = t & 63;
#pragma unroll
        for (int r = 0; r < 16; ++r)
            T[r * 4 + tr][tc] = qw[(size_t)(d0 + r * 4 + tr) * C_ + c0 + tc];
        __syncthreads();
#pragma unroll
        for (int r = 0; r < 16; ++r) {
            int cc = r * 4 + tr;
            qwT[(size_t)(c0 + cc) * C_ + d0 + tc] = f2b(T[tc][cc]);
        }
        return;
    }
    // ---- prep_x part ----
    const int r0 = bx - 4352;
    const int b = r0 >> 9, c0 = ((r0 >> 5) & 15) * 64, l0 = (r0 & 31) * 64;
    const float* xb = x + (size_t)b * C_ * L_;
    const int tc = t >> 6, tl = t & 63;
#pragma unroll
    for (int r = 0; r < 16; ++r) {
        int c = c0 + r * 4 + tc;
        float v = xb[(size_t)c * L_ + l0 + tl];
        T[r * 4 + tc][tl] = v;
        xN[((size_t)b * C_ + c) * L_ + l0 + tl] = f2b(v);
        float s = v;
#pragma unroll
        for (int d = 1; d < 64; d <<= 1) s += __shfl_xor(s, d);
        if (tl == 0) atomicAdd(&X1[b * C_ + c], s);
    }
    __syncthreads();
#pragma unroll
    for (int r = 0; r < 16; ++r) {
        int lr = r * 4 + tc;
        xT[((size_t)b * L_ + l0 + lr) * C_ + c0 + tl] = f2b(T[tl][lr]);
    }
}

// ---------------------------------------------------------------------------
// gram64sym: G[b][c1][c2] = sum_l xN[b,c1,l]*xN[b,c2,l].  G is SYMMETRIC:
// only the 136 lower-triangle 64x64 tile-pairs (i>=j) are computed;
// off-diagonal blocks are emitted twice (direct + transposed restage).
// ---------------------------------------------------------------------------
__global__ __launch_bounds__(256) void gram64sym(
    const unsigned short* __restrict__ xN, unsigned short* __restrict__ G)
{
    const int t = threadIdx.x, w = t >> 6, lane = t & 63;
    const int b = blockIdx.y;
    int p = blockIdx.x, i = 0;
    while (p > i) { p -= i + 1; ++i; }
    const int c10 = i * 64, c20 = p * 64;
    const int l15 = lane & 15, q8 = (lane >> 4) * 8, q4 = (lane >> 4) * 4;
    const int wm = (w >> 1) * 32, wn = (w & 1) * 32;
    const unsigned short* xb = xN + (size_t)b * C_ * L_;

    __shared__ union {
        __align__(16) unsigned short st[2][2][2][64 * 32]; // [buf][A/B][ks]
        __align__(16) unsigned short Cs[64 * 72];
    } u;

    auto stage = [&](int buf, int k0) {
        int row = t >> 2, off = (t & 3) * 8;
        GLOAD16(&xb[(size_t)(c10 + row) * L_ + k0 + off],      &u.st[buf][0][0][(w * 64) * 8]);
        GLOAD16(&xb[(size_t)(c10 + row) * L_ + k0 + 32 + off], &u.st[buf][0][1][(w * 64) * 8]);
        GLOAD16(&xb[(size_t)(c20 + row) * L_ + k0 + off],      &u.st[buf][1][0][(w * 64) * 8]);
        GLOAD16(&xb[(size_t)(c20 + row) * L_ + k0 + 32 + off], &u.st[buf][1][1][(w * 64) * 8]);
    };

    f32x4 acc[2][2] = {};
    stage(0, 0);
    for (int kt = 0; kt < 32; ++kt) {
        const int cur = kt & 1;
        __syncthreads();
        if (kt < 31) stage(cur ^ 1, (kt + 1) * 64);
#pragma unroll
        for (int ks = 0; ks < 2; ++ks) {
            short8 a[2], bf[2];
#pragma unroll
            for (int mi = 0; mi < 2; ++mi)
                a[mi] = *(const short8*)&u.st[cur][0][ks][(wm + mi * 16 + l15) * 32 + q8];
#pragma unroll
            for (int ni = 0; ni < 2; ++ni)
                bf[ni] = *(const short8*)&u.st[cur][1][ks][(wn + ni * 16 + l15) * 32 + q8];
#pragma unroll
            for (int mi = 0; mi < 2; ++mi)
#pragma unroll
                for (int ni = 0; ni < 2; ++ni)
                    acc[mi][ni] = MFMA(a[mi], bf[ni], acc[mi][ni]);
        }
    }

    __syncthreads();
#pragma unroll
    for (int mi = 0; mi < 2; ++mi)
#pragma unroll
        for (int r = 0; r < 4; ++r)
#pragma unroll
            for (int ni = 0; ni < 2; ++ni)
                u.Cs[(wm + mi * 16 + q4 + r) * 72 + wn + ni * 16 + l15] =
                    f2b(acc[mi][ni][r]);
    __syncthreads();
#pragma unroll
    for (int pp = 0; pp < 2; ++pp) {
        int E = pp * 256 + t;
        int row = E >> 3, seg = E & 7;
        short8 val = *(const short8*)&u.Cs[row * 72 + seg * 8];
        *(short8*)&G[((size_t)b * C_ + c10 + row) * C_ + c20 + seg * 8] = val;
    }

    if (c10 != c20) {
        __syncthreads();
#pragma unroll
        for (int mi = 0; mi < 2; ++mi)
#pragma unroll
            for (int r = 0; r < 4; ++r)
#pragma unroll
                for (int ni = 0; ni < 2; ++ni)
                    u.Cs[(wn + ni * 16 + l15) * 72 + wm + mi * 16 + q4 + r] =
                        f2b(acc[mi][ni][r]);
        __syncthreads();
#pragma unroll
        for (int pp = 0; pp < 2; ++pp) {
            int E = pp * 256 + t;
            int row = E >> 3, seg = E & 7;
            short8 val = *(const short8*)&u.Cs[row * 72 + seg * 8];
            *(short8*)&G[((size_t)b * C_ + c20 + row) * C_ + c10 + seg * 8] = val;
        }
    }
}

// ---------------------------------------------------------------------------
// mid_ab (grid 32 = bh):
//  ph1: A_h[c,d] = sum_cc G[b][h*64+c][cc]*kw[h*64+d][cc] + X1[c]*kb[d] -> LDS
//       cvec[b][h*64+c] = X1[c]/2048 + (A_h·qb)[c]*SCALE_
//  ph2: BallT[b][cc][h*64+c] = sum_d A_h[c,d]*qwT[cc][h*64+d]
// r6: ph1 BK 32->64 (gemm64-style 2-ks staging): 16 barrier drains instead of
// 32, 8 MFMA of cover each -- this 32-block kernel is latency-bound.
// ---------------------------------------------------------------------------
__global__ __launch_bounds__(256) void mid_ab(
    const unsigned short* __restrict__ G, const unsigned short* __restrict__ kwb,
    const unsigned short* __restrict__ qwT,
    const float* __restrict__ X1, const float* __restrict__ kb,
    const float* __restrict__ qb,
    unsigned short* __restrict__ BallT, float* __restrict__ cvec)
{
    const int t = threadIdx.x, w = t >> 6, lane = t & 63;
    const int bh = blockIdx.x, b = bh >> 4, h = bh & 15;
    const int l15 = lane & 15, q8 = (lane >> 4) * 8, q4 = (lane >> 4) * 4;

    __shared__ union {
        struct { __align__(16) unsigned short Gs[2][2][64 * 32];   // [buf][ks]
                 __align__(16) unsigned short Ks[2][2][64 * 32]; } st;
        __align__(16) unsigned short As[64 * 72];
    } u;

    const unsigned short* gb  = G   + ((size_t)b * C_ + h * 64) * C_;
    const unsigned short* kwh = kwb + (size_t)h * 64 * C_;

    auto stage = [&](int buf, int k0) {
        int row = t >> 2, off = (t & 3) * 8;
        GLOAD16(&gb[(size_t)row * C_ + k0 + off],       &u.st.Gs[buf][0][(w * 64) * 8]);
        GLOAD16(&gb[(size_t)row * C_ + k0 + 32 + off],  &u.st.Gs[buf][1][(w * 64) * 8]);
        GLOAD16(&kwh[(size_t)row * C_ + k0 + off],      &u.st.Ks[buf][0][(w * 64) * 8]);
        GLOAD16(&kwh[(size_t)row * C_ + k0 + 32 + off], &u.st.Ks[buf][1][(w * 64) * 8]);
    };

    f32x4 acc[4] = {};
    stage(0, 0);
    for (int kt = 0; kt < 16; ++kt) {
        const int cur = kt & 1;
        __syncthreads();
        if (kt < 15) stage(cur ^ 1, (kt + 1) * 64);
#pragma unroll
        for (int ks = 0; ks < 2; ++ks) {
            short8 a = *(const short8*)&u.st.Gs[cur][ks][(w * 16 + l15) * 32 + q8];
#pragma unroll
            for (int ni = 0; ni < 4; ++ni) {
                short8 bf = *(const short8*)&u.st.Ks[cur][ks][(ni * 16 + l15) * 32 + q8];
                acc[ni] = MFMA(a, bf, acc[ni]);
            }
        }
    }
    __syncthreads();

    float x1r[4];
#pragma unroll
    for (int r = 0; r < 4; ++r)
        x1r[r] = X1[b * C_ + h * 64 + w * 16 + q4 + r];
    float ch[4] = {0.f, 0.f, 0.f, 0.f};
#pragma unroll
    for (int ni = 0; ni < 4; ++ni) {
        const int d = ni * 16 + l15;
        const float kbd = kb[h * 64 + d], qbd = qb[h * 64 + d];
#pragma unroll
        for (int r = 0; r < 4; ++r) {
            const int c = w * 16 + q4 + r;
            float a = acc[ni][r] + x1r[r] * kbd;
            u.As[c * 72 + d] = f2b(a);
            ch[r] += a * qbd;
        }
    }
#pragma unroll
    for (int r = 0; r < 4; ++r) {
#pragma unroll
        for (int dd = 1; dd < 16; dd <<= 1) ch[r] += __shfl_xor(ch[r], dd);
        if (l15 == 0)
            cvec[b * C_ + h * 64 + w * 16 + q4 + r] =
                x1r[r] * (1.0f / L_) + ch[r] * SCALE_;
    }
    __syncthreads();

#pragma unroll
    for (int i = 0; i < 4; ++i) {
        const int cc0 = (i * 4 + w) * 64;
        f32x4 ac[4][4] = {};
#pragma unroll
        for (int ks = 0; ks < 2; ++ks) {
            short8 af[4], bf[4];
#pragma unroll
            for (int mi = 0; mi < 4; ++mi)
                af[mi] = *(const short8*)&u.As[(mi * 16 + l15) * 72 + ks * 32 + q8];
#pragma unroll
            for (int ni = 0; ni < 4; ++ni)
                bf[ni] = *(const short8*)&qwT[(size_t)(cc0 + ni * 16 + l15) * C_
                                              + h * 64 + ks * 32 + q8];
#pragma unroll
            for (int mi = 0; mi < 4; ++mi)
#pragma unroll
                for (int ni = 0; ni < 4; ++ni)
                    ac[mi][ni] = MFMA(af[mi], bf[ni], ac[mi][ni]);
        }
#pragma unroll
        for (int ni = 0; ni < 4; ++ni)
#pragma unroll
            for (int mi = 0; mi < 4; ++mi) {
                bs4 o = pack4(ac[mi][ni]);
                *(bs4*)&BallT[((size_t)b * C_ + cc0 + ni * 16 + l15) * C_
                              + h * 64 + mi * 16 + q4] = o;
            }
    }
}

// ---------------------------------------------------------------------------
// wy_gemv: one launch unioning two independent kernels.
//  blocks [0,512)   : wy64  -- Wy[b][o][cc] = SCALE_*sum_c pw[o,c]*BallT[b][cc][c]
//  blocks [512,528) : gemv  -- dvec[b][o] = sum_c pwb[o,c]*cvec[b,c] + pb[o]
// ---------------------------------------------------------------------------
__global__ __launch_bounds__(256) void wy_gemv(
    const unsigned short* __restrict__ pwb, const unsigned short* __restrict__ BallT,
    unsigned short* __restrict__ Wy,
    const float* __restrict__ cvec, const float* __restrict__ pb,
    float* __restrict__ dvec)
{
    const int t = threadIdx.x;
    __shared__ union {
        __align__(16) unsigned short st[2][2][2][64 * 32];
        __align__(16) unsigned short Cs[64 * 72];
        float cv[1024];
    } u;

    const int bid = blockIdx.x;
    if (bid >= 512) {
        // ---- gemv_dvec part ----
        const int r = bid - 512, b = r >> 3;
        const int o = (r & 7) * 128 + (t >> 1), part = t & 1;
#pragma unroll
        for (int i = 0; i < 4; ++i) u.cv[t + i * 256] = cvec[b * C_ + t + i * 256];
        __syncthreads();
        const int base = part * 512;
        float acc = 0.f;
#pragma unroll 8
        for (int j = 0; j < 64; ++j) {
            short8 w8 = *(const short8*)&pwb[(size_t)o * C_ + base + j * 8];
#pragma unroll
            for (int e = 0; e < 8; ++e)
                acc = fmaf(b2f((unsigned short)w8[e]), u.cv[base + j * 8 + e], acc);
        }
        acc += __shfl_xor(acc, 1);
        if (part == 0) dvec[b * C_ + o] = acc + pb[o];
        return;
    }

    // ---- wy64 part ----
    const int w = t >> 6, lane = t & 63;
    const int b = bid >> 8;
    const int o0 = ((bid >> 4) & 15) * 64, cc0 = (bid & 15) * 64;
    const int l15 = lane & 15, q8 = (lane >> 4) * 8, q4 = (lane >> 4) * 4;
    const int wm = (w >> 1) * 32, wn = (w & 1) * 32;
    const unsigned short* Bb = BallT + (size_t)b * C_ * C_;

    auto stage = [&](int buf, int k0) {
        int row = t >> 2, off = (t & 3) * 8;
        GLOAD16(&pwb[(size_t)(o0 + row) * C_ + k0 + off],      &u.st[buf][0][0][(w * 64) * 8]);
        GLOAD16(&pwb[(size_t)(o0 + row) * C_ + k0 + 32 + off], &u.st[buf][0][1][(w * 64) * 8]);
        GLOAD16(&Bb[(size_t)(cc0 + row) * C_ + k0 + off],      &u.st[buf][1][0][(w * 64) * 8]);
        GLOAD16(&Bb[(size_t)(cc0 + row) * C_ + k0 + 32 + off], &u.st[buf][1][1][(w * 64) * 8]);
    };

    f32x4 acc[2][2] = {};
    stage(0, 0);
    for (int kt = 0; kt < 16; ++kt) {
        const int cur = kt & 1;
        __syncthreads();
        if (kt < 15) stage(cur ^ 1, (kt + 1) * 64);
#pragma unroll
        for (int ks = 0; ks < 2; ++ks) {
            short8 a[2], bf[2];
#pragma unroll
            for (int mi = 0; mi < 2; ++mi)
                a[mi] = *(const short8*)&u.st[cur][0][ks][(wm + mi * 16 + l15) * 32 + q8];
#pragma unroll
            for (int ni = 0; ni < 2; ++ni)
                bf[ni] = *(const short8*)&u.st[cur][1][ks][(wn + ni * 16 + l15) * 32 + q8];
#pragma unroll
            for (int mi = 0; mi < 2; ++mi)
#pragma unroll
                for (int ni = 0; ni < 2; ++ni)
                    acc[mi][ni] = MFMA(a[mi], bf[ni], acc[mi][ni]);
        }
    }

    __syncthreads();
#pragma unroll
    for (int mi = 0; mi < 2; ++mi)
#pragma unroll
        for (int r = 0; r < 4; ++r)
#pragma unroll
            for (int ni = 0; ni < 2; ++ni)
                u.Cs[(wm + mi * 16 + q4 + r) * 72 + wn + ni * 16 + l15] =
                    f2b(acc[mi][ni][r] * SCALE_);
    __syncthreads();
#pragma unroll
    for (int p = 0; p < 2; ++p) {
        int E = p * 256 + t;
        int row = E >> 3, seg = E & 7;
        short8 val = *(const short8*)&u.Cs[row * 72 + seg * 8];
        *(short8*)&Wy[((size_t)b * C_ + o0 + row) * C_ + cc0 + seg * 8] = val;
    }
}

// ---------------------------------------------------------------------------
// gemm64: out[o][n] = sum_k A[o][k]*Bt[n][k] (+bias/relu/residuals)
// 64x64 tile, BK=64, dbuf. Grid (N/64, 16) = 1024 blocks = 4/CU.
// Epilogue order: v=acc+bias; relu; v+=add0; outT=f2b(v); v+=add1; outf=v.
// (add1==add0 reuses the loaded value: saves a 16MB f32 read in call 1.)
// ---------------------------------------------------------------------------
__global__ __launch_bounds__(256) void gemm64(
    const unsigned short* __restrict__ A0, size_t abstride,
    const float* __restrict__ bias, int bstride,
    const unsigned short* __restrict__ Bt,
    const float* __restrict__ add0, const float* __restrict__ add1,
    float* __restrict__ outf, unsigned short* __restrict__ outT, int relu)
{
    const int t = threadIdx.x, w = t >> 6, lane = t & 63;
    const int o0 = blockIdx.y * 64, n0 = blockIdx.x * 64;
    const int b_ = n0 >> 11;
    const int l15 = lane & 15, q8 = (lane >> 4) * 8, q4 = (lane >> 4) * 4;
    const int wm = (w >> 1) * 32, wn = (w & 1) * 32;
    const unsigned short* A = A0 + (size_t)b_ * abstride;

    __shared__ union {
        __align__(16) unsigned short st[2][2][2][64 * 32];
        __align__(16) unsigned short Cs[64 * 72];
    } u;
    __shared__ float biass[64];
    if (t < 64) biass[t] = bias[b_ * bstride + o0 + t];

    auto stage = [&](int buf, int k0) {
        int row = t >> 2, off = (t & 3) * 8;
        GLOAD16(&A[(size_t)(o0 + row) * C_ + k0 + off],       &u.st[buf][0][0][(w * 64) * 8]);
        GLOAD16(&A[(size_t)(o0 + row) * C_ + k0 + 32 + off],  &u.st[buf][0][1][(w * 64) * 8]);
        GLOAD16(&Bt[(size_t)(n0 + row) * C_ + k0 + off],      &u.st[buf][1][0][(w * 64) * 8]);
        GLOAD16(&Bt[(size_t)(n0 + row) * C_ + k0 + 32 + off], &u.st[buf][1][1][(w * 64) * 8]);
    };

    f32x4 acc[2][2] = {};
    stage(0, 0);
    for (int kt = 0; kt < 16; ++kt) {
        const int cur = kt & 1;
        __syncthreads();
        if (kt < 15) stage(cur ^ 1, (kt + 1) * 64);
#pragma unroll
        for (int ks = 0; ks < 2; ++ks) {
            short8 a[2], b[2];
#pragma unroll
            for (int mi = 0; mi < 2; ++mi)
                a[mi] = *(const short8*)&u.st[cur][0][ks][(wm + mi * 16 + l15) * 32 + q8];
#pragma unroll
            for (int ni = 0; ni < 2; ++ni)
                b[ni] = *(const short8*)&u.st[cur][1][ks][(wn + ni * 16 + l15) * 32 + q8];
#pragma unroll
            for (int mi = 0; mi < 2; ++mi)
#pragma unroll
                for (int ni = 0; ni < 2; ++ni)
                    acc[mi][ni] = MFMA(a[mi], b[ni], acc[mi][ni]);
        }
    }

    __syncthreads();
    const int lbase = n0 & (L_ - 1);
#pragma unroll
    for (int mi = 0; mi < 2; ++mi)
#pragma unroll
        for (int r = 0; r < 4; ++r) {
            const int row = wm + mi * 16 + q4 + r;
            const float bv = biass[row];
#pragma unroll
            for (int ni = 0; ni < 2; ++ni) {
                const int col = wn + ni * 16 + l15;
                float v = acc[mi][ni][r] + bv;
                if (relu) v = fmaxf(v, 0.f);
                const size_t gidx = ((size_t)b_ * C_ + o0 + row) * L_ + lbase + col;
                float a0v = 0.f;
                if (add0) { a0v = add0[gidx]; v += a0v; }
                if (outT) u.Cs[col * 72 + row] = f2b(v);
                if (add1) v += (add1 == add0) ? a0v : add1[gidx];
                if (outf) outf[gidx] = v;
            }
        }

    if (outT) {
        __syncthreads();
#pragma unroll
        for (int p = 0; p < 2; ++p) {
            int E = p * 256 + t;
            int lr = E >> 3, g = E & 7;
            short8 val = *(const short8*)&u.Cs[lr * 72 + g * 8];
            *(short8*)(outT + (size_t)(n0 + lr) * C_ + o0 + g * 8) = val;
        }
    }
}

// ---------------------------------------------------------------------------
extern "C" void kernel_launch(void* const* d_in, const int* in_sizes, int n_in,
                              void* d_out, int out_size, void* d_ws, size_t ws_size,
                              hipStream_t stream) {
    const float* x   = (const float*)d_in[0];
    const float* kw  = (const float*)d_in[1];
    const float* kb  = (const float*)d_in[2];
    const float* qw  = (const float*)d_in[3];
    const float* qb  = (const float*)d_in[4];
    const float* pw  = (const float*)d_in[5];
    const float* pb  = (const float*)d_in[6];
    const float* c1w = (const float*)d_in[7];
    const float* c1b = (const float*)d_in[8];
    const float* c2w = (const float*)d_in[9];
    const float* c2b = (const float*)d_in[10];
    float* out = (float*)d_out;

    char* p = (char*)d_ws;
    auto carve = [&](size_t bytes) { char* r = p; p += (bytes + 255) & ~(size_t)255; return r; };
    const size_t WN = (size_t)C_ * C_;
    const size_t S  = (size_t)B_ * C_ * L_;
    unsigned short* wb    = (unsigned short*)carve(4 * WN * 2);  // kw,pw,c1w,c2w
    unsigned short* kwb   = wb;
    unsigned short* pwb   = wb + WN;
    unsigned short* c1wb  = wb + 2 * WN;
    unsigned short* c2wb  = wb + 3 * WN;
    unsigned short* qwT   = (unsigned short*)carve(WN * 2);
    unsigned short* xN    = (unsigned short*)carve(S * 2);
    unsigned short* xT    = (unsigned short*)carve(S * 2);
    float*          X1    = (float*)carve((size_t)B_ * C_ * 4);
    unsigned short* G     = (unsigned short*)carve((size_t)B_ * WN * 2);
    unsigned short* BallT = (unsigned short*)carve((size_t)B_ * WN * 2);
    float*          cvec  = (float*)carve((size_t)B_ * C_ * 4);
    unsigned short* Wy    = (unsigned short*)carve((size_t)B_ * WN * 2);
    float*          dvec  = (float*)carve((size_t)B_ * C_ * 4);
    unsigned short* yT    = (unsigned short*)carve(S * 2);
    unsigned short* rT    = (unsigned short*)carve(S * 2);
    float*          ybuf2 = (float*)carve(S * 4);   // holds y + x

    // X1 must be zero before prep_all's atomicAdds (block order is undefined
    // inside one launch, so the zeroing cannot live in prep_all itself).
    hipMemsetAsync(X1, 0, (size_t)B_ * C_ * 4, stream);

    Ptr4 wsrc; wsrc.p[0] = kw; wsrc.p[1] = pw; wsrc.p[2] = c1w; wsrc.p[3] = c2w;
    prep_all<<<4096 + 256 + 1024, 256, 0, stream>>>(wsrc, wb, qw, qwT, x, xN, xT, X1);

    gram64sym<<<dim3(136, B_), 256, 0, stream>>>(xN, G);
    mid_ab<<<BH_, 256, 0, stream>>>(G, kwb, qwT, X1, kb, qb, BallT, cvec);
    wy_gemv<<<528, 256, 0, stream>>>(pwb, BallT, Wy, cvec, pb, dvec);

    dim3 gG(N_ / 64, C_ / 64);       // 64 x 16 = 1024 blocks = 4/CU
    // y = Wy·x + dvec + x ; yT = bf16(y) ; ybuf2 = y + x (x loaded once)
    gemm64<<<gG, 256, 0, stream>>>(Wy, WN, dvec, C_, xT, x, x, ybuf2, yT, 0);
    // r = relu(c1·y + c1b)
    gemm64<<<gG, 256, 0, stream>>>(c1wb, 0, c1b, 0, yT, nullptr, nullptr, nullptr, rT, 1);
    // out = c2·r + c2b + (y + x)
    gemm64<<<gG, 256, 0, stream>>>(c2wb, 0, c2b, 0, rT, ybuf2, nullptr, out, nullptr, 0);
}

// Round 7
// 234.771 us; speedup vs baseline: 1.2056x; 1.0048x over previous
//
#include <hip/hip_runtime.h>

#define B_   2
#define C_   1024
#define L_   2048
#define H_   16
#define HD_  64
#define BH_  (B_*H_)
#define N_   (B_*L_)
#define SCALE_ (1.0f/(1024.0f*2048.0f))

typedef __attribute__((ext_vector_type(8))) short short8;
typedef __attribute__((ext_vector_type(4))) short bs4;
typedef __attribute__((ext_vector_type(4))) float f32x4;

#define MFMA(a,b,c) __builtin_amdgcn_mfma_f32_16x16x32_bf16((a),(b),(c),0,0,0)

#define GLOAD16(gp, lp) \
  __builtin_amdgcn_global_load_lds( \
      (const __attribute__((address_space(1))) void*)(gp), \
      (__attribute__((address_space(3))) void*)(lp), 16, 0, 0)

__device__ __forceinline__ unsigned short f2b(float f) {
    union { float f; unsigned u; } v; v.f = f;
    unsigned r = (v.u + 0x7fffu + ((v.u >> 16) & 1u)) >> 16;
    return (unsigned short)r;
}
__device__ __forceinline__ bs4 pack4(f32x4 e) {
    union { f32x4 v; unsigned u[4]; } a; a.v = e;
    union { bs4 s; unsigned u[2]; } r;
    r.u[0] = __builtin_amdgcn_perm(a.u[1] + 0x8000u, a.u[0] + 0x8000u, 0x07060302u);
    r.u[1] = __builtin_amdgcn_perm(a.u[3] + 0x8000u, a.u[2] + 0x8000u, 0x07060302u);
    return r.s;
}
__device__ __forceinline__ float b2f(unsigned short s) {
    union { unsigned u; float f; } v; v.u = ((unsigned)s) << 16; return v.f;
}

// ---------------------------------------------------------------------------
// prep_all: one launch unioning the two independent prep kernels.
//  blocks [0,4096)     : kw/pw/c1w/c2w fp32->bf16 convert
//  blocks [4096,4352)  : transpose qw -> qwT bf16
//  blocks [4352,5376)  : prep_x (x -> xN bf16, xT bf16, X1 row-sums)
// X1 is zeroed by hipMemsetAsync before this launch (block-order-safe).
// ---------------------------------------------------------------------------
struct Ptr4 { const float* p[4]; };
__global__ __launch_bounds__(256) void prep_all(
    Ptr4 src, unsigned short* __restrict__ dst,
    const float* __restrict__ qw, unsigned short* __restrict__ qwT,
    const float* __restrict__ x, unsigned short* __restrict__ xN,
    unsigned short* __restrict__ xT, float* __restrict__ X1)
{
    const int bx = blockIdx.x, t = threadIdx.x;
    __shared__ float T[64][65];

    if (bx < 4096) {
        const float* s = src.p[bx >> 10];
        unsigned short* d = dst + (size_t)(bx >> 10) * ((size_t)C_ * C_);
        int i = (((bx & 1023) * 256) + t) * 4;
        float4 v = *(const float4*)(s + i);
        ushort4 o;
        o.x = f2b(v.x); o.y = f2b(v.y); o.z = f2b(v.z); o.w = f2b(v.w);
        *(ushort4*)(d + i) = o;
        return;
    }
    if (bx < 4352) {
        const int tb = bx - 4096;
        const int d0 = (tb >> 4) * 64, c0 = (tb & 15) * 64;
        const int tr = t >> 6, tc = t & 63;
#pragma unroll
        for (int r = 0; r < 16; ++r)
            T[r * 4 + tr][tc] = qw[(size_t)(d0 + r * 4 + tr) * C_ + c0 + tc];
        __syncthreads();
#pragma unroll
        for (int r = 0; r < 16; ++r) {
            int cc = r * 4 + tr;
            qwT[(size_t)(c0 + cc) * C_ + d0 + tc] = f2b(T[tc][cc]);
        }
        return;
    }
    // ---- prep_x part ----
    const int r0 = bx - 4352;
    const int b = r0 >> 9, c0 = ((r0 >> 5) & 15) * 64, l0 = (r0 & 31) * 64;
    const float* xb = x + (size_t)b * C_ * L_;
    const int tc = t >> 6, tl = t & 63;
#pragma unroll
    for (int r = 0; r < 16; ++r) {
        int c = c0 + r * 4 + tc;
        float v = xb[(size_t)c * L_ + l0 + tl];
        T[r * 4 + tc][tl] = v;
        xN[((size_t)b * C_ + c) * L_ + l0 + tl] = f2b(v);
        float s = v;
#pragma unroll
        for (int d = 1; d < 64; d <<= 1) s += __shfl_xor(s, d);
        if (tl == 0) atomicAdd(&X1[b * C_ + c], s);
    }
    __syncthreads();
#pragma unroll
    for (int r = 0; r < 16; ++r) {
        int lr = r * 4 + tc;
        xT[((size_t)b * L_ + l0 + lr) * C_ + c0 + tl] = f2b(T[tl][lr]);
    }
}

// ---------------------------------------------------------------------------
// gram64sym: G[b][c1][c2] = sum_l xN[b,c1,l]*xN[b,c2,l].  G is SYMMETRIC:
// only the 136 lower-triangle 64x64 tile-pairs (i>=j) are computed;
// off-diagonal blocks are emitted twice (direct + transposed restage).
// r7: BK 64->128 (4-deep ks) -- 16 barrier drains instead of 32. This kernel
// runs at 1.06 blocks/CU (grid-pinned), so drains are nearly fully exposed;
// LDS 32->64 KB costs nothing at this occupancy.
// ---------------------------------------------------------------------------
__global__ __launch_bounds__(256) void gram64sym(
    const unsigned short* __restrict__ xN, unsigned short* __restrict__ G)
{
    const int t = threadIdx.x, w = t >> 6, lane = t & 63;
    const int b = blockIdx.y;
    int p = blockIdx.x, i = 0;
    while (p > i) { p -= i + 1; ++i; }
    const int c10 = i * 64, c20 = p * 64;
    const int l15 = lane & 15, q8 = (lane >> 4) * 8, q4 = (lane >> 4) * 4;
    const int wm = (w >> 1) * 32, wn = (w & 1) * 32;
    const unsigned short* xb = xN + (size_t)b * C_ * L_;

    __shared__ union {
        __align__(16) unsigned short st[2][2][4][64 * 32]; // [buf][A/B][ks]
        __align__(16) unsigned short Cs[64 * 72];
    } u;

    auto stage = [&](int buf, int k0) {
        int row = t >> 2, off = (t & 3) * 8;
#pragma unroll
        for (int seg = 0; seg < 4; ++seg) {
            GLOAD16(&xb[(size_t)(c10 + row) * L_ + k0 + seg * 32 + off],
                    &u.st[buf][0][seg][(w * 64) * 8]);
            GLOAD16(&xb[(size_t)(c20 + row) * L_ + k0 + seg * 32 + off],
                    &u.st[buf][1][seg][(w * 64) * 8]);
        }
    };

    f32x4 acc[2][2] = {};
    stage(0, 0);
    for (int kt = 0; kt < 16; ++kt) {
        const int cur = kt & 1;
        __syncthreads();
        if (kt < 15) stage(cur ^ 1, (kt + 1) * 128);
#pragma unroll
        for (int ks = 0; ks < 4; ++ks) {
            short8 a[2], bf[2];
#pragma unroll
            for (int mi = 0; mi < 2; ++mi)
                a[mi] = *(const short8*)&u.st[cur][0][ks][(wm + mi * 16 + l15) * 32 + q8];
#pragma unroll
            for (int ni = 0; ni < 2; ++ni)
                bf[ni] = *(const short8*)&u.st[cur][1][ks][(wn + ni * 16 + l15) * 32 + q8];
#pragma unroll
            for (int mi = 0; mi < 2; ++mi)
#pragma unroll
                for (int ni = 0; ni < 2; ++ni)
                    acc[mi][ni] = MFMA(a[mi], bf[ni], acc[mi][ni]);
        }
    }

    __syncthreads();
#pragma unroll
    for (int mi = 0; mi < 2; ++mi)
#pragma unroll
        for (int r = 0; r < 4; ++r)
#pragma unroll
            for (int ni = 0; ni < 2; ++ni)
                u.Cs[(wm + mi * 16 + q4 + r) * 72 + wn + ni * 16 + l15] =
                    f2b(acc[mi][ni][r]);
    __syncthreads();
#pragma unroll
    for (int pp = 0; pp < 2; ++pp) {
        int E = pp * 256 + t;
        int row = E >> 3, seg = E & 7;
        short8 val = *(const short8*)&u.Cs[row * 72 + seg * 8];
        *(short8*)&G[((size_t)b * C_ + c10 + row) * C_ + c20 + seg * 8] = val;
    }

    if (c10 != c20) {
        __syncthreads();
#pragma unroll
        for (int mi = 0; mi < 2; ++mi)
#pragma unroll
            for (int r = 0; r < 4; ++r)
#pragma unroll
                for (int ni = 0; ni < 2; ++ni)
                    u.Cs[(wn + ni * 16 + l15) * 72 + wm + mi * 16 + q4 + r] =
                        f2b(acc[mi][ni][r]);
        __syncthreads();
#pragma unroll
        for (int pp = 0; pp < 2; ++pp) {
            int E = pp * 256 + t;
            int row = E >> 3, seg = E & 7;
            short8 val = *(const short8*)&u.Cs[row * 72 + seg * 8];
            *(short8*)&G[((size_t)b * C_ + c20 + row) * C_ + c10 + seg * 8] = val;
        }
    }
}

// ---------------------------------------------------------------------------
// mid_ab (grid 32 = bh):
//  ph1: A_h[c,d] = sum_cc G[b][h*64+c][cc]*kw[h*64+d][cc] + X1[c]*kb[d] -> LDS
//       cvec[b][h*64+c] = X1[c]/2048 + (A_h·qb)[c]*SCALE_
//  ph2: BallT[b][cc][h*64+c] = sum_d A_h[c,d]*qwT[cc][h*64+d]
// r7: ph1 BK 64->128 (4-deep ks): 8 barrier drains instead of 16; this
// 32-block kernel's drains are fully exposed (0.125 blocks/CU).
// ---------------------------------------------------------------------------
__global__ __launch_bounds__(256) void mid_ab(
    const unsigned short* __restrict__ G, const unsigned short* __restrict__ kwb,
    const unsigned short* __restrict__ qwT,
    const float* __restrict__ X1, const float* __restrict__ kb,
    const float* __restrict__ qb,
    unsigned short* __restrict__ BallT, float* __restrict__ cvec)
{
    const int t = threadIdx.x, w = t >> 6, lane = t & 63;
    const int bh = blockIdx.x, b = bh >> 4, h = bh & 15;
    const int l15 = lane & 15, q8 = (lane >> 4) * 8, q4 = (lane >> 4) * 4;

    __shared__ union {
        struct { __align__(16) unsigned short Gs[2][4][64 * 32];   // [buf][ks]
                 __align__(16) unsigned short Ks[2][4][64 * 32]; } st;
        __align__(16) unsigned short As[64 * 72];
    } u;

    const unsigned short* gb  = G   + ((size_t)b * C_ + h * 64) * C_;
    const unsigned short* kwh = kwb + (size_t)h * 64 * C_;

    auto stage = [&](int buf, int k0) {
        int row = t >> 2, off = (t & 3) * 8;
#pragma unroll
        for (int seg = 0; seg < 4; ++seg) {
            GLOAD16(&gb[(size_t)row * C_ + k0 + seg * 32 + off],
                    &u.st.Gs[buf][seg][(w * 64) * 8]);
            GLOAD16(&kwh[(size_t)row * C_ + k0 + seg * 32 + off],
                    &u.st.Ks[buf][seg][(w * 64) * 8]);
        }
    };

    f32x4 acc[4] = {};
    stage(0, 0);
    for (int kt = 0; kt < 8; ++kt) {
        const int cur = kt & 1;
        __syncthreads();
        if (kt < 7) stage(cur ^ 1, (kt + 1) * 128);
#pragma unroll
        for (int ks = 0; ks < 4; ++ks) {
            short8 a = *(const short8*)&u.st.Gs[cur][ks][(w * 16 + l15) * 32 + q8];
#pragma unroll
            for (int ni = 0; ni < 4; ++ni) {
                short8 bf = *(const short8*)&u.st.Ks[cur][ks][(ni * 16 + l15) * 32 + q8];
                acc[ni] = MFMA(a, bf, acc[ni]);
            }
        }
    }
    __syncthreads();

    float x1r[4];
#pragma unroll
    for (int r = 0; r < 4; ++r)
        x1r[r] = X1[b * C_ + h * 64 + w * 16 + q4 + r];
    float ch[4] = {0.f, 0.f, 0.f, 0.f};
#pragma unroll
    for (int ni = 0; ni < 4; ++ni) {
        const int d = ni * 16 + l15;
        const float kbd = kb[h * 64 + d], qbd = qb[h * 64 + d];
#pragma unroll
        for (int r = 0; r < 4; ++r) {
            const int c = w * 16 + q4 + r;
            float a = acc[ni][r] + x1r[r] * kbd;
            u.As[c * 72 + d] = f2b(a);
            ch[r] += a * qbd;
        }
    }
#pragma unroll
    for (int r = 0; r < 4; ++r) {
#pragma unroll
        for (int dd = 1; dd < 16; dd <<= 1) ch[r] += __shfl_xor(ch[r], dd);
        if (l15 == 0)
            cvec[b * C_ + h * 64 + w * 16 + q4 + r] =
                x1r[r] * (1.0f / L_) + ch[r] * SCALE_;
    }
    __syncthreads();

#pragma unroll
    for (int i = 0; i < 4; ++i) {
        const int cc0 = (i * 4 + w) * 64;
        f32x4 ac[4][4] = {};
#pragma unroll
        for (int ks = 0; ks < 2; ++ks) {
            short8 af[4], bf[4];
#pragma unroll
            for (int mi = 0; mi < 4; ++mi)
                af[mi] = *(const short8*)&u.As[(mi * 16 + l15) * 72 + ks * 32 + q8];
#pragma unroll
            for (int ni = 0; ni < 4; ++ni)
                bf[ni] = *(const short8*)&qwT[(size_t)(cc0 + ni * 16 + l15) * C_
                                              + h * 64 + ks * 32 + q8];
#pragma unroll
            for (int mi = 0; mi < 4; ++mi)
#pragma unroll
                for (int ni = 0; ni < 4; ++ni)
                    ac[mi][ni] = MFMA(af[mi], bf[ni], ac[mi][ni]);
        }
#pragma unroll
        for (int ni = 0; ni < 4; ++ni)
#pragma unroll
            for (int mi = 0; mi < 4; ++mi) {
                bs4 o = pack4(ac[mi][ni]);
                *(bs4*)&BallT[((size_t)b * C_ + cc0 + ni * 16 + l15) * C_
                              + h * 64 + mi * 16 + q4] = o;
            }
    }
}

// ---------------------------------------------------------------------------
// wy_gemv: one launch unioning two independent kernels.
//  blocks [0,512)   : wy64  -- Wy[b][o][cc] = SCALE_*sum_c pw[o,c]*BallT[b][cc][c]
//  blocks [512,528) : gemv  -- dvec[b][o] = sum_c pwb[o,c]*cvec[b,c] + pb[o]
// r7: wy BK 64->128 (4-deep ks): 8 drains instead of 16; 64 KB LDS still
// permits the grid-limited 2 blocks/CU.
// ---------------------------------------------------------------------------
__global__ __launch_bounds__(256) void wy_gemv(
    const unsigned short* __restrict__ pwb, const unsigned short* __restrict__ BallT,
    unsigned short* __restrict__ Wy,
    const float* __restrict__ cvec, const float* __restrict__ pb,
    float* __restrict__ dvec)
{
    const int t = threadIdx.x;
    __shared__ union {
        __align__(16) unsigned short st[2][2][4][64 * 32];
        __align__(16) unsigned short Cs[64 * 72];
        float cv[1024];
    } u;

    const int bid = blockIdx.x;
    if (bid >= 512) {
        // ---- gemv_dvec part ----
        const int r = bid - 512, b = r >> 3;
        const int o = (r & 7) * 128 + (t >> 1), part = t & 1;
#pragma unroll
        for (int i = 0; i < 4; ++i) u.cv[t + i * 256] = cvec[b * C_ + t + i * 256];
        __syncthreads();
        const int base = part * 512;
        float acc = 0.f;
#pragma unroll 8
        for (int j = 0; j < 64; ++j) {
            short8 w8 = *(const short8*)&pwb[(size_t)o * C_ + base + j * 8];
#pragma unroll
            for (int e = 0; e < 8; ++e)
                acc = fmaf(b2f((unsigned short)w8[e]), u.cv[base + j * 8 + e], acc);
        }
        acc += __shfl_xor(acc, 1);
        if (part == 0) dvec[b * C_ + o] = acc + pb[o];
        return;
    }

    // ---- wy64 part ----
    const int w = t >> 6, lane = t & 63;
    const int b = bid >> 8;
    const int o0 = ((bid >> 4) & 15) * 64, cc0 = (bid & 15) * 64;
    const int l15 = lane & 15, q8 = (lane >> 4) * 8, q4 = (lane >> 4) * 4;
    const int wm = (w >> 1) * 32, wn = (w & 1) * 32;
    const unsigned short* Bb = BallT + (size_t)b * C_ * C_;

    auto stage = [&](int buf, int k0) {
        int row = t >> 2, off = (t & 3) * 8;
#pragma unroll
        for (int seg = 0; seg < 4; ++seg) {
            GLOAD16(&pwb[(size_t)(o0 + row) * C_ + k0 + seg * 32 + off],
                    &u.st[buf][0][seg][(w * 64) * 8]);
            GLOAD16(&Bb[(size_t)(cc0 + row) * C_ + k0 + seg * 32 + off],
                    &u.st[buf][1][seg][(w * 64) * 8]);
        }
    };

    f32x4 acc[2][2] = {};
    stage(0, 0);
    for (int kt = 0; kt < 8; ++kt) {
        const int cur = kt & 1;
        __syncthreads();
        if (kt < 7) stage(cur ^ 1, (kt + 1) * 128);
#pragma unroll
        for (int ks = 0; ks < 4; ++ks) {
            short8 a[2], bf[2];
#pragma unroll
            for (int mi = 0; mi < 2; ++mi)
                a[mi] = *(const short8*)&u.st[cur][0][ks][(wm + mi * 16 + l15) * 32 + q8];
#pragma unroll
            for (int ni = 0; ni < 2; ++ni)
                bf[ni] = *(const short8*)&u.st[cur][1][ks][(wn + ni * 16 + l15) * 32 + q8];
#pragma unroll
            for (int mi = 0; mi < 2; ++mi)
#pragma unroll
                for (int ni = 0; ni < 2; ++ni)
                    acc[mi][ni] = MFMA(a[mi], bf[ni], acc[mi][ni]);
        }
    }

    __syncthreads();
#pragma unroll
    for (int mi = 0; mi < 2; ++mi)
#pragma unroll
        for (int r = 0; r < 4; ++r)
#pragma unroll
            for (int ni = 0; ni < 2; ++ni)
                u.Cs[(wm + mi * 16 + q4 + r) * 72 + wn + ni * 16 + l15] =
                    f2b(acc[mi][ni][r] * SCALE_);
    __syncthreads();
#pragma unroll
    for (int p = 0; p < 2; ++p) {
        int E = p * 256 + t;
        int row = E >> 3, seg = E & 7;
        short8 val = *(const short8*)&u.Cs[row * 72 + seg * 8];
        *(short8*)&Wy[((size_t)b * C_ + o0 + row) * C_ + cc0 + seg * 8] = val;
    }
}

// ---------------------------------------------------------------------------
// gemm64: out[o][n] = sum_k A[o][k]*Bt[n][k] (+bias/relu/residuals)
// 64x64 tile, BK=64, dbuf. Grid (N/64, 16) = 1024 blocks = 4/CU.
// (BK stays 64 here: BK=128 would drop occupancy 4->2 and cancel out — m132.)
// Epilogue order: v=acc+bias; relu; v+=add0; outT=f2b(v); v+=add1; outf=v.
// ---------------------------------------------------------------------------
__global__ __launch_bounds__(256) void gemm64(
    const unsigned short* __restrict__ A0, size_t abstride,
    const float* __restrict__ bias, int bstride,
    const unsigned short* __restrict__ Bt,
    const float* __restrict__ add0, const float* __restrict__ add1,
    float* __restrict__ outf, unsigned short* __restrict__ outT, int relu)
{
    const int t = threadIdx.x, w = t >> 6, lane = t & 63;
    const int o0 = blockIdx.y * 64, n0 = blockIdx.x * 64;
    const int b_ = n0 >> 11;
    const int l15 = lane & 15, q8 = (lane >> 4) * 8, q4 = (lane >> 4) * 4;
    const int wm = (w >> 1) * 32, wn = (w & 1) * 32;
    const unsigned short* A = A0 + (size_t)b_ * abstride;

    __shared__ union {
        __align__(16) unsigned short st[2][2][2][64 * 32];
        __align__(16) unsigned short Cs[64 * 72];
    } u;
    __shared__ float biass[64];
    if (t < 64) biass[t] = bias[b_ * bstride + o0 + t];

    auto stage = [&](int buf, int k0) {
        int row = t >> 2, off = (t & 3) * 8;
        GLOAD16(&A[(size_t)(o0 + row) * C_ + k0 + off],       &u.st[buf][0][0][(w * 64) * 8]);
        GLOAD16(&A[(size_t)(o0 + row) * C_ + k0 + 32 + off],  &u.st[buf][0][1][(w * 64) * 8]);
        GLOAD16(&Bt[(size_t)(n0 + row) * C_ + k0 + off],      &u.st[buf][1][0][(w * 64) * 8]);
        GLOAD16(&Bt[(size_t)(n0 + row) * C_ + k0 + 32 + off], &u.st[buf][1][1][(w * 64) * 8]);
    };

    f32x4 acc[2][2] = {};
    stage(0, 0);
    for (int kt = 0; kt < 16; ++kt) {
        const int cur = kt & 1;
        __syncthreads();
        if (kt < 15) stage(cur ^ 1, (kt + 1) * 64);
#pragma unroll
        for (int ks = 0; ks < 2; ++ks) {
            short8 a[2], b[2];
#pragma unroll
            for (int mi = 0; mi < 2; ++mi)
                a[mi] = *(const short8*)&u.st[cur][0][ks][(wm + mi * 16 + l15) * 32 + q8];
#pragma unroll
            for (int ni = 0; ni < 2; ++ni)
                b[ni] = *(const short8*)&u.st[cur][1][ks][(wn + ni * 16 + l15) * 32 + q8];
#pragma unroll
            for (int mi = 0; mi < 2; ++mi)
#pragma unroll
                for (int ni = 0; ni < 2; ++ni)
                    acc[mi][ni] = MFMA(a[mi], b[ni], acc[mi][ni]);
        }
    }

    __syncthreads();
    const int lbase = n0 & (L_ - 1);
#pragma unroll
    for (int mi = 0; mi < 2; ++mi)
#pragma unroll
        for (int r = 0; r < 4; ++r) {
            const int row = wm + mi * 16 + q4 + r;
            const float bv = biass[row];
#pragma unroll
            for (int ni = 0; ni < 2; ++ni) {
                const int col = wn + ni * 16 + l15;
                float v = acc[mi][ni][r] + bv;
                if (relu) v = fmaxf(v, 0.f);
                const size_t gidx = ((size_t)b_ * C_ + o0 + row) * L_ + lbase + col;
                float a0v = 0.f;
                if (add0) { a0v = add0[gidx]; v += a0v; }
                if (outT) u.Cs[col * 72 + row] = f2b(v);
                if (add1) v += (add1 == add0) ? a0v : add1[gidx];
                if (outf) outf[gidx] = v;
            }
        }

    if (outT) {
        __syncthreads();
#pragma unroll
        for (int p = 0; p < 2; ++p) {
            int E = p * 256 + t;
            int lr = E >> 3, g = E & 7;
            short8 val = *(const short8*)&u.Cs[lr * 72 + g * 8];
            *(short8*)(outT + (size_t)(n0 + lr) * C_ + o0 + g * 8) = val;
        }
    }
}

// ---------------------------------------------------------------------------
extern "C" void kernel_launch(void* const* d_in, const int* in_sizes, int n_in,
                              void* d_out, int out_size, void* d_ws, size_t ws_size,
                              hipStream_t stream) {
    const float* x   = (const float*)d_in[0];
    const float* kw  = (const float*)d_in[1];
    const float* kb  = (const float*)d_in[2];
    const float* qw  = (const float*)d_in[3];
    const float* qb  = (const float*)d_in[4];
    const float* pw  = (const float*)d_in[5];
    const float* pb  = (const float*)d_in[6];
    const float* c1w = (const float*)d_in[7];
    const float* c1b = (const float*)d_in[8];
    const float* c2w = (const float*)d_in[9];
    const float* c2b = (const float*)d_in[10];
    float* out = (float*)d_out;

    char* p = (char*)d_ws;
    auto carve = [&](size_t bytes) { char* r = p; p += (bytes + 255) & ~(size_t)255; return r; };
    const size_t WN = (size_t)C_ * C_;
    const size_t S  = (size_t)B_ * C_ * L_;
    unsigned short* wb    = (unsigned short*)carve(4 * WN * 2);  // kw,pw,c1w,c2w
    unsigned short* kwb   = wb;
    unsigned short* pwb   = wb + WN;
    unsigned short* c1wb  = wb + 2 * WN;
    unsigned short* c2wb  = wb + 3 * WN;
    unsigned short* qwT   = (unsigned short*)carve(WN * 2);
    unsigned short* xN    = (unsigned short*)carve(S * 2);
    unsigned short* xT    = (unsigned short*)carve(S * 2);
    float*          X1    = (float*)carve((size_t)B_ * C_ * 4);
    unsigned short* G     = (unsigned short*)carve((size_t)B_ * WN * 2);
    unsigned short* BallT = (unsigned short*)carve((size_t)B_ * WN * 2);
    float*          cvec  = (float*)carve((size_t)B_ * C_ * 4);
    unsigned short* Wy    = (unsigned short*)carve((size_t)B_ * WN * 2);
    float*          dvec  = (float*)carve((size_t)B_ * C_ * 4);
    unsigned short* yT    = (unsigned short*)carve(S * 2);
    unsigned short* rT    = (unsigned short*)carve(S * 2);
    float*          ybuf2 = (float*)carve(S * 4);   // holds y + x

    // X1 must be zero before prep_all's atomicAdds (block order is undefined
    // inside one launch, so the zeroing cannot live in prep_all itself).
    hipMemsetAsync(X1, 0, (size_t)B_ * C_ * 4, stream);

    Ptr4 wsrc; wsrc.p[0] = kw; wsrc.p[1] = pw; wsrc.p[2] = c1w; wsrc.p[3] = c2w;
    prep_all<<<4096 + 256 + 1024, 256, 0, stream>>>(wsrc, wb, qw, qwT, x, xN, xT, X1);

    gram64sym<<<dim3(136, B_), 256, 0, stream>>>(xN, G);
    mid_ab<<<BH_, 256, 0, stream>>>(G, kwb, qwT, X1, kb, qb, BallT, cvec);
    wy_gemv<<<528, 256, 0, stream>>>(pwb, BallT, Wy, cvec, pb, dvec);

    dim3 gG(N_ / 64, C_ / 64);       // 64 x 16 = 1024 blocks = 4/CU
    // y = Wy·x + dvec + x ; yT = bf16(y) ; ybuf2 = y + x (x loaded once)
    gemm64<<<gG, 256, 0, stream>>>(Wy, WN, dvec, C_, xT, x, x, ybuf2, yT, 0);
    // r = relu(c1·y + c1b)
    gemm64<<<gG, 256, 0, stream>>>(c1wb, 0, c1b, 0, yT, nullptr, nullptr, nullptr, rT, 1);
    // out = c2·r + c2b + (y + x)
    gemm64<<<gG, 256, 0, stream>>>(c2wb, 0, c2b, 0, rT, ybuf2, nullptr, out, nullptr, 0);
}

// Round 8
// 232.859 us; speedup vs baseline: 1.2155x; 1.0082x over previous
//
#include <hip/hip_runtime.h>

#define B_   2
#define C_   1024
#define L_   2048
#define H_   16
#define HD_  64
#define BH_  (B_*H_)
#define N_   (B_*L_)
#define SCALE_ (1.0f/(1024.0f*2048.0f))

typedef __attribute__((ext_vector_type(8))) short short8;
typedef __attribute__((ext_vector_type(4))) short bs4;
typedef __attribute__((ext_vector_type(4))) float f32x4;

#define MFMA(a,b,c) __builtin_amdgcn_mfma_f32_16x16x32_bf16((a),(b),(c),0,0,0)

#define GLOAD16(gp, lp) \
  __builtin_amdgcn_global_load_lds( \
      (const __attribute__((address_space(1))) void*)(gp), \
      (__attribute__((address_space(3))) void*)(lp), 16, 0, 0)

__device__ __forceinline__ unsigned short f2b(float f) {
    union { float f; unsigned u; } v; v.f = f;
    unsigned r = (v.u + 0x7fffu + ((v.u >> 16) & 1u)) >> 16;
    return (unsigned short)r;
}
__device__ __forceinline__ bs4 pack4(f32x4 e) {
    union { f32x4 v; unsigned u[4]; } a; a.v = e;
    union { bs4 s; unsigned u[2]; } r;
    r.u[0] = __builtin_amdgcn_perm(a.u[1] + 0x8000u, a.u[0] + 0x8000u, 0x07060302u);
    r.u[1] = __builtin_amdgcn_perm(a.u[3] + 0x8000u, a.u[2] + 0x8000u, 0x07060302u);
    return r.s;
}
__device__ __forceinline__ float b2f(unsigned short s) {
    union { unsigned u; float f; } v; v.u = ((unsigned)s) << 16; return v.f;
}

// ---------------------------------------------------------------------------
// prep_x: x f32 [b][c][l] -> xN bf16, xT bf16 [b*2048+l][c], X1[b][c]=sum_l x.
// Standalone 1024-block launch (memset of X1 precedes it).
// ---------------------------------------------------------------------------
__global__ __launch_bounds__(256) void prep_x(
    const float* __restrict__ x, unsigned short* __restrict__ xN,
    unsigned short* __restrict__ xT, float* __restrict__ X1)
{
    int b = blockIdx.z, c0 = blockIdx.y * 64, l0 = blockIdx.x * 64;
    __shared__ float T[64][65];
    const float* xb = x + (size_t)b * C_ * L_;
    int tc = threadIdx.x >> 6;
    int tl = threadIdx.x & 63;
#pragma unroll
    for (int r = 0; r < 16; ++r) {
        int c = c0 + r * 4 + tc;
        float v = xb[(size_t)c * L_ + l0 + tl];
        T[r * 4 + tc][tl] = v;
        xN[((size_t)b * C_ + c) * L_ + l0 + tl] = f2b(v);
        float s = v;
#pragma unroll
        for (int d = 1; d < 64; d <<= 1) s += __shfl_xor(s, d);
        if (tl == 0) atomicAdd(&X1[b * C_ + c], s);
    }
    __syncthreads();
#pragma unroll
    for (int r = 0; r < 16; ++r) {
        int lr = r * 4 + tc;
        xT[((size_t)b * L_ + l0 + lr) * C_ + c0 + tl] = f2b(T[tl][lr]);
    }
}

// ---------------------------------------------------------------------------
// gram_wprep: one launch, three independent block roles.
//  blocks [0,272)            : gram64sym (critical path; dispatched first).
//     G[b][c1][c2] = sum_l xN[b,c1,l]*xN[b,c2,l]; symmetric -> 136 pairs/b,
//     off-diagonal emitted twice (direct + transposed restage). BK=64
//     (32KB LDS union keeps ~5 blocks/CU so the filler blocks co-schedule).
//  blocks [272,4368)         : kw/pw/c1w/c2w fp32->bf16 convert (filler).
//  blocks [4368,4624)        : transpose qw -> qwT bf16 (filler).
// The ~8-10us of weight prep previously ran serially before gram while gram
// used 1.06 blocks/CU; unioning hides it under gram's shadow.
// ---------------------------------------------------------------------------
struct Ptr4 { const float* p[4]; };
__global__ __launch_bounds__(256) void gram_wprep(
    const unsigned short* __restrict__ xN, unsigned short* __restrict__ G,
    Ptr4 src, unsigned short* __restrict__ wdst,
    const float* __restrict__ qw, unsigned short* __restrict__ qwT)
{
    const int bx = blockIdx.x, t = threadIdx.x;

    __shared__ union {
        __align__(16) unsigned short st[2][2][2][64 * 32]; // [buf][A/B][ks]
        __align__(16) unsigned short Cs[64 * 72];
        float T[64][65];
    } u;

    if (bx >= 272) {
        const int tb = bx - 272;
        if (tb < 4096) {
            // ---- weight fp32->bf16 convert ----
            const float* s = src.p[tb >> 10];
            unsigned short* d = wdst + (size_t)(tb >> 10) * ((size_t)C_ * C_);
            int i = (((tb & 1023) * 256) + t) * 4;
            float4 v = *(const float4*)(s + i);
            ushort4 o;
            o.x = f2b(v.x); o.y = f2b(v.y); o.z = f2b(v.z); o.w = f2b(v.w);
            *(ushort4*)(d + i) = o;
            return;
        }
        // ---- qw transpose ----
        const int tq = tb - 4096;
        const int d0 = (tq >> 4) * 64, c0 = (tq & 15) * 64;
        const int tr = t >> 6, tc = t & 63;
#pragma unroll
        for (int r = 0; r < 16; ++r)
            u.T[r * 4 + tr][tc] = qw[(size_t)(d0 + r * 4 + tr) * C_ + c0 + tc];
        __syncthreads();
#pragma unroll
        for (int r = 0; r < 16; ++r) {
            int cc = r * 4 + tr;
            qwT[(size_t)(c0 + cc) * C_ + d0 + tc] = f2b(u.T[tc][cc]);
        }
        return;
    }

    // ---- gram64sym part ----
    const int w = t >> 6, lane = t & 63;
    const int b = bx / 136;
    int pr = bx % 136, i = 0;
    while (pr > i) { pr -= i + 1; ++i; }
    const int c10 = i * 64, c20 = pr * 64;
    const int l15 = lane & 15, q8 = (lane >> 4) * 8, q4 = (lane >> 4) * 4;
    const int wm = (w >> 1) * 32, wn = (w & 1) * 32;
    const unsigned short* xb = xN + (size_t)b * C_ * L_;

    auto stage = [&](int buf, int k0) {
        int row = t >> 2, off = (t & 3) * 8;
        GLOAD16(&xb[(size_t)(c10 + row) * L_ + k0 + off],      &u.st[buf][0][0][(w * 64) * 8]);
        GLOAD16(&xb[(size_t)(c10 + row) * L_ + k0 + 32 + off], &u.st[buf][0][1][(w * 64) * 8]);
        GLOAD16(&xb[(size_t)(c20 + row) * L_ + k0 + off],      &u.st[buf][1][0][(w * 64) * 8]);
        GLOAD16(&xb[(size_t)(c20 + row) * L_ + k0 + 32 + off], &u.st[buf][1][1][(w * 64) * 8]);
    };

    f32x4 acc[2][2] = {};
    stage(0, 0);
    for (int kt = 0; kt < 32; ++kt) {
        const int cur = kt & 1;
        __syncthreads();
        if (kt < 31) stage(cur ^ 1, (kt + 1) * 64);
#pragma unroll
        for (int ks = 0; ks < 2; ++ks) {
            short8 a[2], bf[2];
#pragma unroll
            for (int mi = 0; mi < 2; ++mi)
                a[mi] = *(const short8*)&u.st[cur][0][ks][(wm + mi * 16 + l15) * 32 + q8];
#pragma unroll
            for (int ni = 0; ni < 2; ++ni)
                bf[ni] = *(const short8*)&u.st[cur][1][ks][(wn + ni * 16 + l15) * 32 + q8];
#pragma unroll
            for (int mi = 0; mi < 2; ++mi)
#pragma unroll
                for (int ni = 0; ni < 2; ++ni)
                    acc[mi][ni] = MFMA(a[mi], bf[ni], acc[mi][ni]);
        }
    }

    __syncthreads();
#pragma unroll
    for (int mi = 0; mi < 2; ++mi)
#pragma unroll
        for (int r = 0; r < 4; ++r)
#pragma unroll
            for (int ni = 0; ni < 2; ++ni)
                u.Cs[(wm + mi * 16 + q4 + r) * 72 + wn + ni * 16 + l15] =
                    f2b(acc[mi][ni][r]);
    __syncthreads();
#pragma unroll
    for (int pp = 0; pp < 2; ++pp) {
        int E = pp * 256 + t;
        int row = E >> 3, seg = E & 7;
        short8 val = *(const short8*)&u.Cs[row * 72 + seg * 8];
        *(short8*)&G[((size_t)b * C_ + c10 + row) * C_ + c20 + seg * 8] = val;
    }

    if (c10 != c20) {
        __syncthreads();
#pragma unroll
        for (int mi = 0; mi < 2; ++mi)
#pragma unroll
            for (int r = 0; r < 4; ++r)
#pragma unroll
                for (int ni = 0; ni < 2; ++ni)
                    u.Cs[(wn + ni * 16 + l15) * 72 + wm + mi * 16 + q4 + r] =
                        f2b(acc[mi][ni][r]);
        __syncthreads();
#pragma unroll
        for (int pp = 0; pp < 2; ++pp) {
            int E = pp * 256 + t;
            int row = E >> 3, seg = E & 7;
            short8 val = *(const short8*)&u.Cs[row * 72 + seg * 8];
            *(short8*)&G[((size_t)b * C_ + c20 + row) * C_ + c10 + seg * 8] = val;
        }
    }
}

// ---------------------------------------------------------------------------
// mid_ab (grid 32 = bh):
//  ph1: A_h[c,d] = sum_cc G[b][h*64+c][cc]*kw[h*64+d][cc] + X1[c]*kb[d] -> LDS
//       cvec[b][h*64+c] = X1[c]/2048 + (A_h·qb)[c]*SCALE_
//  ph2: BallT[b][cc][h*64+c] = sum_d A_h[c,d]*qwT[cc][h*64+d]
// ---------------------------------------------------------------------------
__global__ __launch_bounds__(256) void mid_ab(
    const unsigned short* __restrict__ G, const unsigned short* __restrict__ kwb,
    const unsigned short* __restrict__ qwT,
    const float* __restrict__ X1, const float* __restrict__ kb,
    const float* __restrict__ qb,
    unsigned short* __restrict__ BallT, float* __restrict__ cvec)
{
    const int t = threadIdx.x, w = t >> 6, lane = t & 63;
    const int bh = blockIdx.x, b = bh >> 4, h = bh & 15;
    const int l15 = lane & 15, q8 = (lane >> 4) * 8, q4 = (lane >> 4) * 4;

    __shared__ union {
        struct { __align__(16) unsigned short Gs[2][4][64 * 32];   // [buf][ks]
                 __align__(16) unsigned short Ks[2][4][64 * 32]; } st;
        __align__(16) unsigned short As[64 * 72];
    } u;

    const unsigned short* gb  = G   + ((size_t)b * C_ + h * 64) * C_;
    const unsigned short* kwh = kwb + (size_t)h * 64 * C_;

    auto stage = [&](int buf, int k0) {
        int row = t >> 2, off = (t & 3) * 8;
#pragma unroll
        for (int seg = 0; seg < 4; ++seg) {
            GLOAD16(&gb[(size_t)row * C_ + k0 + seg * 32 + off],
                    &u.st.Gs[buf][seg][(w * 64) * 8]);
            GLOAD16(&kwh[(size_t)row * C_ + k0 + seg * 32 + off],
                    &u.st.Ks[buf][seg][(w * 64) * 8]);
        }
    };

    f32x4 acc[4] = {};
    stage(0, 0);
    for (int kt = 0; kt < 8; ++kt) {
        const int cur = kt & 1;
        __syncthreads();
        if (kt < 7) stage(cur ^ 1, (kt + 1) * 128);
#pragma unroll
        for (int ks = 0; ks < 4; ++ks) {
            short8 a = *(const short8*)&u.st.Gs[cur][ks][(w * 16 + l15) * 32 + q8];
#pragma unroll
            for (int ni = 0; ni < 4; ++ni) {
                short8 bf = *(const short8*)&u.st.Ks[cur][ks][(ni * 16 + l15) * 32 + q8];
                acc[ni] = MFMA(a, bf, acc[ni]);
            }
        }
    }
    __syncthreads();

    float x1r[4];
#pragma unroll
    for (int r = 0; r < 4; ++r)
        x1r[r] = X1[b * C_ + h * 64 + w * 16 + q4 + r];
    float ch[4] = {0.f, 0.f, 0.f, 0.f};
#pragma unroll
    for (int ni = 0; ni < 4; ++ni) {
        const int d = ni * 16 + l15;
        const float kbd = kb[h * 64 + d], qbd = qb[h * 64 + d];
#pragma unroll
        for (int r = 0; r < 4; ++r) {
            const int c = w * 16 + q4 + r;
            float a = acc[ni][r] + x1r[r] * kbd;
            u.As[c * 72 + d] = f2b(a);
            ch[r] += a * qbd;
        }
    }
#pragma unroll
    for (int r = 0; r < 4; ++r) {
#pragma unroll
        for (int dd = 1; dd < 16; dd <<= 1) ch[r] += __shfl_xor(ch[r], dd);
        if (l15 == 0)
            cvec[b * C_ + h * 64 + w * 16 + q4 + r] =
                x1r[r] * (1.0f / L_) + ch[r] * SCALE_;
    }
    __syncthreads();

#pragma unroll
    for (int i = 0; i < 4; ++i) {
        const int cc0 = (i * 4 + w) * 64;
        f32x4 ac[4][4] = {};
#pragma unroll
        for (int ks = 0; ks < 2; ++ks) {
            short8 af[4], bf[4];
#pragma unroll
            for (int mi = 0; mi < 4; ++mi)
                af[mi] = *(const short8*)&u.As[(mi * 16 + l15) * 72 + ks * 32 + q8];
#pragma unroll
            for (int ni = 0; ni < 4; ++ni)
                bf[ni] = *(const short8*)&qwT[(size_t)(cc0 + ni * 16 + l15) * C_
                                              + h * 64 + ks * 32 + q8];
#pragma unroll
            for (int mi = 0; mi < 4; ++mi)
#pragma unroll
                for (int ni = 0; ni < 4; ++ni)
                    ac[mi][ni] = MFMA(af[mi], bf[ni], ac[mi][ni]);
        }
#pragma unroll
        for (int ni = 0; ni < 4; ++ni)
#pragma unroll
            for (int mi = 0; mi < 4; ++mi) {
                bs4 o = pack4(ac[mi][ni]);
                *(bs4*)&BallT[((size_t)b * C_ + cc0 + ni * 16 + l15) * C_
                              + h * 64 + mi * 16 + q4] = o;
            }
    }
}

// ---------------------------------------------------------------------------
// wy_gemv: one launch unioning two independent kernels.
//  blocks [0,512)   : wy64 BK=128 -- Wy[b][o][cc] = SCALE_*sum_c pw[o,c]*BallT[b][cc][c]
//  blocks [512,528) : gemv -- dvec[b][o] = sum_c pwb[o,c]*cvec[b,c] + pb[o]
// ---------------------------------------------------------------------------
__global__ __launch_bounds__(256) void wy_gemv(
    const unsigned short* __restrict__ pwb, const unsigned short* __restrict__ BallT,
    unsigned short* __restrict__ Wy,
    const float* __restrict__ cvec, const float* __restrict__ pb,
    float* __restrict__ dvec)
{
    const int t = threadIdx.x;
    __shared__ union {
        __align__(16) unsigned short st[2][2][4][64 * 32];
        __align__(16) unsigned short Cs[64 * 72];
        float cv[1024];
    } u;

    const int bid = blockIdx.x;
    if (bid >= 512) {
        // ---- gemv_dvec part ----
        const int r = bid - 512, b = r >> 3;
        const int o = (r & 7) * 128 + (t >> 1), part = t & 1;
#pragma unroll
        for (int i = 0; i < 4; ++i) u.cv[t + i * 256] = cvec[b * C_ + t + i * 256];
        __syncthreads();
        const int base = part * 512;
        float acc = 0.f;
#pragma unroll 8
        for (int j = 0; j < 64; ++j) {
            short8 w8 = *(const short8*)&pwb[(size_t)o * C_ + base + j * 8];
#pragma unroll
            for (int e = 0; e < 8; ++e)
                acc = fmaf(b2f((unsigned short)w8[e]), u.cv[base + j * 8 + e], acc);
        }
        acc += __shfl_xor(acc, 1);
        if (part == 0) dvec[b * C_ + o] = acc + pb[o];
        return;
    }

    // ---- wy64 part ----
    const int w = t >> 6, lane = t & 63;
    const int b = bid >> 8;
    const int o0 = ((bid >> 4) & 15) * 64, cc0 = (bid & 15) * 64;
    const int l15 = lane & 15, q8 = (lane >> 4) * 8, q4 = (lane >> 4) * 4;
    const int wm = (w >> 1) * 32, wn = (w & 1) * 32;
    const unsigned short* Bb = BallT + (size_t)b * C_ * C_;

    auto stage = [&](int buf, int k0) {
        int row = t >> 2, off = (t & 3) * 8;
#pragma unroll
        for (int seg = 0; seg < 4; ++seg) {
            GLOAD16(&pwb[(size_t)(o0 + row) * C_ + k0 + seg * 32 + off],
                    &u.st[buf][0][seg][(w * 64) * 8]);
            GLOAD16(&Bb[(size_t)(cc0 + row) * C_ + k0 + seg * 32 + off],
                    &u.st[buf][1][seg][(w * 64) * 8]);
        }
    };

    f32x4 acc[2][2] = {};
    stage(0, 0);
    for (int kt = 0; kt < 8; ++kt) {
        const int cur = kt & 1;
        __syncthreads();
        if (kt < 7) stage(cur ^ 1, (kt + 1) * 128);
#pragma unroll
        for (int ks = 0; ks < 4; ++ks) {
            short8 a[2], bf[2];
#pragma unroll
            for (int mi = 0; mi < 2; ++mi)
                a[mi] = *(const short8*)&u.st[cur][0][ks][(wm + mi * 16 + l15) * 32 + q8];
#pragma unroll
            for (int ni = 0; ni < 2; ++ni)
                bf[ni] = *(const short8*)&u.st[cur][1][ks][(wn + ni * 16 + l15) * 32 + q8];
#pragma unroll
            for (int mi = 0; mi < 2; ++mi)
#pragma unroll
                for (int ni = 0; ni < 2; ++ni)
                    acc[mi][ni] = MFMA(a[mi], bf[ni], acc[mi][ni]);
        }
    }

    __syncthreads();
#pragma unroll
    for (int mi = 0; mi < 2; ++mi)
#pragma unroll
        for (int r = 0; r < 4; ++r)
#pragma unroll
            for (int ni = 0; ni < 2; ++ni)
                u.Cs[(wm + mi * 16 + q4 + r) * 72 + wn + ni * 16 + l15] =
                    f2b(acc[mi][ni][r] * SCALE_);
    __syncthreads();
#pragma unroll
    for (int p = 0; p < 2; ++p) {
        int E = p * 256 + t;
        int row = E >> 3, seg = E & 7;
        short8 val = *(const short8*)&u.Cs[row * 72 + seg * 8];
        *(short8*)&Wy[((size_t)b * C_ + o0 + row) * C_ + cc0 + seg * 8] = val;
    }
}

// ---------------------------------------------------------------------------
// gemm64: out[o][n] = sum_k A[o][k]*Bt[n][k] (+bias/relu/residuals)
// 64x64 tile, BK=64, dbuf. Grid (N/64, 16) = 1024 blocks = 4/CU.
// (BK stays 64 here: BK=128 would drop occupancy 4->2 and cancel out — m132.)
// Epilogue order: v=acc+bias; relu; v+=add0; outT=f2b(v); v+=add1; outf=v.
// ---------------------------------------------------------------------------
__global__ __launch_bounds__(256) void gemm64(
    const unsigned short* __restrict__ A0, size_t abstride,
    const float* __restrict__ bias, int bstride,
    const unsigned short* __restrict__ Bt,
    const float* __restrict__ add0, const float* __restrict__ add1,
    float* __restrict__ outf, unsigned short* __restrict__ outT, int relu)
{
    const int t = threadIdx.x, w = t >> 6, lane = t & 63;
    const int o0 = blockIdx.y * 64, n0 = blockIdx.x * 64;
    const int b_ = n0 >> 11;
    const int l15 = lane & 15, q8 = (lane >> 4) * 8, q4 = (lane >> 4) * 4;
    const int wm = (w >> 1) * 32, wn = (w & 1) * 32;
    const unsigned short* A = A0 + (size_t)b_ * abstride;

    __shared__ union {
        __align__(16) unsigned short st[2][2][2][64 * 32];
        __align__(16) unsigned short Cs[64 * 72];
    } u;
    __shared__ float biass[64];
    if (t < 64) biass[t] = bias[b_ * bstride + o0 + t];

    auto stage = [&](int buf, int k0) {
        int row = t >> 2, off = (t & 3) * 8;
        GLOAD16(&A[(size_t)(o0 + row) * C_ + k0 + off],       &u.st[buf][0][0][(w * 64) * 8]);
        GLOAD16(&A[(size_t)(o0 + row) * C_ + k0 + 32 + off],  &u.st[buf][0][1][(w * 64) * 8]);
        GLOAD16(&Bt[(size_t)(n0 + row) * C_ + k0 + off],      &u.st[buf][1][0][(w * 64) * 8]);
        GLOAD16(&Bt[(size_t)(n0 + row) * C_ + k0 + 32 + off], &u.st[buf][1][1][(w * 64) * 8]);
    };

    f32x4 acc[2][2] = {};
    stage(0, 0);
    for (int kt = 0; kt < 16; ++kt) {
        const int cur = kt & 1;
        __syncthreads();
        if (kt < 15) stage(cur ^ 1, (kt + 1) * 64);
#pragma unroll
        for (int ks = 0; ks < 2; ++ks) {
            short8 a[2], b[2];
#pragma unroll
            for (int mi = 0; mi < 2; ++mi)
                a[mi] = *(const short8*)&u.st[cur][0][ks][(wm + mi * 16 + l15) * 32 + q8];
#pragma unroll
            for (int ni = 0; ni < 2; ++ni)
                b[ni] = *(const short8*)&u.st[cur][1][ks][(wn + ni * 16 + l15) * 32 + q8];
#pragma unroll
            for (int mi = 0; mi < 2; ++mi)
#pragma unroll
                for (int ni = 0; ni < 2; ++ni)
                    acc[mi][ni] = MFMA(a[mi], b[ni], acc[mi][ni]);
        }
    }

    __syncthreads();
    const int lbase = n0 & (L_ - 1);
#pragma unroll
    for (int mi = 0; mi < 2; ++mi)
#pragma unroll
        for (int r = 0; r < 4; ++r) {
            const int row = wm + mi * 16 + q4 + r;
            const float bv = biass[row];
#pragma unroll
            for (int ni = 0; ni < 2; ++ni) {
                const int col = wn + ni * 16 + l15;
                float v = acc[mi][ni][r] + bv;
                if (relu) v = fmaxf(v, 0.f);
                const size_t gidx = ((size_t)b_ * C_ + o0 + row) * L_ + lbase + col;
                float a0v = 0.f;
                if (add0) { a0v = add0[gidx]; v += a0v; }
                if (outT) u.Cs[col * 72 + row] = f2b(v);
                if (add1) v += (add1 == add0) ? a0v : add1[gidx];
                if (outf) outf[gidx] = v;
            }
        }

    if (outT) {
        __syncthreads();
#pragma unroll
        for (int p = 0; p < 2; ++p) {
            int E = p * 256 + t;
            int lr = E >> 3, g = E & 7;
            short8 val = *(const short8*)&u.Cs[lr * 72 + g * 8];
            *(short8*)(outT + (size_t)(n0 + lr) * C_ + o0 + g * 8) = val;
        }
    }
}

// ---------------------------------------------------------------------------
extern "C" void kernel_launch(void* const* d_in, const int* in_sizes, int n_in,
                              void* d_out, int out_size, void* d_ws, size_t ws_size,
                              hipStream_t stream) {
    const float* x   = (const float*)d_in[0];
    const float* kw  = (const float*)d_in[1];
    const float* kb  = (const float*)d_in[2];
    const float* qw  = (const float*)d_in[3];
    const float* qb  = (const float*)d_in[4];
    const float* pw  = (const float*)d_in[5];
    const float* pb  = (const float*)d_in[6];
    const float* c1w = (const float*)d_in[7];
    const float* c1b = (const float*)d_in[8];
    const float* c2w = (const float*)d_in[9];
    const float* c2b = (const float*)d_in[10];
    float* out = (float*)d_out;

    char* p = (char*)d_ws;
    auto carve = [&](size_t bytes) { char* r = p; p += (bytes + 255) & ~(size_t)255; return r; };
    const size_t WN = (size_t)C_ * C_;
    const size_t S  = (size_t)B_ * C_ * L_;
    unsigned short* wb    = (unsigned short*)carve(4 * WN * 2);  // kw,pw,c1w,c2w
    unsigned short* kwb   = wb;
    unsigned short* pwb   = wb + WN;
    unsigned short* c1wb  = wb + 2 * WN;
    unsigned short* c2wb  = wb + 3 * WN;
    unsigned short* qwT   = (unsigned short*)carve(WN * 2);
    unsigned short* xN    = (unsigned short*)carve(S * 2);
    unsigned short* xT    = (unsigned short*)carve(S * 2);
    float*          X1    = (float*)carve((size_t)B_ * C_ * 4);
    unsigned short* G     = (unsigned short*)carve((size_t)B_ * WN * 2);
    unsigned short* BallT = (unsigned short*)carve((size_t)B_ * WN * 2);
    float*          cvec  = (float*)carve((size_t)B_ * C_ * 4);
    unsigned short* Wy    = (unsigned short*)carve((size_t)B_ * WN * 2);
    float*          dvec  = (float*)carve((size_t)B_ * C_ * 4);
    unsigned short* yT    = (unsigned short*)carve(S * 2);
    unsigned short* rT    = (unsigned short*)carve(S * 2);
    float*          ybuf2 = (float*)carve(S * 4);   // holds y + x

    // X1 must be zero before prep_x's atomicAdds.
    hipMemsetAsync(X1, 0, (size_t)B_ * C_ * 4, stream);

    prep_x<<<dim3(L_ / 64, C_ / 64, B_), 256, 0, stream>>>(x, xN, xT, X1);

    Ptr4 wsrc; wsrc.p[0] = kw; wsrc.p[1] = pw; wsrc.p[2] = c1w; wsrc.p[3] = c2w;
    // gram blocks [0,272) dispatch first and own the critical path; the 4352
    // weight-prep blocks backfill idle CUs (gram runs at ~1 block/CU).
    gram_wprep<<<272 + 4096 + 256, 256, 0, stream>>>(xN, G, wsrc, wb, qw, qwT);

    mid_ab<<<BH_, 256, 0, stream>>>(G, kwb, qwT, X1, kb, qb, BallT, cvec);
    wy_gemv<<<528, 256, 0, stream>>>(pwb, BallT, Wy, cvec, pb, dvec);

    dim3 gG(N_ / 64, C_ / 64);       // 64 x 16 = 1024 blocks = 4/CU
    // y = Wy·x + dvec + x ; yT = bf16(y) ; ybuf2 = y + x (x loaded once)
    gemm64<<<gG, 256, 0, stream>>>(Wy, WN, dvec, C_, xT, x, x, ybuf2, yT, 0);
    // r = relu(c1·y + c1b)
    gemm64<<<gG, 256, 0, stream>>>(c1wb, 0, c1b, 0, yT, nullptr, nullptr, nullptr, rT, 1);
    // out = c2·r + c2b + (y + x)
    gemm64<<<gG, 256, 0, stream>>>(c2wb, 0, c2b, 0, rT, ybuf2, nullptr, out, nullptr, 0);
}

// Round 9
// 229.868 us; speedup vs baseline: 1.2313x; 1.0130x over previous
//
#include <hip/hip_runtime.h>

#define B_   2
#define C_   1024
#define L_   2048
#define H_   16
#define HD_  64
#define BH_  (B_*H_)
#define N_   (B_*L_)
#define SCALE_ (1.0f/(1024.0f*2048.0f))

typedef __attribute__((ext_vector_type(8))) short short8;
typedef __attribute__((ext_vector_type(4))) short bs4;
typedef __attribute__((ext_vector_type(4))) float f32x4;

#define MFMA(a,b,c) __builtin_amdgcn_mfma_f32_16x16x32_bf16((a),(b),(c),0,0,0)

#define GLOAD16(gp, lp) \
  __builtin_amdgcn_global_load_lds( \
      (const __attribute__((address_space(1))) void*)(gp), \
      (__attribute__((address_space(3))) void*)(lp), 16, 0, 0)

#define MEMFENCE asm volatile("" ::: "memory")

__device__ __forceinline__ unsigned short f2b(float f) {
    union { float f; unsigned u; } v; v.f = f;
    unsigned r = (v.u + 0x7fffu + ((v.u >> 16) & 1u)) >> 16;
    return (unsigned short)r;
}
__device__ __forceinline__ bs4 pack4(f32x4 e) {
    union { f32x4 v; unsigned u[4]; } a; a.v = e;
    union { bs4 s; unsigned u[2]; } r;
    r.u[0] = __builtin_amdgcn_perm(a.u[1] + 0x8000u, a.u[0] + 0x8000u, 0x07060302u);
    r.u[1] = __builtin_amdgcn_perm(a.u[3] + 0x8000u, a.u[2] + 0x8000u, 0x07060302u);
    return r.s;
}
__device__ __forceinline__ float b2f(unsigned short s) {
    union { unsigned u; float f; } v; v.u = ((unsigned)s) << 16; return v.f;
}

// ---------------------------------------------------------------------------
// prep_x: x f32 [b][c][l] -> xN bf16, xT bf16 [b*2048+l][c], X1[b][c]=sum_l x.
// ---------------------------------------------------------------------------
__global__ __launch_bounds__(256) void prep_x(
    const float* __restrict__ x, unsigned short* __restrict__ xN,
    unsigned short* __restrict__ xT, float* __restrict__ X1)
{
    int b = blockIdx.z, c0 = blockIdx.y * 64, l0 = blockIdx.x * 64;
    __shared__ float T[64][65];
    const float* xb = x + (size_t)b * C_ * L_;
    int tc = threadIdx.x >> 6;
    int tl = threadIdx.x & 63;
#pragma unroll
    for (int r = 0; r < 16; ++r) {
        int c = c0 + r * 4 + tc;
        float v = xb[(size_t)c * L_ + l0 + tl];
        T[r * 4 + tc][tl] = v;
        xN[((size_t)b * C_ + c) * L_ + l0 + tl] = f2b(v);
        float s = v;
#pragma unroll
        for (int d = 1; d < 64; d <<= 1) s += __shfl_xor(s, d);
        if (tl == 0) atomicAdd(&X1[b * C_ + c], s);
    }
    __syncthreads();
#pragma unroll
    for (int r = 0; r < 16; ++r) {
        int lr = r * 4 + tc;
        xT[((size_t)b * L_ + l0 + lr) * C_ + c0 + tl] = f2b(T[tl][lr]);
    }
}

// ---------------------------------------------------------------------------
// gram_wprep: one launch, three independent block roles.
//  blocks [0,272)    : gram64sym (critical path; dispatched first).
//  blocks [272,4368) : kw/pw/c1w/c2w fp32->bf16 convert (filler).
//  blocks [4368,4624): transpose qw -> qwT bf16 (filler).
// ---------------------------------------------------------------------------
struct Ptr4 { const float* p[4]; };
__global__ __launch_bounds__(256) void gram_wprep(
    const unsigned short* __restrict__ xN, unsigned short* __restrict__ G,
    Ptr4 src, unsigned short* __restrict__ wdst,
    const float* __restrict__ qw, unsigned short* __restrict__ qwT)
{
    const int bx = blockIdx.x, t = threadIdx.x;

    __shared__ union {
        __align__(16) unsigned short st[2][2][2][64 * 32]; // [buf][A/B][ks]
        __align__(16) unsigned short Cs[64 * 72];
        float T[64][65];
    } u;

    if (bx >= 272) {
        const int tb = bx - 272;
        if (tb < 4096) {
            const float* s = src.p[tb >> 10];
            unsigned short* d = wdst + (size_t)(tb >> 10) * ((size_t)C_ * C_);
            int i = (((tb & 1023) * 256) + t) * 4;
            float4 v = *(const float4*)(s + i);
            ushort4 o;
            o.x = f2b(v.x); o.y = f2b(v.y); o.z = f2b(v.z); o.w = f2b(v.w);
            *(ushort4*)(d + i) = o;
            return;
        }
        const int tq = tb - 4096;
        const int d0 = (tq >> 4) * 64, c0 = (tq & 15) * 64;
        const int tr = t >> 6, tc = t & 63;
#pragma unroll
        for (int r = 0; r < 16; ++r)
            u.T[r * 4 + tr][tc] = qw[(size_t)(d0 + r * 4 + tr) * C_ + c0 + tc];
        __syncthreads();
#pragma unroll
        for (int r = 0; r < 16; ++r) {
            int cc = r * 4 + tr;
            qwT[(size_t)(c0 + cc) * C_ + d0 + tc] = f2b(u.T[tc][cc]);
        }
        return;
    }

    // ---- gram64sym part ----
    const int w = t >> 6, lane = t & 63;
    const int b = bx / 136;
    int pr = bx % 136, i = 0;
    while (pr > i) { pr -= i + 1; ++i; }
    const int c10 = i * 64, c20 = pr * 64;
    const int l15 = lane & 15, q8 = (lane >> 4) * 8, q4 = (lane >> 4) * 4;
    const int wm = (w >> 1) * 32, wn = (w & 1) * 32;
    const unsigned short* xb = xN + (size_t)b * C_ * L_;

    auto stage = [&](int buf, int k0) {
        int row = t >> 2, off = (t & 3) * 8;
        GLOAD16(&xb[(size_t)(c10 + row) * L_ + k0 + off],      &u.st[buf][0][0][(w * 64) * 8]);
        GLOAD16(&xb[(size_t)(c10 + row) * L_ + k0 + 32 + off], &u.st[buf][0][1][(w * 64) * 8]);
        GLOAD16(&xb[(size_t)(c20 + row) * L_ + k0 + off],      &u.st[buf][1][0][(w * 64) * 8]);
        GLOAD16(&xb[(size_t)(c20 + row) * L_ + k0 + 32 + off], &u.st[buf][1][1][(w * 64) * 8]);
    };

    f32x4 acc[2][2] = {};
    stage(0, 0);
    for (int kt = 0; kt < 32; ++kt) {
        const int cur = kt & 1;
        __syncthreads();
        if (kt < 31) stage(cur ^ 1, (kt + 1) * 64);
#pragma unroll
        for (int ks = 0; ks < 2; ++ks) {
            short8 a[2], bf[2];
#pragma unroll
            for (int mi = 0; mi < 2; ++mi)
                a[mi] = *(const short8*)&u.st[cur][0][ks][(wm + mi * 16 + l15) * 32 + q8];
#pragma unroll
            for (int ni = 0; ni < 2; ++ni)
                bf[ni] = *(const short8*)&u.st[cur][1][ks][(wn + ni * 16 + l15) * 32 + q8];
#pragma unroll
            for (int mi = 0; mi < 2; ++mi)
#pragma unroll
                for (int ni = 0; ni < 2; ++ni)
                    acc[mi][ni] = MFMA(a[mi], bf[ni], acc[mi][ni]);
        }
    }

    __syncthreads();
#pragma unroll
    for (int mi = 0; mi < 2; ++mi)
#pragma unroll
        for (int r = 0; r < 4; ++r)
#pragma unroll
            for (int ni = 0; ni < 2; ++ni)
                u.Cs[(wm + mi * 16 + q4 + r) * 72 + wn + ni * 16 + l15] =
                    f2b(acc[mi][ni][r]);
    __syncthreads();
#pragma unroll
    for (int pp = 0; pp < 2; ++pp) {
        int E = pp * 256 + t;
        int row = E >> 3, seg = E & 7;
        short8 val = *(const short8*)&u.Cs[row * 72 + seg * 8];
        *(short8*)&G[((size_t)b * C_ + c10 + row) * C_ + c20 + seg * 8] = val;
    }

    if (c10 != c20) {
        __syncthreads();
#pragma unroll
        for (int mi = 0; mi < 2; ++mi)
#pragma unroll
            for (int r = 0; r < 4; ++r)
#pragma unroll
                for (int ni = 0; ni < 2; ++ni)
                    u.Cs[(wn + ni * 16 + l15) * 72 + wm + mi * 16 + q4 + r] =
                        f2b(acc[mi][ni][r]);
        __syncthreads();
#pragma unroll
        for (int pp = 0; pp < 2; ++pp) {
            int E = pp * 256 + t;
            int row = E >> 3, seg = E & 7;
            short8 val = *(const short8*)&u.Cs[row * 72 + seg * 8];
            *(short8*)&G[((size_t)b * C_ + c20 + row) * C_ + c10 + seg * 8] = val;
        }
    }
}

// ---------------------------------------------------------------------------
// mid_ab (grid 32 = bh): unchanged from r8.
// ---------------------------------------------------------------------------
__global__ __launch_bounds__(256) void mid_ab(
    const unsigned short* __restrict__ G, const unsigned short* __restrict__ kwb,
    const unsigned short* __restrict__ qwT,
    const float* __restrict__ X1, const float* __restrict__ kb,
    const float* __restrict__ qb,
    unsigned short* __restrict__ BallT, float* __restrict__ cvec)
{
    const int t = threadIdx.x, w = t >> 6, lane = t & 63;
    const int bh = blockIdx.x, b = bh >> 4, h = bh & 15;
    const int l15 = lane & 15, q8 = (lane >> 4) * 8, q4 = (lane >> 4) * 4;

    __shared__ union {
        struct { __align__(16) unsigned short Gs[2][4][64 * 32];   // [buf][ks]
                 __align__(16) unsigned short Ks[2][4][64 * 32]; } st;
        __align__(16) unsigned short As[64 * 72];
    } u;

    const unsigned short* gb  = G   + ((size_t)b * C_ + h * 64) * C_;
    const unsigned short* kwh = kwb + (size_t)h * 64 * C_;

    auto stage = [&](int buf, int k0) {
        int row = t >> 2, off = (t & 3) * 8;
#pragma unroll
        for (int seg = 0; seg < 4; ++seg) {
            GLOAD16(&gb[(size_t)row * C_ + k0 + seg * 32 + off],
                    &u.st.Gs[buf][seg][(w * 64) * 8]);
            GLOAD16(&kwh[(size_t)row * C_ + k0 + seg * 32 + off],
                    &u.st.Ks[buf][seg][(w * 64) * 8]);
        }
    };

    f32x4 acc[4] = {};
    stage(0, 0);
    for (int kt = 0; kt < 8; ++kt) {
        const int cur = kt & 1;
        __syncthreads();
        if (kt < 7) stage(cur ^ 1, (kt + 1) * 128);
#pragma unroll
        for (int ks = 0; ks < 4; ++ks) {
            short8 a = *(const short8*)&u.st.Gs[cur][ks][(w * 16 + l15) * 32 + q8];
#pragma unroll
            for (int ni = 0; ni < 4; ++ni) {
                short8 bf = *(const short8*)&u.st.Ks[cur][ks][(ni * 16 + l15) * 32 + q8];
                acc[ni] = MFMA(a, bf, acc[ni]);
            }
        }
    }
    __syncthreads();

    float x1r[4];
#pragma unroll
    for (int r = 0; r < 4; ++r)
        x1r[r] = X1[b * C_ + h * 64 + w * 16 + q4 + r];
    float ch[4] = {0.f, 0.f, 0.f, 0.f};
#pragma unroll
    for (int ni = 0; ni < 4; ++ni) {
        const int d = ni * 16 + l15;
        const float kbd = kb[h * 64 + d], qbd = qb[h * 64 + d];
#pragma unroll
        for (int r = 0; r < 4; ++r) {
            const int c = w * 16 + q4 + r;
            float a = acc[ni][r] + x1r[r] * kbd;
            u.As[c * 72 + d] = f2b(a);
            ch[r] += a * qbd;
        }
    }
#pragma unroll
    for (int r = 0; r < 4; ++r) {
#pragma unroll
        for (int dd = 1; dd < 16; dd <<= 1) ch[r] += __shfl_xor(ch[r], dd);
        if (l15 == 0)
            cvec[b * C_ + h * 64 + w * 16 + q4 + r] =
                x1r[r] * (1.0f / L_) + ch[r] * SCALE_;
    }
    __syncthreads();

#pragma unroll
    for (int i = 0; i < 4; ++i) {
        const int cc0 = (i * 4 + w) * 64;
        f32x4 ac[4][4] = {};
#pragma unroll
        for (int ks = 0; ks < 2; ++ks) {
            short8 af[4], bf[4];
#pragma unroll
            for (int mi = 0; mi < 4; ++mi)
                af[mi] = *(const short8*)&u.As[(mi * 16 + l15) * 72 + ks * 32 + q8];
#pragma unroll
            for (int ni = 0; ni < 4; ++ni)
                bf[ni] = *(const short8*)&qwT[(size_t)(cc0 + ni * 16 + l15) * C_
                                              + h * 64 + ks * 32 + q8];
#pragma unroll
            for (int mi = 0; mi < 4; ++mi)
#pragma unroll
                for (int ni = 0; ni < 4; ++ni)
                    ac[mi][ni] = MFMA(af[mi], bf[ni], ac[mi][ni]);
        }
#pragma unroll
        for (int ni = 0; ni < 4; ++ni)
#pragma unroll
            for (int mi = 0; mi < 4; ++mi) {
                bs4 o = pack4(ac[mi][ni]);
                *(bs4*)&BallT[((size_t)b * C_ + cc0 + ni * 16 + l15) * C_
                              + h * 64 + mi * 16 + q4] = o;
            }
    }
}

// ---------------------------------------------------------------------------
// wy_gemv: unchanged from r8.
// ---------------------------------------------------------------------------
__global__ __launch_bounds__(256) void wy_gemv(
    const unsigned short* __restrict__ pwb, const unsigned short* __restrict__ BallT,
    unsigned short* __restrict__ Wy,
    const float* __restrict__ cvec, const float* __restrict__ pb,
    float* __restrict__ dvec)
{
    const int t = threadIdx.x;
    __shared__ union {
        __align__(16) unsigned short st[2][2][4][64 * 32];
        __align__(16) unsigned short Cs[64 * 72];
        float cv[1024];
    } u;

    const int bid = blockIdx.x;
    if (bid >= 512) {
        const int r = bid - 512, b = r >> 3;
        const int o = (r & 7) * 128 + (t >> 1), part = t & 1;
#pragma unroll
        for (int i = 0; i < 4; ++i) u.cv[t + i * 256] = cvec[b * C_ + t + i * 256];
        __syncthreads();
        const int base = part * 512;
        float acc = 0.f;
#pragma unroll 8
        for (int j = 0; j < 64; ++j) {
            short8 w8 = *(const short8*)&pwb[(size_t)o * C_ + base + j * 8];
#pragma unroll
            for (int e = 0; e < 8; ++e)
                acc = fmaf(b2f((unsigned short)w8[e]), u.cv[base + j * 8 + e], acc);
        }
        acc += __shfl_xor(acc, 1);
        if (part == 0) dvec[b * C_ + o] = acc + pb[o];
        return;
    }

    const int w = t >> 6, lane = t & 63;
    const int b = bid >> 8;
    const int o0 = ((bid >> 4) & 15) * 64, cc0 = (bid & 15) * 64;
    const int l15 = lane & 15, q8 = (lane >> 4) * 8, q4 = (lane >> 4) * 4;
    const int wm = (w >> 1) * 32, wn = (w & 1) * 32;
    const unsigned short* Bb = BallT + (size_t)b * C_ * C_;

    auto stage = [&](int buf, int k0) {
        int row = t >> 2, off = (t & 3) * 8;
#pragma unroll
        for (int seg = 0; seg < 4; ++seg) {
            GLOAD16(&pwb[(size_t)(o0 + row) * C_ + k0 + seg * 32 + off],
                    &u.st[buf][0][seg][(w * 64) * 8]);
            GLOAD16(&Bb[(size_t)(cc0 + row) * C_ + k0 + seg * 32 + off],
                    &u.st[buf][1][seg][(w * 64) * 8]);
        }
    };

    f32x4 acc[2][2] = {};
    stage(0, 0);
    for (int kt = 0; kt < 8; ++kt) {
        const int cur = kt & 1;
        __syncthreads();
        if (kt < 7) stage(cur ^ 1, (kt + 1) * 128);
#pragma unroll
        for (int ks = 0; ks < 4; ++ks) {
            short8 a[2], bf[2];
#pragma unroll
            for (int mi = 0; mi < 2; ++mi)
                a[mi] = *(const short8*)&u.st[cur][0][ks][(wm + mi * 16 + l15) * 32 + q8];
#pragma unroll
            for (int ni = 0; ni < 2; ++ni)
                bf[ni] = *(const short8*)&u.st[cur][1][ks][(wn + ni * 16 + l15) * 32 + q8];
#pragma unroll
            for (int mi = 0; mi < 2; ++mi)
#pragma unroll
                for (int ni = 0; ni < 2; ++ni)
                    acc[mi][ni] = MFMA(a[mi], bf[ni], acc[mi][ni]);
        }
    }

    __syncthreads();
#pragma unroll
    for (int mi = 0; mi < 2; ++mi)
#pragma unroll
        for (int r = 0; r < 4; ++r)
#pragma unroll
            for (int ni = 0; ni < 2; ++ni)
                u.Cs[(wm + mi * 16 + q4 + r) * 72 + wn + ni * 16 + l15] =
                    f2b(acc[mi][ni][r] * SCALE_);
    __syncthreads();
#pragma unroll
    for (int p = 0; p < 2; ++p) {
        int E = p * 256 + t;
        int row = E >> 3, seg = E & 7;
        short8 val = *(const short8*)&u.Cs[row * 72 + seg * 8];
        *(short8*)&Wy[((size_t)b * C_ + o0 + row) * C_ + cc0 + seg * 8] = val;
    }
}

// ---------------------------------------------------------------------------
// gemm64 (r9: counted-vmcnt 2-phase, T4): out[o][n] = sum_k A[o][k]*Bt[n][k].
// Same 64x64 tile / BK=64 / dbuf / 32KB LDS / 4 blocks/CU. The K-loop replaces
// __syncthreads (which drains vmcnt to 0 each step) with:
//   vmcnt(4) -> s_barrier -> ds_read buf[cur] -> lgkmcnt(0) -> s_barrier
//   -> stage buf[cur] for kt+2 -> MFMA
// Invariant: each wave keeps exactly 8 gloads outstanding; oldest 4 are always
// buf[cur]'s, so vmcnt(4)+barrier proves buf[cur] landed for ALL waves while
// the newest 4 remain in flight ACROSS the barrier (never drained mid-loop).
// Overwrite safety: stage into buf[cur] is issued only after lgkmcnt(0)+barrier
// proves every wave's ds_reads of buf[cur] completed (this is the hazard that
// broke the r3/r4 wave-private scheme). All waits are asm volatile "memory";
// raw barriers are fenced both sides against compiler reordering.
// Epilogue order: v=acc+bias; relu; v+=add0; outT=f2b(v); v+=add1; outf=v.
// ---------------------------------------------------------------------------
__global__ __launch_bounds__(256) void gemm64(
    const unsigned short* __restrict__ A0, size_t abstride,
    const float* __restrict__ bias, int bstride,
    const unsigned short* __restrict__ Bt,
    const float* __restrict__ add0, const float* __restrict__ add1,
    float* __restrict__ outf, unsigned short* __restrict__ outT, int relu)
{
    const int t = threadIdx.x, w = t >> 6, lane = t & 63;
    const int o0 = blockIdx.y * 64, n0 = blockIdx.x * 64;
    const int b_ = n0 >> 11;
    const int l15 = lane & 15, q8 = (lane >> 4) * 8, q4 = (lane >> 4) * 4;
    const int wm = (w >> 1) * 32, wn = (w & 1) * 32;
    const unsigned short* A = A0 + (size_t)b_ * abstride;

    __shared__ union {
        __align__(16) unsigned short st[2][2][2][64 * 32];
        __align__(16) unsigned short Cs[64 * 72];
    } u;
    __shared__ float biass[64];
    if (t < 64) biass[t] = bias[b_ * bstride + o0 + t];

    auto stage = [&](int buf, int k0) {
        int row = t >> 2, off = (t & 3) * 8;
        GLOAD16(&A[(size_t)(o0 + row) * C_ + k0 + off],       &u.st[buf][0][0][(w * 64) * 8]);
        GLOAD16(&A[(size_t)(o0 + row) * C_ + k0 + 32 + off],  &u.st[buf][0][1][(w * 64) * 8]);
        GLOAD16(&Bt[(size_t)(n0 + row) * C_ + k0 + off],      &u.st[buf][1][0][(w * 64) * 8]);
        GLOAD16(&Bt[(size_t)(n0 + row) * C_ + k0 + 32 + off], &u.st[buf][1][1][(w * 64) * 8]);
    };

    f32x4 acc[2][2] = {};
    stage(0, 0);
    MEMFENCE;                    // pin buf0's 4 gloads oldest
    stage(1, 64);
    MEMFENCE;

    auto body = [&](int cur) {   // ds_read buf[cur] + 8 MFMA (regs only)
        short8 a[2][2], b[2][2];
#pragma unroll
        for (int ks = 0; ks < 2; ++ks) {
#pragma unroll
            for (int mi = 0; mi < 2; ++mi)
                a[ks][mi] = *(const short8*)&u.st[cur][0][ks][(wm + mi * 16 + l15) * 32 + q8];
#pragma unroll
            for (int ni = 0; ni < 2; ++ni)
                b[ks][ni] = *(const short8*)&u.st[cur][1][ks][(wn + ni * 16 + l15) * 32 + q8];
        }
        asm volatile("s_waitcnt lgkmcnt(0)" ::: "memory");
        __builtin_amdgcn_s_barrier();        // all waves done reading buf[cur]
        MEMFENCE;
        return [=]() {};                     // (unused; reads already in regs)
    };

    for (int kt = 0; kt < 15; ++kt) {
        const int cur = kt & 1;
        asm volatile("s_waitcnt vmcnt(4)" ::: "memory"); // oldest 4 = buf[cur] landed
        __builtin_amdgcn_s_barrier();                    // ...for every wave
        MEMFENCE;
        short8 a[2][2], b[2][2];
#pragma unroll
        for (int ks = 0; ks < 2; ++ks) {
#pragma unroll
            for (int mi = 0; mi < 2; ++mi)
                a[ks][mi] = *(const short8*)&u.st[cur][0][ks][(wm + mi * 16 + l15) * 32 + q8];
#pragma unroll
            for (int ni = 0; ni < 2; ++ni)
                b[ks][ni] = *(const short8*)&u.st[cur][1][ks][(wn + ni * 16 + l15) * 32 + q8];
        }
        asm volatile("s_waitcnt lgkmcnt(0)" ::: "memory"); // my reads in regs
        __builtin_amdgcn_s_barrier();                      // everyone's reads done
        MEMFENCE;
        if (kt < 14) stage(cur, (kt + 2) * 64);  // refill freed buffer; in flight across barriers
#pragma unroll
        for (int ks = 0; ks < 2; ++ks)
#pragma unroll
            for (int mi = 0; mi < 2; ++mi)
#pragma unroll
                for (int ni = 0; ni < 2; ++ni)
                    acc[mi][ni] = MFMA(a[ks][mi], b[ks][ni], acc[mi][ni]);
    }
    // peeled last step (kt=15, cur=1): drain everything
    {
        asm volatile("s_waitcnt vmcnt(0)" ::: "memory");
        __builtin_amdgcn_s_barrier();
        MEMFENCE;
        short8 a[2][2], b[2][2];
#pragma unroll
        for (int ks = 0; ks < 2; ++ks) {
#pragma unroll
            for (int mi = 0; mi < 2; ++mi)
                a[ks][mi] = *(const short8*)&u.st[1][0][ks][(wm + mi * 16 + l15) * 32 + q8];
#pragma unroll
            for (int ni = 0; ni < 2; ++ni)
                b[ks][ni] = *(const short8*)&u.st[1][1][ks][(wn + ni * 16 + l15) * 32 + q8];
        }
        asm volatile("s_waitcnt lgkmcnt(0)" ::: "memory");
#pragma unroll
        for (int ks = 0; ks < 2; ++ks)
#pragma unroll
            for (int mi = 0; mi < 2; ++mi)
#pragma unroll
                for (int ni = 0; ni < 2; ++ni)
                    acc[mi][ni] = MFMA(a[ks][mi], b[ks][ni], acc[mi][ni]);
    }

    __syncthreads();
    const int lbase = n0 & (L_ - 1);
#pragma unroll
    for (int mi = 0; mi < 2; ++mi)
#pragma unroll
        for (int r = 0; r < 4; ++r) {
            const int row = wm + mi * 16 + q4 + r;
            const float bv = biass[row];
#pragma unroll
            for (int ni = 0; ni < 2; ++ni) {
                const int col = wn + ni * 16 + l15;
                float v = acc[mi][ni][r] + bv;
                if (relu) v = fmaxf(v, 0.f);
                const size_t gidx = ((size_t)b_ * C_ + o0 + row) * L_ + lbase + col;
                float a0v = 0.f;
                if (add0) { a0v = add0[gidx]; v += a0v; }
                if (outT) u.Cs[col * 72 + row] = f2b(v);
                if (add1) v += (add1 == add0) ? a0v : add1[gidx];
                if (outf) outf[gidx] = v;
            }
        }

    if (outT) {
        __syncthreads();
#pragma unroll
        for (int p = 0; p < 2; ++p) {
            int E = p * 256 + t;
            int lr = E >> 3, g = E & 7;
            short8 val = *(const short8*)&u.Cs[lr * 72 + g * 8];
            *(short8*)(outT + (size_t)(n0 + lr) * C_ + o0 + g * 8) = val;
        }
    }
}

// ---------------------------------------------------------------------------
extern "C" void kernel_launch(void* const* d_in, const int* in_sizes, int n_in,
                              void* d_out, int out_size, void* d_ws, size_t ws_size,
                              hipStream_t stream) {
    const float* x   = (const float*)d_in[0];
    const float* kw  = (const float*)d_in[1];
    const float* kb  = (const float*)d_in[2];
    const float* qw  = (const float*)d_in[3];
    const float* qb  = (const float*)d_in[4];
    const float* pw  = (const float*)d_in[5];
    const float* pb  = (const float*)d_in[6];
    const float* c1w = (const float*)d_in[7];
    const float* c1b = (const float*)d_in[8];
    const float* c2w = (const float*)d_in[9];
    const float* c2b = (const float*)d_in[10];
    float* out = (float*)d_out;

    char* p = (char*)d_ws;
    auto carve = [&](size_t bytes) { char* r = p; p += (bytes + 255) & ~(size_t)255; return r; };
    const size_t WN = (size_t)C_ * C_;
    const size_t S  = (size_t)B_ * C_ * L_;
    unsigned short* wb    = (unsigned short*)carve(4 * WN * 2);  // kw,pw,c1w,c2w
    unsigned short* kwb   = wb;
    unsigned short* pwb   = wb + WN;
    unsigned short* c1wb  = wb + 2 * WN;
    unsigned short* c2wb  = wb + 3 * WN;
    unsigned short* qwT   = (unsigned short*)carve(WN * 2);
    unsigned short* xN    = (unsigned short*)carve(S * 2);
    unsigned short* xT    = (unsigned short*)carve(S * 2);
    float*          X1    = (float*)carve((size_t)B_ * C_ * 4);
    unsigned short* G     = (unsigned short*)carve((size_t)B_ * WN * 2);
    unsigned short* BallT = (unsigned short*)carve((size_t)B_ * WN * 2);
    float*          cvec  = (float*)carve((size_t)B_ * C_ * 4);
    unsigned short* Wy    = (unsigned short*)carve((size_t)B_ * WN * 2);
    float*          dvec  = (float*)carve((size_t)B_ * C_ * 4);
    unsigned short* yT    = (unsigned short*)carve(S * 2);
    unsigned short* rT    = (unsigned short*)carve(S * 2);
    float*          ybuf2 = (float*)carve(S * 4);   // holds y + x

    // X1 must be zero before prep_x's atomicAdds.
    hipMemsetAsync(X1, 0, (size_t)B_ * C_ * 4, stream);

    prep_x<<<dim3(L_ / 64, C_ / 64, B_), 256, 0, stream>>>(x, xN, xT, X1);

    Ptr4 wsrc; wsrc.p[0] = kw; wsrc.p[1] = pw; wsrc.p[2] = c1w; wsrc.p[3] = c2w;
    gram_wprep<<<272 + 4096 + 256, 256, 0, stream>>>(xN, G, wsrc, wb, qw, qwT);

    mid_ab<<<BH_, 256, 0, stream>>>(G, kwb, qwT, X1, kb, qb, BallT, cvec);
    wy_gemv<<<528, 256, 0, stream>>>(pwb, BallT, Wy, cvec, pb, dvec);

    dim3 gG(N_ / 64, C_ / 64);       // 64 x 16 = 1024 blocks = 4/CU
    // y = Wy·x + dvec + x ; yT = bf16(y) ; ybuf2 = y + x (x loaded once)
    gemm64<<<gG, 256, 0, stream>>>(Wy, WN, dvec, C_, xT, x, x, ybuf2, yT, 0);
    // r = relu(c1·y + c1b)
    gemm64<<<gG, 256, 0, stream>>>(c1wb, 0, c1b, 0, yT, nullptr, nullptr, nullptr, rT, 1);
    // out = c2·r + c2b + (y + x)
    gemm64<<<gG, 256, 0, stream>>>(c2wb, 0, c2b, 0, rT, ybuf2, nullptr, out, nullptr, 0);
}

// Round 10
// 229.813 us; speedup vs baseline: 1.2316x; 1.0002x over previous
//
#include <hip/hip_runtime.h>

#define B_   2
#define C_   1024
#define L_   2048
#define H_   16
#define HD_  64
#define BH_  (B_*H_)
#define N_   (B_*L_)
#define SCALE_ (1.0f/(1024.0f*2048.0f))

typedef __attribute__((ext_vector_type(8))) short short8;
typedef __attribute__((ext_vector_type(4))) short bs4;
typedef __attribute__((ext_vector_type(4))) float f32x4;

#define MFMA(a,b,c) __builtin_amdgcn_mfma_f32_16x16x32_bf16((a),(b),(c),0,0,0)

#define GLOAD16(gp, lp) \
  __builtin_amdgcn_global_load_lds( \
      (const __attribute__((address_space(1))) void*)(gp), \
      (__attribute__((address_space(3))) void*)(lp), 16, 0, 0)

#define MEMFENCE asm volatile("" ::: "memory")
#define WAIT_VM(n) asm volatile("s_waitcnt vmcnt(" #n ")" ::: "memory")
#define WAIT_LGKM0 asm volatile("s_waitcnt lgkmcnt(0)" ::: "memory")

__device__ __forceinline__ unsigned short f2b(float f) {
    union { float f; unsigned u; } v; v.f = f;
    unsigned r = (v.u + 0x7fffu + ((v.u >> 16) & 1u)) >> 16;
    return (unsigned short)r;
}
__device__ __forceinline__ bs4 pack4(f32x4 e) {
    union { f32x4 v; unsigned u[4]; } a; a.v = e;
    union { bs4 s; unsigned u[2]; } r;
    r.u[0] = __builtin_amdgcn_perm(a.u[1] + 0x8000u, a.u[0] + 0x8000u, 0x07060302u);
    r.u[1] = __builtin_amdgcn_perm(a.u[3] + 0x8000u, a.u[2] + 0x8000u, 0x07060302u);
    return r.s;
}
__device__ __forceinline__ float b2f(unsigned short s) {
    union { unsigned u; float f; } v; v.u = ((unsigned)s) << 16; return v.f;
}

// ---------------------------------------------------------------------------
// prep_x: x f32 [b][c][l] -> xN bf16, xT bf16 [b*2048+l][c], X1[b][c]=sum_l x.
// ---------------------------------------------------------------------------
__global__ __launch_bounds__(256) void prep_x(
    const float* __restrict__ x, unsigned short* __restrict__ xN,
    unsigned short* __restrict__ xT, float* __restrict__ X1)
{
    int b = blockIdx.z, c0 = blockIdx.y * 64, l0 = blockIdx.x * 64;
    __shared__ float T[64][65];
    const float* xb = x + (size_t)b * C_ * L_;
    int tc = threadIdx.x >> 6;
    int tl = threadIdx.x & 63;
#pragma unroll
    for (int r = 0; r < 16; ++r) {
        int c = c0 + r * 4 + tc;
        float v = xb[(size_t)c * L_ + l0 + tl];
        T[r * 4 + tc][tl] = v;
        xN[((size_t)b * C_ + c) * L_ + l0 + tl] = f2b(v);
        float s = v;
#pragma unroll
        for (int d = 1; d < 64; d <<= 1) s += __shfl_xor(s, d);
        if (tl == 0) atomicAdd(&X1[b * C_ + c], s);
    }
    __syncthreads();
#pragma unroll
    for (int r = 0; r < 16; ++r) {
        int lr = r * 4 + tc;
        xT[((size_t)b * L_ + l0 + lr) * C_ + c0 + tl] = f2b(T[tl][lr]);
    }
}

// ---------------------------------------------------------------------------
// gram_wprep: one launch, three independent block roles.
//  blocks [0,272)    : gram64sym (critical path; dispatched first).
//  blocks [272,4368) : kw/pw/c1w/c2w fp32->bf16 convert (filler).
//  blocks [4368,4624): transpose qw -> qwT bf16 (filler).
// r10: gram K-loop converted to counted-vmcnt 2-phase (T4, the r9-verified
// pattern). This kernel runs at ~1 block/CU (1 wave/SIMD, NO TLP) -- the
// regime where exposed load latency dominates and counted-vmcnt's
// loads-in-flight-across-barriers actually pays (r9's gemm64 at 4 blocks/CU
// was already TLP-hidden; r7's BK-doubling was null here because it cut
// drain COUNT, not per-drain exposed latency).
// ---------------------------------------------------------------------------
struct Ptr4 { const float* p[4]; };
__global__ __launch_bounds__(256) void gram_wprep(
    const unsigned short* __restrict__ xN, unsigned short* __restrict__ G,
    Ptr4 src, unsigned short* __restrict__ wdst,
    const float* __restrict__ qw, unsigned short* __restrict__ qwT)
{
    const int bx = blockIdx.x, t = threadIdx.x;

    __shared__ union {
        __align__(16) unsigned short st[2][2][2][64 * 32]; // [buf][A/B][ks]
        __align__(16) unsigned short Cs[64 * 72];
        float T[64][65];
    } u;

    if (bx >= 272) {
        const int tb = bx - 272;
        if (tb < 4096) {
            const float* s = src.p[tb >> 10];
            unsigned short* d = wdst + (size_t)(tb >> 10) * ((size_t)C_ * C_);
            int i = (((tb & 1023) * 256) + t) * 4;
            float4 v = *(const float4*)(s + i);
            ushort4 o;
            o.x = f2b(v.x); o.y = f2b(v.y); o.z = f2b(v.z); o.w = f2b(v.w);
            *(ushort4*)(d + i) = o;
            return;
        }
        const int tq = tb - 4096;
        const int d0 = (tq >> 4) * 64, c0 = (tq & 15) * 64;
        const int tr = t >> 6, tc = t & 63;
#pragma unroll
        for (int r = 0; r < 16; ++r)
            u.T[r * 4 + tr][tc] = qw[(size_t)(d0 + r * 4 + tr) * C_ + c0 + tc];
        __syncthreads();
#pragma unroll
        for (int r = 0; r < 16; ++r) {
            int cc = r * 4 + tr;
            qwT[(size_t)(c0 + cc) * C_ + d0 + tc] = f2b(u.T[tc][cc]);
        }
        return;
    }

    // ---- gram64sym part ----
    const int w = t >> 6, lane = t & 63;
    const int b = bx / 136;
    int pr = bx % 136, i = 0;
    while (pr > i) { pr -= i + 1; ++i; }
    const int c10 = i * 64, c20 = pr * 64;
    const int l15 = lane & 15, q8 = (lane >> 4) * 8, q4 = (lane >> 4) * 4;
    const int wm = (w >> 1) * 32, wn = (w & 1) * 32;
    const unsigned short* xb = xN + (size_t)b * C_ * L_;

    auto stage = [&](int buf, int k0) {          // 4 gloads / thread
        int row = t >> 2, off = (t & 3) * 8;
        GLOAD16(&xb[(size_t)(c10 + row) * L_ + k0 + off],      &u.st[buf][0][0][(w * 64) * 8]);
        GLOAD16(&xb[(size_t)(c10 + row) * L_ + k0 + 32 + off], &u.st[buf][0][1][(w * 64) * 8]);
        GLOAD16(&xb[(size_t)(c20 + row) * L_ + k0 + off],      &u.st[buf][1][0][(w * 64) * 8]);
        GLOAD16(&xb[(size_t)(c20 + row) * L_ + k0 + 32 + off], &u.st[buf][1][1][(w * 64) * 8]);
    };
    auto ld = [&](int cur, short8 a[2][2], short8 bf[2][2]) {
#pragma unroll
        for (int ks = 0; ks < 2; ++ks) {
#pragma unroll
            for (int mi = 0; mi < 2; ++mi)
                a[ks][mi] = *(const short8*)&u.st[cur][0][ks][(wm + mi * 16 + l15) * 32 + q8];
#pragma unroll
            for (int ni = 0; ni < 2; ++ni)
                bf[ks][ni] = *(const short8*)&u.st[cur][1][ks][(wn + ni * 16 + l15) * 32 + q8];
        }
    };

    f32x4 acc[2][2] = {};
    stage(0, 0);  MEMFENCE;          // pin buf0's 4 gloads oldest
    stage(1, 64); MEMFENCE;

    for (int kt = 0; kt < 31; ++kt) {
        const int cur = kt & 1;
        WAIT_VM(4);                          // oldest 4 = buf[cur] landed
        __builtin_amdgcn_s_barrier();        // ...for every wave
        MEMFENCE;
        short8 a[2][2], bf[2][2];
        ld(cur, a, bf);
        WAIT_LGKM0;                          // my reads in regs
        __builtin_amdgcn_s_barrier();        // everyone's reads done
        MEMFENCE;
        if (kt < 30) stage(cur, (kt + 2) * 64);  // refill freed buf; stays in flight
#pragma unroll
        for (int ks = 0; ks < 2; ++ks)
#pragma unroll
            for (int mi = 0; mi < 2; ++mi)
#pragma unroll
                for (int ni = 0; ni < 2; ++ni)
                    acc[mi][ni] = MFMA(a[ks][mi], bf[ks][ni], acc[mi][ni]);
    }
    {   // peeled kt=31 (cur=1): drain
        WAIT_VM(0);
        __builtin_amdgcn_s_barrier();
        MEMFENCE;
        short8 a[2][2], bf[2][2];
        ld(1, a, bf);
        WAIT_LGKM0;
#pragma unroll
        for (int ks = 0; ks < 2; ++ks)
#pragma unroll
            for (int mi = 0; mi < 2; ++mi)
#pragma unroll
                for (int ni = 0; ni < 2; ++ni)
                    acc[mi][ni] = MFMA(a[ks][mi], bf[ks][ni], acc[mi][ni]);
    }

    __syncthreads();
#pragma unroll
    for (int mi = 0; mi < 2; ++mi)
#pragma unroll
        for (int r = 0; r < 4; ++r)
#pragma unroll
            for (int ni = 0; ni < 2; ++ni)
                u.Cs[(wm + mi * 16 + q4 + r) * 72 + wn + ni * 16 + l15] =
                    f2b(acc[mi][ni][r]);
    __syncthreads();
#pragma unroll
    for (int pp = 0; pp < 2; ++pp) {
        int E = pp * 256 + t;
        int row = E >> 3, seg = E & 7;
        short8 val = *(const short8*)&u.Cs[row * 72 + seg * 8];
        *(short8*)&G[((size_t)b * C_ + c10 + row) * C_ + c20 + seg * 8] = val;
    }

    if (c10 != c20) {
        __syncthreads();
#pragma unroll
        for (int mi = 0; mi < 2; ++mi)
#pragma unroll
            for (int r = 0; r < 4; ++r)
#pragma unroll
                for (int ni = 0; ni < 2; ++ni)
                    u.Cs[(wn + ni * 16 + l15) * 72 + wm + mi * 16 + q4 + r] =
                        f2b(acc[mi][ni][r]);
        __syncthreads();
#pragma unroll
        for (int pp = 0; pp < 2; ++pp) {
            int E = pp * 256 + t;
            int row = E >> 3, seg = E & 7;
            short8 val = *(const short8*)&u.Cs[row * 72 + seg * 8];
            *(short8*)&G[((size_t)b * C_ + c20 + row) * C_ + c10 + seg * 8] = val;
        }
    }
}

// ---------------------------------------------------------------------------
// mid_ab (grid 32 = bh):
//  ph1: A_h[c,d] = sum_cc G[b][h*64+c][cc]*kw[h*64+d][cc] + X1[c]*kb[d] -> LDS
//       cvec[b][h*64+c] = X1[c]/2048 + (A_h·qb)[c]*SCALE_
//  ph2: BallT[b][cc][h*64+c] = sum_d A_h[c,d]*qwT[cc][h*64+d]
// r10: ph1 K-loop -> counted-vmcnt (8 gloads/stage, vmcnt(8)). 32-block
// kernel: drains are fully exposed (no TLP) -- the regime where T4 pays.
// ---------------------------------------------------------------------------
__global__ __launch_bounds__(256) void mid_ab(
    const unsigned short* __restrict__ G, const unsigned short* __restrict__ kwb,
    const unsigned short* __restrict__ qwT,
    const float* __restrict__ X1, const float* __restrict__ kb,
    const float* __restrict__ qb,
    unsigned short* __restrict__ BallT, float* __restrict__ cvec)
{
    const int t = threadIdx.x, w = t >> 6, lane = t & 63;
    const int bh = blockIdx.x, b = bh >> 4, h = bh & 15;
    const int l15 = lane & 15, q8 = (lane >> 4) * 8, q4 = (lane >> 4) * 4;

    __shared__ union {
        struct { __align__(16) unsigned short Gs[2][4][64 * 32];   // [buf][ks]
                 __align__(16) unsigned short Ks[2][4][64 * 32]; } st;
        __align__(16) unsigned short As[64 * 72];
    } u;

    const unsigned short* gb  = G   + ((size_t)b * C_ + h * 64) * C_;
    const unsigned short* kwh = kwb + (size_t)h * 64 * C_;

    auto stage = [&](int buf, int k0) {          // 8 gloads / thread
        int row = t >> 2, off = (t & 3) * 8;
#pragma unroll
        for (int seg = 0; seg < 4; ++seg) {
            GLOAD16(&gb[(size_t)row * C_ + k0 + seg * 32 + off],
                    &u.st.Gs[buf][seg][(w * 64) * 8]);
            GLOAD16(&kwh[(size_t)row * C_ + k0 + seg * 32 + off],
                    &u.st.Ks[buf][seg][(w * 64) * 8]);
        }
    };
    auto ld = [&](int cur, short8 a[4], short8 bf[4][4]) {
#pragma unroll
        for (int ks = 0; ks < 4; ++ks) {
            a[ks] = *(const short8*)&u.st.Gs[cur][ks][(w * 16 + l15) * 32 + q8];
#pragma unroll
            for (int ni = 0; ni < 4; ++ni)
                bf[ks][ni] = *(const short8*)&u.st.Ks[cur][ks][(ni * 16 + l15) * 32 + q8];
        }
    };

    f32x4 acc[4] = {};
    stage(0, 0);   MEMFENCE;
    stage(1, 128); MEMFENCE;

    for (int kt = 0; kt < 7; ++kt) {
        const int cur = kt & 1;
        WAIT_VM(8);                          // oldest 8 = buf[cur] landed
        __builtin_amdgcn_s_barrier();
        MEMFENCE;
        short8 a[4], bf[4][4];
        ld(cur, a, bf);
        WAIT_LGKM0;
        __builtin_amdgcn_s_barrier();
        MEMFENCE;
        if (kt < 6) stage(cur, (kt + 2) * 128);
#pragma unroll
        for (int ks = 0; ks < 4; ++ks)
#pragma unroll
            for (int ni = 0; ni < 4; ++ni)
                acc[ni] = MFMA(a[ks], bf[ks][ni], acc[ni]);
    }
    {   // peeled kt=7 (cur=1)
        WAIT_VM(0);
        __builtin_amdgcn_s_barrier();
        MEMFENCE;
        short8 a[4], bf[4][4];
        ld(1, a, bf);
        WAIT_LGKM0;
#pragma unroll
        for (int ks = 0; ks < 4; ++ks)
#pragma unroll
            for (int ni = 0; ni < 4; ++ni)
                acc[ni] = MFMA(a[ks], bf[ks][ni], acc[ni]);
    }
    __syncthreads();

    float x1r[4];
#pragma unroll
    for (int r = 0; r < 4; ++r)
        x1r[r] = X1[b * C_ + h * 64 + w * 16 + q4 + r];
    float ch[4] = {0.f, 0.f, 0.f, 0.f};
#pragma unroll
    for (int ni = 0; ni < 4; ++ni) {
        const int d = ni * 16 + l15;
        const float kbd = kb[h * 64 + d], qbd = qb[h * 64 + d];
#pragma unroll
        for (int r = 0; r < 4; ++r) {
            const int c = w * 16 + q4 + r;
            float a = acc[ni][r] + x1r[r] * kbd;
            u.As[c * 72 + d] = f2b(a);
            ch[r] += a * qbd;
        }
    }
#pragma unroll
    for (int r = 0; r < 4; ++r) {
#pragma unroll
        for (int dd = 1; dd < 16; dd <<= 1) ch[r] += __shfl_xor(ch[r], dd);
        if (l15 == 0)
            cvec[b * C_ + h * 64 + w * 16 + q4 + r] =
                x1r[r] * (1.0f / L_) + ch[r] * SCALE_;
    }
    __syncthreads();

#pragma unroll
    for (int i = 0; i < 4; ++i) {
        const int cc0 = (i * 4 + w) * 64;
        f32x4 ac[4][4] = {};
#pragma unroll
        for (int ks = 0; ks < 2; ++ks) {
            short8 af[4], bf[4];
#pragma unroll
            for (int mi = 0; mi < 4; ++mi)
                af[mi] = *(const short8*)&u.As[(mi * 16 + l15) * 72 + ks * 32 + q8];
#pragma unroll
            for (int ni = 0; ni < 4; ++ni)
                bf[ni] = *(const short8*)&qwT[(size_t)(cc0 + ni * 16 + l15) * C_
                                              + h * 64 + ks * 32 + q8];
#pragma unroll
            for (int mi = 0; mi < 4; ++mi)
#pragma unroll
                for (int ni = 0; ni < 4; ++ni)
                    ac[mi][ni] = MFMA(af[mi], bf[ni], ac[mi][ni]);
        }
#pragma unroll
        for (int ni = 0; ni < 4; ++ni)
#pragma unroll
            for (int mi = 0; mi < 4; ++mi) {
                bs4 o = pack4(ac[mi][ni]);
                *(bs4*)&BallT[((size_t)b * C_ + cc0 + ni * 16 + l15) * C_
                              + h * 64 + mi * 16 + q4] = o;
            }
    }
}

// ---------------------------------------------------------------------------
// wy_gemv: one launch unioning two independent kernels.
//  blocks [0,512)   : wy64 BK=128 -- now counted-vmcnt (8 gloads/stage).
//  blocks [512,528) : gemv -- dvec[b][o] = sum_c pwb[o,c]*cvec[b,c] + pb[o]
// ---------------------------------------------------------------------------
__global__ __launch_bounds__(256) void wy_gemv(
    const unsigned short* __restrict__ pwb, const unsigned short* __restrict__ BallT,
    unsigned short* __restrict__ Wy,
    const float* __restrict__ cvec, const float* __restrict__ pb,
    float* __restrict__ dvec)
{
    const int t = threadIdx.x;
    __shared__ union {
        __align__(16) unsigned short st[2][2][4][64 * 32];
        __align__(16) unsigned short Cs[64 * 72];
        float cv[1024];
    } u;

    const int bid = blockIdx.x;
    if (bid >= 512) {
        const int r = bid - 512, b = r >> 3;
        const int o = (r & 7) * 128 + (t >> 1), part = t & 1;
#pragma unroll
        for (int i = 0; i < 4; ++i) u.cv[t + i * 256] = cvec[b * C_ + t + i * 256];
        __syncthreads();
        const int base = part * 512;
        float acc = 0.f;
#pragma unroll 8
        for (int j = 0; j < 64; ++j) {
            short8 w8 = *(const short8*)&pwb[(size_t)o * C_ + base + j * 8];
#pragma unroll
            for (int e = 0; e < 8; ++e)
                acc = fmaf(b2f((unsigned short)w8[e]), u.cv[base + j * 8 + e], acc);
        }
        acc += __shfl_xor(acc, 1);
        if (part == 0) dvec[b * C_ + o] = acc + pb[o];
        return;
    }

    const int w = t >> 6, lane = t & 63;
    const int b = bid >> 8;
    const int o0 = ((bid >> 4) & 15) * 64, cc0 = (bid & 15) * 64;
    const int l15 = lane & 15, q8 = (lane >> 4) * 8, q4 = (lane >> 4) * 4;
    const int wm = (w >> 1) * 32, wn = (w & 1) * 32;
    const unsigned short* Bb = BallT + (size_t)b * C_ * C_;

    auto stage = [&](int buf, int k0) {          // 8 gloads / thread
        int row = t >> 2, off = (t & 3) * 8;
#pragma unroll
        for (int seg = 0; seg < 4; ++seg) {
            GLOAD16(&pwb[(size_t)(o0 + row) * C_ + k0 + seg * 32 + off],
                    &u.st[buf][0][seg][(w * 64) * 8]);
            GLOAD16(&Bb[(size_t)(cc0 + row) * C_ + k0 + seg * 32 + off],
                    &u.st[buf][1][seg][(w * 64) * 8]);
        }
    };
    auto ld = [&](int cur, short8 a[4][2], short8 bf[4][2]) {
#pragma unroll
        for (int ks = 0; ks < 4; ++ks) {
#pragma unroll
            for (int mi = 0; mi < 2; ++mi)
                a[ks][mi] = *(const short8*)&u.st[cur][0][ks][(wm + mi * 16 + l15) * 32 + q8];
#pragma unroll
            for (int ni = 0; ni < 2; ++ni)
                bf[ks][ni] = *(const short8*)&u.st[cur][1][ks][(wn + ni * 16 + l15) * 32 + q8];
        }
    };

    f32x4 acc[2][2] = {};
    stage(0, 0);   MEMFENCE;
    stage(1, 128); MEMFENCE;

    for (int kt = 0; kt < 7; ++kt) {
        const int cur = kt & 1;
        WAIT_VM(8);
        __builtin_amdgcn_s_barrier();
        MEMFENCE;
        short8 a[4][2], bf[4][2];
        ld(cur, a, bf);
        WAIT_LGKM0;
        __builtin_amdgcn_s_barrier();
        MEMFENCE;
        if (kt < 6) stage(cur, (kt + 2) * 128);
#pragma unroll
        for (int ks = 0; ks < 4; ++ks)
#pragma unroll
            for (int mi = 0; mi < 2; ++mi)
#pragma unroll
                for (int ni = 0; ni < 2; ++ni)
                    acc[mi][ni] = MFMA(a[ks][mi], bf[ks][ni], acc[mi][ni]);
    }
    {   // peeled kt=7 (cur=1)
        WAIT_VM(0);
        __builtin_amdgcn_s_barrier();
        MEMFENCE;
        short8 a[4][2], bf[4][2];
        ld(1, a, bf);
        WAIT_LGKM0;
#pragma unroll
        for (int ks = 0; ks < 4; ++ks)
#pragma unroll
            for (int mi = 0; mi < 2; ++mi)
#pragma unroll
                for (int ni = 0; ni < 2; ++ni)
                    acc[mi][ni] = MFMA(a[ks][mi], bf[ks][ni], acc[mi][ni]);
    }

    __syncthreads();
#pragma unroll
    for (int mi = 0; mi < 2; ++mi)
#pragma unroll
        for (int r = 0; r < 4; ++r)
#pragma unroll
            for (int ni = 0; ni < 2; ++ni)
                u.Cs[(wm + mi * 16 + q4 + r) * 72 + wn + ni * 16 + l15] =
                    f2b(acc[mi][ni][r] * SCALE_);
    __syncthreads();
#pragma unroll
    for (int p = 0; p < 2; ++p) {
        int E = p * 256 + t;
        int row = E >> 3, seg = E & 7;
        short8 val = *(const short8*)&u.Cs[row * 72 + seg * 8];
        *(short8*)&Wy[((size_t)b * C_ + o0 + row) * C_ + cc0 + seg * 8] = val;
    }
}

// ---------------------------------------------------------------------------
// gemm64 (r9 counted-vmcnt 2-phase, T4; unchanged in r10 except dead code
// removed): out[o][n] = sum_k A[o][k]*Bt[n][k]. 64x64 tile, BK=64, dbuf,
// 4 blocks/CU. Invariant: each wave keeps 8 gloads outstanding; oldest 4 are
// always buf[cur]'s; vmcnt(4)+barrier proves buf[cur] landed for ALL waves
// while the newest 4 stay in flight ACROSS the barrier. Stage into buf[cur]
// only after lgkmcnt(0)+barrier proves all waves' reads of it are done.
// Epilogue order: v=acc+bias; relu; v+=add0; outT=f2b(v); v+=add1; outf=v.
// ---------------------------------------------------------------------------
__global__ __launch_bounds__(256) void gemm64(
    const unsigned short* __restrict__ A0, size_t abstride,
    const float* __restrict__ bias, int bstride,
    const unsigned short* __restrict__ Bt,
    const float* __restrict__ add0, const float* __restrict__ add1,
    float* __restrict__ outf, unsigned short* __restrict__ outT, int relu)
{
    const int t = threadIdx.x, w = t >> 6, lane = t & 63;
    const int o0 = blockIdx.y * 64, n0 = blockIdx.x * 64;
    const int b_ = n0 >> 11;
    const int l15 = lane & 15, q8 = (lane >> 4) * 8, q4 = (lane >> 4) * 4;
    const int wm = (w >> 1) * 32, wn = (w & 1) * 32;
    const unsigned short* A = A0 + (size_t)b_ * abstride;

    __shared__ union {
        __align__(16) unsigned short st[2][2][2][64 * 32];
        __align__(16) unsigned short Cs[64 * 72];
    } u;
    __shared__ float biass[64];
    if (t < 64) biass[t] = bias[b_ * bstride + o0 + t];

    auto stage = [&](int buf, int k0) {
        int row = t >> 2, off = (t & 3) * 8;
        GLOAD16(&A[(size_t)(o0 + row) * C_ + k0 + off],       &u.st[buf][0][0][(w * 64) * 8]);
        GLOAD16(&A[(size_t)(o0 + row) * C_ + k0 + 32 + off],  &u.st[buf][0][1][(w * 64) * 8]);
        GLOAD16(&Bt[(size_t)(n0 + row) * C_ + k0 + off],      &u.st[buf][1][0][(w * 64) * 8]);
        GLOAD16(&Bt[(size_t)(n0 + row) * C_ + k0 + 32 + off], &u.st[buf][1][1][(w * 64) * 8]);
    };
    auto ld = [&](int cur, short8 a[2][2], short8 b[2][2]) {
#pragma unroll
        for (int ks = 0; ks < 2; ++ks) {
#pragma unroll
            for (int mi = 0; mi < 2; ++mi)
                a[ks][mi] = *(const short8*)&u.st[cur][0][ks][(wm + mi * 16 + l15) * 32 + q8];
#pragma unroll
            for (int ni = 0; ni < 2; ++ni)
                b[ks][ni] = *(const short8*)&u.st[cur][1][ks][(wn + ni * 16 + l15) * 32 + q8];
        }
    };

    f32x4 acc[2][2] = {};
    stage(0, 0);  MEMFENCE;
    stage(1, 64); MEMFENCE;

    for (int kt = 0; kt < 15; ++kt) {
        const int cur = kt & 1;
        WAIT_VM(4);
        __builtin_amdgcn_s_barrier();
        MEMFENCE;
        short8 a[2][2], b[2][2];
        ld(cur, a, b);
        WAIT_LGKM0;
        __builtin_amdgcn_s_barrier();
        MEMFENCE;
        if (kt < 14) stage(cur, (kt + 2) * 64);
#pragma unroll
        for (int ks = 0; ks < 2; ++ks)
#pragma unroll
            for (int mi = 0; mi < 2; ++mi)
#pragma unroll
                for (int ni = 0; ni < 2; ++ni)
                    acc[mi][ni] = MFMA(a[ks][mi], b[ks][ni], acc[mi][ni]);
    }
    {   // peeled kt=15 (cur=1)
        WAIT_VM(0);
        __builtin_amdgcn_s_barrier();
        MEMFENCE;
        short8 a[2][2], b[2][2];
        ld(1, a, b);
        WAIT_LGKM0;
#pragma unroll
        for (int ks = 0; ks < 2; ++ks)
#pragma unroll
            for (int mi = 0; mi < 2; ++mi)
#pragma unroll
                for (int ni = 0; ni < 2; ++ni)
                    acc[mi][ni] = MFMA(a[ks][mi], b[ks][ni], acc[mi][ni]);
    }

    __syncthreads();
    const int lbase = n0 & (L_ - 1);
#pragma unroll
    for (int mi = 0; mi < 2; ++mi)
#pragma unroll
        for (int r = 0; r < 4; ++r) {
            const int row = wm + mi * 16 + q4 + r;
            const float bv = biass[row];
#pragma unroll
            for (int ni = 0; ni < 2; ++ni) {
                const int col = wn + ni * 16 + l15;
                float v = acc[mi][ni][r] + bv;
                if (relu) v = fmaxf(v, 0.f);
                const size_t gidx = ((size_t)b_ * C_ + o0 + row) * L_ + lbase + col;
                float a0v = 0.f;
                if (add0) { a0v = add0[gidx]; v += a0v; }
                if (outT) u.Cs[col * 72 + row] = f2b(v);
                if (add1) v += (add1 == add0) ? a0v : add1[gidx];
                if (outf) outf[gidx] = v;
            }
        }

    if (outT) {
        __syncthreads();
#pragma unroll
        for (int p = 0; p < 2; ++p) {
            int E = p * 256 + t;
            int lr = E >> 3, g = E & 7;
            short8 val = *(const short8*)&u.Cs[lr * 72 + g * 8];
            *(short8*)(outT + (size_t)(n0 + lr) * C_ + o0 + g * 8) = val;
        }
    }
}

// ---------------------------------------------------------------------------
extern "C" void kernel_launch(void* const* d_in, const int* in_sizes, int n_in,
                              void* d_out, int out_size, void* d_ws, size_t ws_size,
                              hipStream_t stream) {
    const float* x   = (const float*)d_in[0];
    const float* kw  = (const float*)d_in[1];
    const float* kb  = (const float*)d_in[2];
    const float* qw  = (const float*)d_in[3];
    const float* qb  = (const float*)d_in[4];
    const float* pw  = (const float*)d_in[5];
    const float* pb  = (const float*)d_in[6];
    const float* c1w = (const float*)d_in[7];
    const float* c1b = (const float*)d_in[8];
    const float* c2w = (const float*)d_in[9];
    const float* c2b = (const float*)d_in[10];
    float* out = (float*)d_out;

    char* p = (char*)d_ws;
    auto carve = [&](size_t bytes) { char* r = p; p += (bytes + 255) & ~(size_t)255; return r; };
    const size_t WN = (size_t)C_ * C_;
    const size_t S  = (size_t)B_ * C_ * L_;
    unsigned short* wb    = (unsigned short*)carve(4 * WN * 2);  // kw,pw,c1w,c2w
    unsigned short* kwb   = wb;
    unsigned short* pwb   = wb + WN;
    unsigned short* c1wb  = wb + 2 * WN;
    unsigned short* c2wb  = wb + 3 * WN;
    unsigned short* qwT   = (unsigned short*)carve(WN * 2);
    unsigned short* xN    = (unsigned short*)carve(S * 2);
    unsigned short* xT    = (unsigned short*)carve(S * 2);
    float*          X1    = (float*)carve((size_t)B_ * C_ * 4);
    unsigned short* G     = (unsigned short*)carve((size_t)B_ * WN * 2);
    unsigned short* BallT = (unsigned short*)carve((size_t)B_ * WN * 2);
    float*          cvec  = (float*)carve((size_t)B_ * C_ * 4);
    unsigned short* Wy    = (unsigned short*)carve((size_t)B_ * WN * 2);
    float*          dvec  = (float*)carve((size_t)B_ * C_ * 4);
    unsigned short* yT    = (unsigned short*)carve(S * 2);
    unsigned short* rT    = (unsigned short*)carve(S * 2);
    float*          ybuf2 = (float*)carve(S * 4);   // holds y + x

    // X1 must be zero before prep_x's atomicAdds.
    hipMemsetAsync(X1, 0, (size_t)B_ * C_ * 4, stream);

    prep_x<<<dim3(L_ / 64, C_ / 64, B_), 256, 0, stream>>>(x, xN, xT, X1);

    Ptr4 wsrc; wsrc.p[0] = kw; wsrc.p[1] = pw; wsrc.p[2] = c1w; wsrc.p[3] = c2w;
    gram_wprep<<<272 + 4096 + 256, 256, 0, stream>>>(xN, G, wsrc, wb, qw, qwT);

    mid_ab<<<BH_, 256, 0, stream>>>(G, kwb, qwT, X1, kb, qb, BallT, cvec);
    wy_gemv<<<528, 256, 0, stream>>>(pwb, BallT, Wy, cvec, pb, dvec);

    dim3 gG(N_ / 64, C_ / 64);       // 64 x 16 = 1024 blocks = 4/CU
    // y = Wy·x + dvec + x ; yT = bf16(y) ; ybuf2 = y + x (x loaded once)
    gemm64<<<gG, 256, 0, stream>>>(Wy, WN, dvec, C_, xT, x, x, ybuf2, yT, 0);
    // r = relu(c1·y + c1b)
    gemm64<<<gG, 256, 0, stream>>>(c1wb, 0, c1b, 0, yT, nullptr, nullptr, nullptr, rT, 1);
    // out = c2·r + c2b + (y + x)
    gemm64<<<gG, 256, 0, stream>>>(c2wb, 0, c2b, 0, rT, ybuf2, nullptr, out, nullptr, 0);
}